// Round 6
// baseline (6953.332 us; speedup 1.0000x reference)
//
#include <hip/hip_runtime.h>
#include <cstddef>

#define NS_ITERS 12
#define MSZ 262144  // 512*512
#define PL  6291456 // 24*MSZ

typedef unsigned short u16;
typedef __attribute__((ext_vector_type(8))) short bf16x8;
typedef __attribute__((ext_vector_type(4))) float f32x4;
typedef __attribute__((ext_vector_type(4))) short u16x4;

__device__ inline u16 bf16_rne(float x){
  unsigned u = __float_as_uint(x);
  unsigned r = u + 0x7fffu + ((u>>16)&1u);
  return (u16)(r>>16);
}
__device__ inline float bf16f(u16 h){
  return __uint_as_float(((unsigned)h)<<16);
}

// ---------------- workspace offsets (in floats) ----------------
#define OFF_F4C   0ul
#define OFF_F4S   2097152ul
#define OFF_TF    4194304ul
#define OFF_DEC   6291456ul
#define OFF_SMALL 10223616ul
#define OFF_ARENA 10354688ul

// SMALL sub-offsets (floats)
#define SM_CENT    0
#define SM_ASSIGN  12288
#define SM_MU      20480
#define SM_COUNTS  32768
#define SM_SVAL    32800
#define SM_SCALE   32832
#define SM_TVEC    32864
#define SM_STATS_S 39008
#define SM_STATS_D 46688
#define SM_CLOSS   54368
#define SM_G       54400
#define SM_OS      54432

// ---------------- kernels ----------------

__global__ __launch_bounds__(256) void zerok(float* p, int n){
  int i = blockIdx.x*256 + threadIdx.x;
  if (i < n) p[i] = 0.f;
}

// ---- split-bf16 MFMA direct conv 3x3 SAME, generalized with channel padding ----
// Block: 64 Cout x 64 positions (8x8 px tile, halo 10x10), 4 waves of 32x32.
// CinP = Cin rounded up to 32 (loop bound); CinR/CoutR are true tensor dims.
__global__ __launch_bounds__(256) void convm(
    const float* __restrict__ in, const float* __restrict__ wgt,
    const float* __restrict__ bias, float* __restrict__ out,
    int CinP, int CinR, int CoutR, int H, int W, int relu)
{
  const int tilesW = W >> 3;
  const int h0 = (blockIdx.x / tilesW) << 3;
  const int w0 = (blockIdx.x % tilesW) << 3;
  const int co0 = blockIdx.y << 6;
  const int b  = blockIdx.z;
  const int tid = threadIdx.x;
  const int wid = tid >> 6, lane = tid & 63;
  const int wm = wid >> 1, wn = wid & 1;
  const int quad = lane >> 4, ln = lane & 15;

  __shared__ __align__(16) u16 sXh[100*40], sXl[100*40];
  __shared__ __align__(16) u16 sWh[3*64*40], sWl[3*64*40];

  f32x4 acc[2][2];
  #pragma unroll
  for (int i=0;i<2;i++)
    #pragma unroll
    for (int j=0;j<2;j++)
      #pragma unroll
      for (int e=0;e<4;e++) acc[i][j][e] = 0.f;

  for (int ci0 = 0; ci0 < CinP; ci0 += 32){
    __syncthreads();
    for (int e = tid; e < 3200; e += 256){
      int ci = e / 100, px = e - ci*100;
      int pr = px / 10, pc = px - pr*10;
      int ih = h0 + pr - 1, iw = w0 + pc - 1;
      float v = 0.f;
      if (ci0+ci < CinR && (unsigned)ih < (unsigned)H && (unsigned)iw < (unsigned)W)
        v = in[((size_t)(b*CinR + ci0+ci)*H + ih)*W + iw];
      u16 h = bf16_rne(v);
      sXh[px*40 + ci] = h;
      sXl[px*40 + ci] = bf16_rne(v - bf16f(h));
    }
    for (int dh = 0; dh < 3; ++dh){
      if (dh) __syncthreads();
      for (int e = tid; e < 6144; e += 256){
        int dw = e >> 11;
        int r  = e & 2047;
        int co = r >> 5, ci = r & 31;
        int cog = co0 + co, cig = ci0 + ci;
        float v = 0.f;
        if (cog < CoutR && cig < CinR)
          v = wgt[((size_t)cog*CinR + cig)*9 + dh*3 + dw];
        u16 h = bf16_rne(v);
        sWh[(dw*64+co)*40 + ci] = h;
        sWl[(dw*64+co)*40 + ci] = bf16_rne(v - bf16f(h));
      }
      __syncthreads();
      #pragma unroll
      for (int dw = 0; dw < 3; ++dw){
        bf16x8 ah[2], al[2], bh[2], bl[2];
        #pragma unroll
        for (int t=0;t<2;t++){
          const int co_l = (wm*2+t)*16 + ln;
          const int wo = (dw*64 + co_l)*40 + quad*8;
          ah[t] = *(const bf16x8*)&sWh[wo];
          al[t] = *(const bf16x8*)&sWl[wo];
          const int p = (wn*2+t)*16 + ln;
          const int px = ((p>>3) + dh)*10 + (p&7) + dw;
          const int xo = px*40 + quad*8;
          bh[t] = *(const bf16x8*)&sXh[xo];
          bl[t] = *(const bf16x8*)&sXl[xo];
        }
        #pragma unroll
        for (int mi=0;mi<2;mi++)
          #pragma unroll
          for (int ni=0;ni<2;ni++){
            acc[mi][ni] = __builtin_amdgcn_mfma_f32_16x16x32_bf16(ah[mi], bh[ni], acc[mi][ni], 0, 0, 0);
            acc[mi][ni] = __builtin_amdgcn_mfma_f32_16x16x32_bf16(ah[mi], bl[ni], acc[mi][ni], 0, 0, 0);
            acc[mi][ni] = __builtin_amdgcn_mfma_f32_16x16x32_bf16(al[mi], bh[ni], acc[mi][ni], 0, 0, 0);
          }
      }
    }
  }
  #pragma unroll
  for (int mi=0;mi<2;mi++){
    const int co = co0 + (wm*2+mi)*16 + quad*4;
    #pragma unroll
    for (int ni=0;ni<2;ni++){
      const int p = (wn*2+ni)*16 + ln;
      const int oh = h0 + (p>>3), ow = w0 + (p&7);
      #pragma unroll
      for (int rg=0; rg<4; rg++){
        const int cog = co + rg;
        if (cog < CoutR){
          float v = acc[mi][ni][rg] + bias[cog];
          if (relu) v = fmaxf(v, 0.f);
          out[((size_t)(b*CoutR + cog)*H + oh)*W + ow] = v;
        }
      }
    }
  }
}

__global__ __launch_bounds__(256) void pool2k(const float* __restrict__ in, float* __restrict__ out,
                                              int n, int Ho, int Wo){
  int idx = blockIdx.x*256 + threadIdx.x;
  if (idx >= n) return;
  int wo = idx % Wo; int t = idx / Wo; int ho = t % Ho; int bc = t / Ho;
  const float* p = in + ((size_t)bc*(Ho*2) + ho*2)*(size_t)(Wo*2) + (size_t)wo*2;
  out[idx] = 0.25f*(p[0] + p[1] + p[2*Wo] + p[2*Wo+1]);
}

__global__ __launch_bounds__(256) void up2k(const float* __restrict__ in, float* __restrict__ out,
                                            int n, int Ho, int Wo){
  int idx = blockIdx.x*256 + threadIdx.x;
  if (idx >= n) return;
  int wo = idx % Wo; int t = idx / Wo; int ho = t % Ho; int bc = t / Ho;
  int Hi = Ho >> 1, Wi = Wo >> 1;
  out[idx] = in[((size_t)bc*Hi + (ho>>1))*Wi + (wo>>1)];
}

// per-(b,c) spatial mean & std (ddof=0)
__global__ __launch_bounds__(256) void statsk(const float* __restrict__ x, int HW,
                                              float* __restrict__ mo, float* __restrict__ so){
  int bc = blockIdx.x, tid = threadIdx.x;
  const float* p = x + (size_t)bc*HW;
  double s = 0.0, s2 = 0.0;
  for (int i = tid; i < HW; i += 256){ double v = p[i]; s += v; s2 += v*v; }
  __shared__ double sh[256], sh2[256];
  sh[tid] = s; sh2[tid] = s2; __syncthreads();
  for (int k=128;k>0;k>>=1){ if (tid<k){ sh[tid]+=sh[tid+k]; sh2[tid]+=sh2[tid+k]; } __syncthreads(); }
  if (tid == 0){
    double m = sh[0]/HW;
    double var = sh2[0]/HW - m*m;
    if (var < 0.0) var = 0.0;
    mo[bc] = (float)m;
    so[bc] = (float)sqrt(var);
  }
}

// f4 (C-major, per image 512x1024) -> ptsT [8][1024][512]
__global__ __launch_bounds__(256) void transposek(const float* __restrict__ f4c,
                                                  const float* __restrict__ f4s,
                                                  float* __restrict__ ptsT){
  __shared__ float t[32][33];
  int r = blockIdx.z;
  const float* src = (r < 4) ? (f4c + (size_t)r*524288) : (f4s + (size_t)(r-4)*524288);
  int n0 = blockIdx.x*32, c0 = blockIdx.y*32;
  int lx = threadIdx.x & 31, ly = threadIdx.x >> 5;
  for (int j=0;j<32;j+=8)
    t[ly+j][lx] = src[(size_t)(c0+ly+j)*1024 + n0+lx];
  __syncthreads();
  for (int j=0;j<32;j+=8)
    ptsT[((size_t)r*1024 + n0+ly+j)*512 + c0+lx] = t[lx][ly+j];
}

__global__ __launch_bounds__(256) void initcentk(const float* __restrict__ ptsT, float* __restrict__ cent){
  int i = blockIdx.x*256 + threadIdx.x;
  if (i >= 12288) return;
  int c = i & 511; int k = (i >> 9) % 3; int r = i / 1536;
  cent[i] = ptsT[((size_t)r*1024 + k)*512 + c];
}

// one wave per point; first-min argmin (matches jnp.argmin)
__global__ __launch_bounds__(256) void assignk(const float* __restrict__ ptsT,
                                               const float* __restrict__ cent, int* __restrict__ a){
  int gp = blockIdx.x*4 + (threadIdx.x >> 6);
  int lane = threadIdx.x & 63;
  int r = gp >> 10;
  const float* p = ptsT + (size_t)gp*512;
  const float* ce = cent + r*1536;
  float d0=0.f,d1=0.f,d2=0.f;
  #pragma unroll
  for (int i=0;i<8;i++){
    int c = lane + i*64;
    float v = p[c];
    float e0 = v - ce[c], e1 = v - ce[512+c], e2 = v - ce[1024+c];
    d0 = fmaf(e0,e0,d0); d1 = fmaf(e1,e1,d1); d2 = fmaf(e2,e2,d2);
  }
  #pragma unroll
  for (int off=32; off>0; off>>=1){
    d0 += __shfl_down(d0, off, 64);
    d1 += __shfl_down(d1, off, 64);
    d2 += __shfl_down(d2, off, 64);
  }
  if (lane == 0){
    int bi = 0; float bd = d0;
    if (d1 < bd){ bd = d1; bi = 1; }
    if (d2 < bd){ bd = d2; bi = 2; }
    a[gp] = bi;
  }
}

// parallel centroid update: grid (r=8, cc=16), 256 thr
template<int WRITE>
__global__ __launch_bounds__(256) void updatek(const float* __restrict__ ptsT,
                                               const int* __restrict__ a,
                                               float* __restrict__ dst,
                                               float* __restrict__ counts){
  int r = blockIdx.x, cc = blockIdx.y;
  int tid = threadIdx.x;
  int lane = tid & 31, p = tid >> 5;
  int c = cc*32 + lane;
  __shared__ int sa[1024];
  __shared__ int scnt[3];
  if (tid < 3) scnt[tid] = 0;
  for (int i = tid; i < 1024; i += 256) sa[i] = a[r*1024 + i];
  __syncthreads();
  {
    int l0=0,l1=0,l2=0;
    #pragma unroll
    for (int i=tid*4;i<tid*4+4;i++){ int an=sa[i]; l0+=(an==0); l1+=(an==1); l2+=(an==2); }
    if (l0) atomicAdd(&scnt[0], l0);
    if (l1) atomicAdd(&scnt[1], l1);
    if (l2) atomicAdd(&scnt[2], l2);
  }
  const float* base = ptsT + (size_t)r*524288;
  float s0=0.f,s1=0.f,s2=0.f;
  for (int n = p*128; n < p*128+128; ++n){
    float v = base[(size_t)n*512 + c];
    int an = sa[n];
    s0 += (an==0) ? v : 0.f;
    s1 += (an==1) ? v : 0.f;
    s2 += (an==2) ? v : 0.f;
  }
  __shared__ float red[8][3][32];
  red[p][0][lane]=s0; red[p][1][lane]=s1; red[p][2][lane]=s2;
  __syncthreads();
  if (p == 0){
    float t0=0.f,t1=0.f,t2=0.f;
    #pragma unroll
    for (int q=0;q<8;q++){ t0+=red[q][0][lane]; t1+=red[q][1][lane]; t2+=red[q][2][lane]; }
    float n0 = (float)scnt[0] + 1e-6f, n1 = (float)scnt[1] + 1e-6f, n2 = (float)scnt[2] + 1e-6f;
    if (WRITE == 0){
      dst[r*1536 + c]        = t0/n0;
      dst[r*1536 + 512 + c]  = t1/n1;
      dst[r*1536 + 1024 + c] = t2/n2;
    } else {
      int cs = r >> 2, img = r & 3;
      int i0 = cs*12 + img*3;
      dst[(size_t)(i0+0)*512 + c] = t0/n0;
      dst[(size_t)(i0+1)*512 + c] = t1/n1;
      dst[(size_t)(i0+2)*512 + c] = t2/n2;
      if (cc == 0 && lane == 0){
        counts[i0]   = (float)scnt[0];
        counts[i0+1] = (float)scnt[1];
        counts[i0+2] = (float)scnt[2];
      }
    }
  }
}

// masked centered split planes: P[z][c][n] = (a[n]==k) ? pts[c][n]-mu[z][c] : 0
__global__ __launch_bounds__(256) void maskcenterk(const float* __restrict__ f4c, const float* __restrict__ f4s,
        const int* __restrict__ a, const float* __restrict__ mu,
        u16* __restrict__ Ph, u16* __restrict__ Pl){
  size_t i4 = ((size_t)blockIdx.x*256 + threadIdx.x)*4;
  if (i4 >= (size_t)PL*2) return;   // PL*2? no: total 24*512*1024 = 12582912 = PL*2
  int z = (int)(i4 >> 19);
  int rc = (int)(i4 & 524287);
  int c = rc >> 10, n = rc & 1023;
  int cs = z / 12; int rem = z - cs*12; int img = rem / 3; int k = rem - img*3;
  const float* pts = (cs ? f4s : f4c) + (size_t)img*524288;
  float m = mu[(size_t)z*512 + c];
  const int* an = a + (cs*4 + img)*1024 + n;
  float4 v4 = *(const float4*)&pts[(size_t)c*1024 + n];
  float vv[4] = {v4.x, v4.y, v4.z, v4.w};
  u16x4 oh, ol;
  #pragma unroll
  for (int j=0;j<4;j++){
    float v = (an[j] == k) ? (vv[j] - m) : 0.f;
    u16 h = bf16_rne(v);
    oh[j] = (short)h;
    ol[j] = (short)bf16_rne(v - bf16f(h));
  }
  *(u16x4*)&Ph[i4] = oh;
  *(u16x4*)&Pl[i4] = ol;
}

// covariance via MFMA: Ycov[z] = P[z] @ P[z]^T / nc + 0.1 I   (K=1024)
__global__ __launch_bounds__(256) void covgemm(const u16* __restrict__ Ph, const u16* __restrict__ Pl,
        const float* __restrict__ counts, float* __restrict__ Ycov){
  const int z = blockIdx.z;
  const u16* Pbh = Ph + (size_t)z*524288;
  const u16* Pbl = Pl + (size_t)z*524288;
  const int m0 = blockIdx.y*128, n0 = blockIdx.x*128;
  const int tid = threadIdx.x;

  __shared__ __align__(16) u16 sAh[128*40], sAl[128*40];
  __shared__ __align__(16) u16 sBh[128*40], sBl[128*40];

  const int ra = tid >> 2, qa = tid & 3;
  const int wid = tid >> 6, lane = tid & 63;
  const int wm = wid >> 1, wn = wid & 1;
  const int quad = lane >> 4, ln = lane & 15;

  f32x4 acc[4][4];
  #pragma unroll
  for (int i=0;i<4;i++)
    #pragma unroll
    for (int j=0;j<4;j++)
      #pragma unroll
      for (int e=0;e<4;e++) acc[i][j][e] = 0.f;

  for (int k0 = 0; k0 < 1024; k0 += 32){
    *(bf16x8*)&sAh[ra*40 + qa*8]      = *(const bf16x8*)&Pbh[(size_t)(m0+ra)*1024    + k0 + qa*8];
    *(bf16x8*)&sAl[ra*40 + qa*8]      = *(const bf16x8*)&Pbl[(size_t)(m0+ra)*1024    + k0 + qa*8];
    *(bf16x8*)&sAh[(ra+64)*40 + qa*8] = *(const bf16x8*)&Pbh[(size_t)(m0+ra+64)*1024 + k0 + qa*8];
    *(bf16x8*)&sAl[(ra+64)*40 + qa*8] = *(const bf16x8*)&Pbl[(size_t)(m0+ra+64)*1024 + k0 + qa*8];
    // B = P^T: the [n][k] LDS tile is just rows n0.. of P — contiguous, no scatter
    *(bf16x8*)&sBh[ra*40 + qa*8]      = *(const bf16x8*)&Pbh[(size_t)(n0+ra)*1024    + k0 + qa*8];
    *(bf16x8*)&sBl[ra*40 + qa*8]      = *(const bf16x8*)&Pbl[(size_t)(n0+ra)*1024    + k0 + qa*8];
    *(bf16x8*)&sBh[(ra+64)*40 + qa*8] = *(const bf16x8*)&Pbh[(size_t)(n0+ra+64)*1024 + k0 + qa*8];
    *(bf16x8*)&sBl[(ra+64)*40 + qa*8] = *(const bf16x8*)&Pbl[(size_t)(n0+ra+64)*1024 + k0 + qa*8];
    __syncthreads();

    bf16x8 ah[4], al[4], bh[4], bl[4];
    #pragma unroll
    for (int t=0;t<4;t++){
      const int moA = ((wm*4+t)*16 + ln)*40 + quad*8;
      const int moB = ((wn*4+t)*16 + ln)*40 + quad*8;
      ah[t] = *(const bf16x8*)&sAh[moA];
      al[t] = *(const bf16x8*)&sAl[moA];
      bh[t] = *(const bf16x8*)&sBh[moB];
      bl[t] = *(const bf16x8*)&sBl[moB];
    }
    #pragma unroll
    for (int mi=0;mi<4;mi++)
      #pragma unroll
      for (int ni=0;ni<4;ni++){
        acc[mi][ni] = __builtin_amdgcn_mfma_f32_16x16x32_bf16(ah[mi], bh[ni], acc[mi][ni], 0, 0, 0);
        acc[mi][ni] = __builtin_amdgcn_mfma_f32_16x16x32_bf16(ah[mi], bl[ni], acc[mi][ni], 0, 0, 0);
        acc[mi][ni] = __builtin_amdgcn_mfma_f32_16x16x32_bf16(al[mi], bh[ni], acc[mi][ni], 0, 0, 0);
      }
    __syncthreads();
  }
  const float inv = 1.f/(counts[z] + 1e-6f);
  #pragma unroll
  for (int mi=0;mi<4;mi++){
    const int mbase = m0 + (wm*4+mi)*16 + quad*4;
    #pragma unroll
    for (int ni=0;ni<4;ni++){
      const int n = n0 + (wn*4+ni)*16 + ln;
      #pragma unroll
      for (int rg=0;rg<4;rg++){
        const int m = mbase + rg;
        Ycov[(size_t)z*MSZ + (size_t)m*512 + n] = acc[mi][ni][rg]*inv + ((m==n)?0.1f:0.f);
      }
    }
  }
}

// power iteration for lambda_max
__global__ __launch_bounds__(256) void powk(const float* __restrict__ Y, float* __restrict__ sval){
  int z = blockIdx.x, tid = threadIdx.x;
  const float* M = Y + (size_t)z*MSZ;
  __shared__ float v[512];
  __shared__ float red[256];
  __shared__ float nrmsh;
  v[tid] = 1.f; v[tid+256] = 1.f;
  __syncthreads();
  float lastn = 0.1f;
  for (int it=0; it<10; ++it){
    float y0=0.f, y1=0.f;
    for (int c=0;c<512;c++){
      float vc = v[c];
      y0 = fmaf(M[(size_t)c*512 + tid      ], vc, y0);
      y1 = fmaf(M[(size_t)c*512 + tid + 256], vc, y1);
    }
    red[tid] = y0*y0 + y1*y1;
    __syncthreads();
    for (int s=128;s>0;s>>=1){ if (tid<s) red[tid]+=red[tid+s]; __syncthreads(); }
    if (tid==0) nrmsh = sqrtf(red[0]) + 1e-30f;
    __syncthreads();
    float nrm = nrmsh;
    v[tid] = y0/nrm; v[tid+256] = y1/nrm;
    lastn = nrm;
    __syncthreads();
  }
  if (tid==0) sval[z] = lastn*1.05f + 1e-12f;
}

// init split planes: Y = Ycov/s (hi+lo bf16), Z = I
__global__ __launch_bounds__(256) void nsinitk(const float* __restrict__ Ycov, const float* __restrict__ sval,
                                               u16* __restrict__ Yh, u16* __restrict__ Yl,
                                               u16* __restrict__ Zh, u16* __restrict__ Zl){
  size_t idx = (size_t)blockIdx.x*256 + threadIdx.x;
  if (idx >= (size_t)PL) return;
  int z = (int)(idx >> 18);
  int rc = (int)(idx & (MSZ-1));
  int rr = rc >> 9, cc = rc & 511;
  float y = Ycov[idx] / sval[z];
  u16 h = bf16_rne(y);
  Yh[idx] = h;
  Yl[idx] = bf16_rne(y - bf16f(h));
  Zh[idx] = (rr==cc) ? (u16)0x3F80 : (u16)0;
  Zl[idx] = 0;
}

// trace-scaled NS factors from split M: g = min(512/tr, 2.7); os = sqrt(g)/2
__global__ __launch_bounds__(256) void scalek(const u16* __restrict__ Mh, const u16* __restrict__ Ml,
                                              float* __restrict__ g, float* __restrict__ os){
  int z = blockIdx.x, tid = threadIdx.x;
  const u16* H = Mh + (size_t)z*MSZ;
  const u16* L = Ml + (size_t)z*MSZ;
  float s = bf16f(H[(size_t)tid*513]) + bf16f(L[(size_t)tid*513])
          + bf16f(H[(size_t)(tid+256)*513]) + bf16f(L[(size_t)(tid+256)*513]);
  __shared__ float sh[256];
  sh[tid] = s; __syncthreads();
  for (int k=128;k>0;k>>=1){ if (tid<k) sh[tid]+=sh[tid+k]; __syncthreads(); }
  if (tid==0){
    float tr = fmaxf(sh[0], 1e-6f);
    float g2 = fminf(512.f/tr, 2.7f);
    g[z] = g2;
    os[z] = 0.5f*sqrtf(g2);
  }
}

// ---- split-bf16 MFMA batched GEMM 512x512x512, general B (transpose-staged) ----
// MODE 0: C(split) = A@B ; MODE 1: C(split) = os*(3*D - g*(A@B)) ; MODE 2: C(split) = osc*(A@B)
template<int MODE>
__global__ __launch_bounds__(256) void bmms(
    const u16* __restrict__ Ah, const u16* __restrict__ Al,
    const u16* __restrict__ Bh, const u16* __restrict__ Bl,
    const u16* __restrict__ Dh, const u16* __restrict__ Dl,
    u16* __restrict__ Ch, u16* __restrict__ Cl,
    const float* __restrict__ gam, const float* __restrict__ osc,
    int aoff)
{
  const int z = blockIdx.z;
  const u16* Abh = Ah + (size_t)(z+aoff)*MSZ;
  const u16* Abl = Al + (size_t)(z+aoff)*MSZ;
  const u16* Bbh = Bh + (size_t)z*MSZ;
  const u16* Bbl = Bl + (size_t)z*MSZ;
  const int m0 = blockIdx.y*128, n0 = blockIdx.x*128;
  const int tid = threadIdx.x;

  __shared__ __align__(16) u16 sAh[128*40], sAl[128*40];
  __shared__ __align__(16) u16 sBh[128*40], sBl[128*40];

  const int ra = tid >> 2, qa = tid & 3;
  const int kb = tid >> 4, gb = tid & 15;

  const int wid = tid >> 6, lane = tid & 63;
  const int wm = wid >> 1, wn = wid & 1;
  const int quad = lane >> 4, ln = lane & 15;

  f32x4 acc[4][4];
  #pragma unroll
  for (int i=0;i<4;i++)
    #pragma unroll
    for (int j=0;j<4;j++)
      #pragma unroll
      for (int e=0;e<4;e++) acc[i][j][e] = 0.f;

  for (int k0 = 0; k0 < 512; k0 += 32){
    *(bf16x8*)&sAh[ra*40 + qa*8]      = *(const bf16x8*)&Abh[(size_t)(m0+ra)*512    + k0 + qa*8];
    *(bf16x8*)&sAl[ra*40 + qa*8]      = *(const bf16x8*)&Abl[(size_t)(m0+ra)*512    + k0 + qa*8];
    *(bf16x8*)&sAh[(ra+64)*40 + qa*8] = *(const bf16x8*)&Abh[(size_t)(m0+ra+64)*512 + k0 + qa*8];
    *(bf16x8*)&sAl[(ra+64)*40 + qa*8] = *(const bf16x8*)&Abl[(size_t)(m0+ra+64)*512 + k0 + qa*8];
    {
      bf16x8 vh = *(const bf16x8*)&Bbh[(size_t)(k0+kb)*512 + n0 + gb*8];
      bf16x8 vl = *(const bf16x8*)&Bbl[(size_t)(k0+kb)*512 + n0 + gb*8];
      #pragma unroll
      for (int j=0;j<8;j++){
        sBh[(gb*8+j)*40 + kb] = (u16)vh[j];
        sBl[(gb*8+j)*40 + kb] = (u16)vl[j];
      }
      vh = *(const bf16x8*)&Bbh[(size_t)(k0+kb+16)*512 + n0 + gb*8];
      vl = *(const bf16x8*)&Bbl[(size_t)(k0+kb+16)*512 + n0 + gb*8];
      #pragma unroll
      for (int j=0;j<8;j++){
        sBh[(gb*8+j)*40 + kb+16] = (u16)vh[j];
        sBl[(gb*8+j)*40 + kb+16] = (u16)vl[j];
      }
    }
    __syncthreads();

    bf16x8 ah[4], al[4], bh[4], bl[4];
    #pragma unroll
    for (int t=0;t<4;t++){
      const int moA = ((wm*4+t)*16 + ln)*40 + quad*8;
      const int moB = ((wn*4+t)*16 + ln)*40 + quad*8;
      ah[t] = *(const bf16x8*)&sAh[moA];
      al[t] = *(const bf16x8*)&sAl[moA];
      bh[t] = *(const bf16x8*)&sBh[moB];
      bl[t] = *(const bf16x8*)&sBl[moB];
    }
    #pragma unroll
    for (int mi=0;mi<4;mi++)
      #pragma unroll
      for (int ni=0;ni<4;ni++){
        acc[mi][ni] = __builtin_amdgcn_mfma_f32_16x16x32_bf16(ah[mi], bh[ni], acc[mi][ni], 0, 0, 0);
        acc[mi][ni] = __builtin_amdgcn_mfma_f32_16x16x32_bf16(ah[mi], bl[ni], acc[mi][ni], 0, 0, 0);
        acc[mi][ni] = __builtin_amdgcn_mfma_f32_16x16x32_bf16(al[mi], bh[ni], acc[mi][ni], 0, 0, 0);
      }
    __syncthreads();
  }

  float alpha = 1.f, beta = 0.f;
  if constexpr (MODE==1){ float gz = gam[z], oz = osc[z]; alpha = -gz*oz; beta = 3.f*oz; }
  if constexpr (MODE==2){ alpha = osc[z]; }

  #pragma unroll
  for (int mi=0;mi<4;mi++){
    const int mbase = m0 + (wm*4+mi)*16 + quad*4;
    #pragma unroll
    for (int ni=0;ni<4;ni++){
      const int n = n0 + (wn*4+ni)*16 + ln;
      #pragma unroll
      for (int rg=0;rg<4;rg++){
        const int m = mbase + rg;
        const size_t off = (size_t)z*MSZ + (size_t)m*512 + n;
        float v = alpha*acc[mi][ni][rg];
        if constexpr (MODE==1)
          v += beta*(bf16f(Dh[off]) + bf16f(Dl[off]));
        u16 h = bf16_rne(v);
        Ch[off] = h;
        Cl[off] = bf16_rne(v - bf16f(h));
      }
    }
  }
}

// tpts = T[z] @ f[img]: M=512, N=1024, K=512, fp32 out
__global__ __launch_bounds__(256) void bmmt(
    const u16* __restrict__ Th, const u16* __restrict__ Tl,
    const u16* __restrict__ fh, const u16* __restrict__ fl,
    float* __restrict__ Cf)
{
  const int z = blockIdx.z;
  const u16* Abh = Th + (size_t)z*MSZ;
  const u16* Abl = Tl + (size_t)z*MSZ;
  const u16* Bbh = fh + (size_t)(z/3)*524288;
  const u16* Bbl = fl + (size_t)(z/3)*524288;
  const int m0 = blockIdx.y*128, n0 = blockIdx.x*128;
  const int tid = threadIdx.x;

  __shared__ __align__(16) u16 sAh[128*40], sAl[128*40];
  __shared__ __align__(16) u16 sBh[128*40], sBl[128*40];

  const int ra = tid >> 2, qa = tid & 3;
  const int kb = tid >> 4, gb = tid & 15;
  const int wid = tid >> 6, lane = tid & 63;
  const int wm = wid >> 1, wn = wid & 1;
  const int quad = lane >> 4, ln = lane & 15;

  f32x4 acc[4][4];
  #pragma unroll
  for (int i=0;i<4;i++)
    #pragma unroll
    for (int j=0;j<4;j++)
      #pragma unroll
      for (int e=0;e<4;e++) acc[i][j][e] = 0.f;

  for (int k0 = 0; k0 < 512; k0 += 32){
    *(bf16x8*)&sAh[ra*40 + qa*8]      = *(const bf16x8*)&Abh[(size_t)(m0+ra)*512    + k0 + qa*8];
    *(bf16x8*)&sAl[ra*40 + qa*8]      = *(const bf16x8*)&Abl[(size_t)(m0+ra)*512    + k0 + qa*8];
    *(bf16x8*)&sAh[(ra+64)*40 + qa*8] = *(const bf16x8*)&Abh[(size_t)(m0+ra+64)*512 + k0 + qa*8];
    *(bf16x8*)&sAl[(ra+64)*40 + qa*8] = *(const bf16x8*)&Abl[(size_t)(m0+ra+64)*512 + k0 + qa*8];
    {
      bf16x8 vh = *(const bf16x8*)&Bbh[(size_t)(k0+kb)*1024 + n0 + gb*8];
      bf16x8 vl = *(const bf16x8*)&Bbl[(size_t)(k0+kb)*1024 + n0 + gb*8];
      #pragma unroll
      for (int j=0;j<8;j++){
        sBh[(gb*8+j)*40 + kb] = (u16)vh[j];
        sBl[(gb*8+j)*40 + kb] = (u16)vl[j];
      }
      vh = *(const bf16x8*)&Bbh[(size_t)(k0+kb+16)*1024 + n0 + gb*8];
      vl = *(const bf16x8*)&Bbl[(size_t)(k0+kb+16)*1024 + n0 + gb*8];
      #pragma unroll
      for (int j=0;j<8;j++){
        sBh[(gb*8+j)*40 + kb+16] = (u16)vh[j];
        sBl[(gb*8+j)*40 + kb+16] = (u16)vl[j];
      }
    }
    __syncthreads();

    bf16x8 ah[4], al[4], bh[4], bl[4];
    #pragma unroll
    for (int t=0;t<4;t++){
      const int moA = ((wm*4+t)*16 + ln)*40 + quad*8;
      const int moB = ((wn*4+t)*16 + ln)*40 + quad*8;
      ah[t] = *(const bf16x8*)&sAh[moA];
      al[t] = *(const bf16x8*)&sAl[moA];
      bh[t] = *(const bf16x8*)&sBh[moB];
      bl[t] = *(const bf16x8*)&sBl[moB];
    }
    #pragma unroll
    for (int mi=0;mi<4;mi++)
      #pragma unroll
      for (int ni=0;ni<4;ni++){
        acc[mi][ni] = __builtin_amdgcn_mfma_f32_16x16x32_bf16(ah[mi], bh[ni], acc[mi][ni], 0, 0, 0);
        acc[mi][ni] = __builtin_amdgcn_mfma_f32_16x16x32_bf16(ah[mi], bl[ni], acc[mi][ni], 0, 0, 0);
        acc[mi][ni] = __builtin_amdgcn_mfma_f32_16x16x32_bf16(al[mi], bh[ni], acc[mi][ni], 0, 0, 0);
      }
    __syncthreads();
  }
  #pragma unroll
  for (int mi=0;mi<4;mi++){
    const int mbase = m0 + (wm*4+mi)*16 + quad*4;
    #pragma unroll
    for (int ni=0;ni<4;ni++){
      const int n = n0 + (wn*4+ni)*16 + ln;
      #pragma unroll
      for (int rg=0;rg<4;rg++){
        const int m = mbase + rg;
        Cf[(size_t)z*524288 + (size_t)m*1024 + n] = acc[mi][ni][rg];
      }
    }
  }
}

// generic fp32 -> split bf16
__global__ __launch_bounds__(256) void splitk(const float* __restrict__ src,
                                              u16* __restrict__ dh, u16* __restrict__ dl, int n4){
  int i = blockIdx.x*256 + threadIdx.x;
  if (i >= n4) return;
  float4 v4 = *(const float4*)&src[(size_t)i*4];
  float vv[4] = {v4.x, v4.y, v4.z, v4.w};
  u16x4 oh, ol;
  #pragma unroll
  for (int j=0;j<4;j++){
    u16 h = bf16_rne(vv[j]);
    oh[j] = (short)h;
    ol[j] = (short)bf16_rne(vv[j] - bf16f(h));
  }
  *(u16x4*)&dh[(size_t)i*4] = oh;
  *(u16x4*)&dl[(size_t)i*4] = ol;
}

__global__ void make_scalesk(const float* __restrict__ sval, float* __restrict__ scl){
  int i = threadIdx.x;
  if (i < 12) scl[i] = sqrtf(sval[12+i] / sval[i]);
}

// tvec[b] = mu_s[b] - T[b] @ mu_c[b]   (T in split form)
__global__ __launch_bounds__(512) void tveck(const u16* __restrict__ Th, const u16* __restrict__ Tl,
                                             const float* __restrict__ mu, float* __restrict__ tvec){
  int b = blockIdx.x; int c = threadIdx.x;
  __shared__ float mc[512];
  mc[c] = mu[(size_t)b*512 + c];
  __syncthreads();
  const u16* Trh = Th + ((size_t)b*512 + c)*512;
  const u16* Trl = Tl + ((size_t)b*512 + c)*512;
  float s = 0.f;
  for (int d=0; d<512; d++) s = fmaf(bf16f(Trh[d]) + bf16f(Trl[d]), mc[d], s);
  tvec[b*512 + c] = mu[(size_t)(12+b)*512 + c] - s;
}

__global__ __launch_bounds__(256) void selectk(const float* __restrict__ tpts, const float* __restrict__ tvec,
        const int* __restrict__ a, const float* __restrict__ f4c, float* __restrict__ tf){
  size_t idx = (size_t)blockIdx.x*256 + threadIdx.x;
  if (idx >= 2097152ul) return;
  int n = (int)(idx & 1023);
  int c = (int)((idx >> 10) & 511);
  int img = (int)(idx >> 19);
  int k = a[img*1024 + n];
  int b = img*3 + k;
  float v = tpts[((size_t)b*512 + c)*1024 + n] + tvec[b*512 + c];
  tf[idx] = 0.6f*v + 0.4f*f4c[idx];
}

__global__ __launch_bounds__(256) void clossk(const float* __restrict__ x, const float* __restrict__ y,
                                              int n, float* __restrict__ acc){
  int tid = threadIdx.x;
  float s = 0.f;
  for (size_t i = (size_t)blockIdx.x*256 + tid; i < (size_t)n; i += (size_t)gridDim.x*256){
    float d = x[i] - y[i]; s = fmaf(d, d, s);
  }
  __shared__ float sh[256];
  sh[tid] = s; __syncthreads();
  for (int k=128;k>0;k>>=1){ if (tid<k) sh[tid]+=sh[tid+k]; __syncthreads(); }
  if (tid==0) atomicAdd(acc, sh[0]);
}

__global__ __launch_bounds__(256) void finalk(const float* __restrict__ sm, float* __restrict__ out){
  int tid = threadIdx.x;
  const int cnts[4] = {256,512,1024,2048};
  const int offs[4] = {0,256,768,1792};
  const float* mS = sm + SM_STATS_S;
  const float* sS = sm + SM_STATS_S + 3840;
  const float* mD = sm + SM_STATS_D;
  const float* sD = sm + SM_STATS_D + 3840;
  double sl = 0.0;
  for (int L=0; L<4; ++L){
    int cnt = cnts[L], off = offs[L];
    double inv = 1.0/cnt;
    for (int i=tid; i<cnt; i+=256){
      double dm = (double)mD[off+i] - (double)mS[off+i];
      double ds = (double)sD[off+i] - (double)sS[off+i];
      sl += (dm*dm + ds*ds)*inv;
    }
  }
  __shared__ double sh[256];
  sh[tid] = sl; __syncthreads();
  for (int k=128;k>0;k>>=1){ if (tid<k) sh[tid]+=sh[tid+k]; __syncthreads(); }
  if (tid==0){
    double closs = (double)sm[SM_CLOSS] / 2097152.0;
    out[0] = (float)(closs + 0.01*sh[0]);
  }
}

// ---------------- host ----------------

extern "C" void kernel_launch(void* const* d_in, const int* in_sizes, int n_in,
                              void* d_out, int out_size, void* d_ws, size_t ws_size,
                              hipStream_t stream)
{
  const float* content = (const float*)d_in[0];
  const float* style   = (const float*)d_in[1];
  const float* Wm[8]; const float* Bm[8];
  for (int i=0;i<8;i++){ Wm[i] = (const float*)d_in[2+2*i]; Bm[i] = (const float*)d_in[3+2*i]; }
  float* out = (float*)d_out;
  float* ws = (float*)d_ws;

  float* f4c  = ws + OFF_F4C;
  float* f4s  = ws + OFF_F4S;
  float* tf   = ws + OFF_TF;
  float* dec  = ws + OFF_DEC;
  float* sm   = ws + OFF_SMALL;
  float* AR   = ws + OFF_ARENA;
  int*   aPtr = (int*)(sm + SM_ASSIGN);
  float* cent = sm + SM_CENT;
  float* mu   = sm + SM_MU;
  float* counts = sm + SM_COUNTS;
  float* sval = sm + SM_SVAL;
  float* scl  = sm + SM_SCALE;
  float* tvec = sm + SM_TVEC;
  float* gbuf = sm + SM_G;
  float* obuf = sm + SM_OS;

  // arena plan (float-slot offsets):
  //   0..6291456        : Ycov (fp32) -> later Mh/Ml (split) -> later tpts (fp32) -> decoder scratch
  //   6291456..12582912 : Yh/Yl
  //   12582912..18874368: Zh/Zl
  //   18874368..31457280: Ph/Pl (cov) -> later Y2/Z2 planes; also Th/Tl/fsh/fsl after NS
  //   25165824..29360128: ptsT (dead before Pl written? no - Pl IS there; ptsT dead before maskcenterk)
  float* Ycov = AR;
  u16* Mh  = (u16*)(AR);
  u16* Ml  = (u16*)(AR + 3145728ul);
  u16* Yh  = (u16*)(AR + 6291456ul);
  u16* Yl  = (u16*)(AR + 9437184ul);
  u16* Zh  = (u16*)(AR + 12582912ul);
  u16* Zl  = (u16*)(AR + 15728640ul);
  u16* Y2h = (u16*)(AR + 18874368ul);
  u16* Y2l = (u16*)(AR + 22020096ul);
  u16* Z2h = (u16*)(AR + 25165824ul);
  u16* Z2l = (u16*)(AR + 28311552ul);
  u16* Ph  = (u16*)(AR + 18874368ul);   // 24*524288 u16 = 6291456 slots (aliases Y2h/Y2l; dead before NS)
  u16* Pl  = (u16*)(AR + 25165824ul);   // aliases Z2h/Z2l
  float* ptsT = AR + 25165824ul;        // dead before maskcenterk writes Pl
  // post-NS split T and f4c (alias Y2/Z2 regions, free after NS loop)
  u16* Th  = (u16*)(AR + 18874368ul);
  u16* Tl  = (u16*)(AR + 20971520ul);
  u16* fsh = (u16*)(AR + 23068672ul);
  u16* fsl = (u16*)(AR + 24117248ul);

  zerok<<<512,256,0,stream>>>(sm, 131072);

  auto convM = [&](const float* inp, int li, float* outp, int CinR,int CoutR,int H,int Wd,int relu){
    int CinP = (CinR + 31) & ~31;
    dim3 g((H>>3)*(Wd>>3), (CoutR+63)>>6, 4);
    convm<<<g,256,0,stream>>>(inp,Wm[li],Bm[li],outp,CinP,CinR,CoutR,H,Wd,relu);
  };
  auto pool = [&](const float* inp, float* outp, int C,int Ho,int Wo){
    int n = 4*C*Ho*Wo;
    pool2k<<<(n+255)/256,256,0,stream>>>(inp,outp,n,Ho,Wo);
  };
  auto up = [&](const float* inp, float* outp, int C,int Ho,int Wo){
    int n = 4*C*Ho*Wo;
    up2k<<<(n+255)/256,256,0,stream>>>(inp,outp,n,Ho,Wo);
  };

  // encode scratch (arena)
  float* F1 = AR + 0;
  float* P1 = AR + 16777216ul;
  float* F2 = AR + 0;
  float* P2 = AR + 8388608ul;
  float* F3 = AR + 10485760ul;
  float* P3 = AR + 0;

  // ---- content encode ----
  convM(content, 0, F1, 3,64,256,256,1);
  pool(F1,P1,64,128,128);
  convM(P1,1,F2, 64,128,128,128,1);
  pool(F2,P2,128,64,64);
  convM(P2,2,F3, 128,256,64,64,1);
  pool(F3,P3,256,32,32);
  convM(P3,3,f4c, 256,512,32,32,1);

  // ---- style encode + stats ----
  float* mS = sm + SM_STATS_S;
  float* sS = sm + SM_STATS_S + 3840;
  convM(style, 0, F1, 3,64,256,256,1);
  statsk<<<256,256,0,stream>>>(F1,65536, mS+0, sS+0);
  pool(F1,P1,64,128,128);
  convM(P1,1,F2, 64,128,128,128,1);
  statsk<<<512,256,0,stream>>>(F2,16384, mS+256, sS+256);
  pool(F2,P2,128,64,64);
  convM(P2,2,F3, 128,256,64,64,1);
  statsk<<<1024,256,0,stream>>>(F3,4096, mS+768, sS+768);
  pool(F3,P3,256,32,32);
  convM(P3,3,f4s, 256,512,32,32,1);
  statsk<<<2048,256,0,stream>>>(f4s,1024, mS+1792, sS+1792);

  // ---- k-means (content r=0..3, style r=4..7) ----
  transposek<<<dim3(32,16,8),256,0,stream>>>(f4c,f4s,ptsT);
  initcentk<<<48,256,0,stream>>>(ptsT,cent);
  for (int it=0; it<10; ++it){
    assignk<<<2048,256,0,stream>>>(ptsT,cent,aPtr);
    updatek<0><<<dim3(8,16),256,0,stream>>>(ptsT,aPtr,cent,nullptr);
  }
  assignk<<<2048,256,0,stream>>>(ptsT,cent,aPtr);
  updatek<1><<<dim3(8,16),256,0,stream>>>(ptsT,aPtr,mu,counts);

  // ---- covariances via MFMA ----
  maskcenterk<<<12288,256,0,stream>>>(f4c,f4s,aPtr,mu,Ph,Pl);
  covgemm<<<dim3(4,4,24),256,0,stream>>>(Ph,Pl,counts,Ycov);
  powk<<<24,256,0,stream>>>(Ycov,sval);
  nsinitk<<<24576,256,0,stream>>>(Ycov,sval,Yh,Yl,Zh,Zl);

  // ---- split-bf16 MFMA Newton-Schulz ----
  u16 *Ych=Yh,*Ycl=Yl,*Zch=Zh,*Zcl=Zl,*Yah=Y2h,*Yal=Y2l,*Zah=Z2h,*Zal=Z2l;
  for (int it=0; it<NS_ITERS; ++it){
    bmms<0><<<dim3(4,4,24),256,0,stream>>>(Zch,Zcl,Ych,Ycl,nullptr,nullptr,Mh,Ml,nullptr,nullptr,0);
    scalek<<<24,256,0,stream>>>(Mh,Ml,gbuf,obuf);
    bmms<1><<<dim3(4,4,24),256,0,stream>>>(Ych,Ycl,Mh,Ml,Ych,Ycl,Yah,Yal,gbuf,obuf,0);
    bmms<1><<<dim3(4,4,24),256,0,stream>>>(Mh,Ml,Zch,Zcl,Zch,Zcl,Zah,Zal,gbuf,obuf,0);
    u16* t;
    t=Ych;Ych=Yah;Yah=t; t=Ycl;Ycl=Yal;Yal=t;
    t=Zch;Zch=Zah;Zah=t; t=Zcl;Zcl=Zal;Zal=t;
  }
  // T[b] = sqrt(s_s/s_c) * Y_style[b] @ Z_content[b]  (split out; NS_ITERS even -> Ych=Yh, Zch=Zh)
  make_scalesk<<<1,64,0,stream>>>(sval,scl);
  bmms<2><<<dim3(4,4,12),256,0,stream>>>(Ych,Ycl,Zch,Zcl,nullptr,nullptr,Th,Tl,nullptr,scl,12);
  tveck<<<12,512,0,stream>>>(Th,Tl,mu,tvec);
  // tpts[b] = T[b] @ f[img]
  splitk<<<2048,256,0,stream>>>(f4c,fsh,fsl,524288);
  float* Mb = AR + 0;
  bmmt<<<dim3(8,4,12),256,0,stream>>>(Th,Tl,fsh,fsl,Mb);
  selectk<<<8192,256,0,stream>>>(Mb,tvec,aPtr,f4c,tf);

  // ---- decode ----
  float* X1 = AR + 0;
  float* U1 = AR + 1048576ul;
  float* X2 = AR + 5242880ul;
  float* U2 = AR + 7340032ul;
  float* X3 = AR + 0;
  float* U3 = AR + 4194304ul;
  convM(tf, 4, X1, 512,256,32,32,1);
  up(X1,U1,256,64,64);
  convM(U1,5,X2, 256,128,64,64,1);
  up(X2,U2,128,128,128);
  convM(U2,6,X3, 128,64,128,128,1);
  up(X3,U3,64,256,256);
  convM(U3,7,dec, 64,3,256,256,0);

  // ---- decoded encode + stats + content loss ----
  float* mD = sm + SM_STATS_D;
  float* sD = sm + SM_STATS_D + 3840;
  convM(dec, 0, F1, 3,64,256,256,1);
  statsk<<<256,256,0,stream>>>(F1,65536, mD+0, sD+0);
  pool(F1,P1,64,128,128);
  convM(P1,1,F2, 64,128,128,128,1);
  statsk<<<512,256,0,stream>>>(F2,16384, mD+256, sD+256);
  pool(F2,P2,128,64,64);
  convM(P2,2,F3, 128,256,64,64,1);
  statsk<<<1024,256,0,stream>>>(F3,4096, mD+768, sD+768);
  pool(F3,P3,256,32,32);
  convM(P3,3,tf, 256,512,32,32,1);   // f4(dec) reuses tf buffer
  statsk<<<2048,256,0,stream>>>(tf,1024, mD+1792, sD+1792);
  clossk<<<2048,256,0,stream>>>(tf,f4c,2097152, sm+SM_CLOSS);
  finalk<<<1,256,0,stream>>>(sm,out);
}

// Round 7
// 3423.390 us; speedup vs baseline: 2.0311x; 2.0311x over previous
//
#include <hip/hip_runtime.h>
#include <cstddef>

#define NS_ITERS 10
#define MSZ 262144  // 512*512
#define PL  6291456 // 24*MSZ

typedef unsigned short u16;
typedef __attribute__((ext_vector_type(8))) short bf16x8;
typedef __attribute__((ext_vector_type(4))) float f32x4;
typedef __attribute__((ext_vector_type(4))) short u16x4;

__device__ inline u16 bf16_rne(float x){
  unsigned u = __float_as_uint(x);
  unsigned r = u + 0x7fffu + ((u>>16)&1u);
  return (u16)(r>>16);
}
__device__ inline float bf16f(u16 h){
  return __uint_as_float(((unsigned)h)<<16);
}

// ---------------- workspace offsets (in floats) ----------------
#define OFF_F4C   0ul
#define OFF_F4S   2097152ul
#define OFF_TF    4194304ul
#define OFF_DEC   6291456ul
#define OFF_WSPL  7077888ul      // 3145728 floats: pre-split conv weights (u16 hi/lo)
#define OFF_SMALL 10223616ul
#define OFF_ARENA 10354688ul

// SMALL sub-offsets (floats)
#define SM_CENT    0
#define SM_ASSIGN  12288
#define SM_MU      20480
#define SM_COUNTS  32768
#define SM_SVAL    32800
#define SM_SCALE   32832
#define SM_TVEC    32864
#define SM_STATS_S 39008
#define SM_STATS_D 46688
#define SM_CLOSS   54368
#define SM_G       54400
#define SM_OS      54432

// ---------------- kernels ----------------

__global__ __launch_bounds__(256) void zerok(float* p, int n){
  int i = blockIdx.x*256 + threadIdx.x;
  if (i < n) p[i] = 0.f;
}

// direct 3x3 SAME conv (for e1: Cin=3, and d4: Cout=3 — tiny FLOPs, fp32 VALU is fine)
template<int COT>
__global__ __launch_bounds__(256) void conv3x3(
    const float* __restrict__ in, const float* __restrict__ wgt,
    const float* __restrict__ bias, float* __restrict__ out,
    int B, int Cin, int Cout, int H, int W, int relu)
{
  __shared__ float s_in[8][34][34];
  __shared__ float s_w[COT][8][9];
  const int tid = threadIdx.x;
  const int tx = tid & 15, ty = tid >> 4;
  const int tilesW = W >> 5;
  const int h0 = (blockIdx.x / tilesW) << 5;
  const int w0 = (blockIdx.x % tilesW) << 5;
  const int co0 = blockIdx.y * COT;
  const int b = blockIdx.z;
  float acc[COT][2][2];
  #pragma unroll
  for (int o=0;o<COT;o++){acc[o][0][0]=0.f;acc[o][0][1]=0.f;acc[o][1][0]=0.f;acc[o][1][1]=0.f;}
  const int y0 = ty*2, x0 = tx*2;
  for (int ci0 = 0; ci0 < Cin; ci0 += 8){
    const int cic = (Cin - ci0 < 8) ? (Cin - ci0) : 8;
    const int tot = cic*1156;
    for (int e = tid; e < tot; e += 256){
      int c = e / 1156; int r = e - c*1156;
      int lh = r / 34, lw = r - lh*34;
      int ih = h0 + lh - 1, iw = w0 + lw - 1;
      float v = 0.f;
      if ((unsigned)ih < (unsigned)H && (unsigned)iw < (unsigned)W)
        v = in[((size_t)(b*Cin + ci0 + c)*H + ih)*W + iw];
      s_in[c][lh][lw] = v;
    }
    const int wtot = COT*cic*9;
    for (int e = tid; e < wtot; e += 256){
      int o = e / (cic*9); int r = e - o*(cic*9);
      int c = r / 9, t = r - c*9;
      int co = co0 + o;
      float v = 0.f;
      if (co < Cout) v = wgt[(size_t)(co*Cin + ci0 + c)*9 + t];
      s_w[o][c][t] = v;
    }
    __syncthreads();
    for (int c = 0; c < cic; ++c){
      float p[4][4];
      #pragma unroll
      for (int r=0;r<4;r++)
        #pragma unroll
        for (int s=0;s<4;s++)
          p[r][s] = s_in[c][y0+r][x0+s];
      #pragma unroll
      for (int dh=0; dh<3; dh++)
        #pragma unroll
        for (int dw=0; dw<3; dw++){
          #pragma unroll
          for (int o=0;o<COT;o++){
            float wv = s_w[o][c][dh*3+dw];
            acc[o][0][0] = fmaf(p[dh  ][dw  ], wv, acc[o][0][0]);
            acc[o][0][1] = fmaf(p[dh  ][dw+1], wv, acc[o][0][1]);
            acc[o][1][0] = fmaf(p[dh+1][dw  ], wv, acc[o][1][0]);
            acc[o][1][1] = fmaf(p[dh+1][dw+1], wv, acc[o][1][1]);
          }
        }
    }
    __syncthreads();
  }
  #pragma unroll
  for (int o=0;o<COT;o++){
    int co = co0 + o;
    if (co >= Cout) continue;
    float bv = bias[co];
    #pragma unroll
    for (int r=0;r<2;r++)
      #pragma unroll
      for (int s=0;s<2;s++){
        float v = acc[o][r][s] + bv;
        if (relu) v = fmaxf(v, 0.f);
        out[((size_t)(b*Cout + co)*H + h0+y0+r)*W + w0+x0+s] = v;
      }
  }
}

// pre-split conv weights: dst[(dhw*Cout + co)*Cin + ci] = split(wgt[(co*Cin+ci)*9 + dhw])
__global__ __launch_bounds__(256) void wsplitk(const float* __restrict__ wgt,
                                               u16* __restrict__ dh_, u16* __restrict__ dl_,
                                               int Cout, int Cin){
  int idx = blockIdx.x*256 + threadIdx.x;
  int n = 9*Cout*Cin;
  if (idx >= n) return;
  int cc = Cout*Cin;
  int dhw = idx / cc;
  int r = idx - dhw*cc;
  int co = r / Cin, ci = r - co*Cin;
  float v = wgt[((size_t)co*Cin + ci)*9 + dhw];
  u16 h = bf16_rne(v);
  dh_[idx] = h;
  dl_[idx] = bf16_rne(v - bf16f(h));
}

// ---- split-bf16 MFMA direct conv 3x3 SAME; requires Cin%32==0, Cout%64==0 ----
// Block: 64 Cout x 64 positions (8x8 px tile, halo 10x10), 4 waves of 32x32.
// Weights pre-split in global: [(dh*3+dw)*Cout + co]*Cin + ci.
__global__ __launch_bounds__(256) void convm(
    const float* __restrict__ in, const u16* __restrict__ wsh, const u16* __restrict__ wsl,
    const float* __restrict__ bias, float* __restrict__ out,
    int Cin, int Cout, int H, int W, int relu)
{
  const int tilesW = W >> 3;
  const int h0 = (blockIdx.x / tilesW) << 3;
  const int w0 = (blockIdx.x % tilesW) << 3;
  const int co0 = blockIdx.y << 6;
  const int b  = blockIdx.z;
  const int tid = threadIdx.x;
  const int wid = tid >> 6, lane = tid & 63;
  const int wm = wid >> 1, wn = wid & 1;
  const int quad = lane >> 4, ln = lane & 15;

  __shared__ __align__(16) u16 sXh[100*40], sXl[100*40];
  __shared__ __align__(16) u16 sWh[3*64*40], sWl[3*64*40];

  f32x4 acc[2][2];
  #pragma unroll
  for (int i=0;i<2;i++)
    #pragma unroll
    for (int j=0;j<2;j++)
      #pragma unroll
      for (int e=0;e<4;e++) acc[i][j][e] = 0.f;

  for (int ci0 = 0; ci0 < Cin; ci0 += 32){
    __syncthreads();
    for (int e = tid; e < 3200; e += 256){
      int ci = e / 100, px = e - ci*100;
      int pr = px / 10, pc = px - pr*10;
      int ih = h0 + pr - 1, iw = w0 + pc - 1;
      float v = 0.f;
      if ((unsigned)ih < (unsigned)H && (unsigned)iw < (unsigned)W)
        v = in[((size_t)(b*Cin + ci0+ci)*H + ih)*W + iw];
      u16 h = bf16_rne(v);
      sXh[px*40 + ci] = h;
      sXl[px*40 + ci] = bf16_rne(v - bf16f(h));
    }
    for (int dh = 0; dh < 3; ++dh){
      if (dh) __syncthreads();
      // stage pre-split weight row dh: 3dw x 64co x 32ci = 768 vec8 copies
      for (int e2 = tid; e2 < 768; e2 += 256){
        int dw = e2 >> 8, r = e2 & 255;
        int co = r >> 2, cg = (r & 3) << 3;
        size_t so = ((size_t)((dh*3+dw)*Cout + co0+co))*Cin + ci0 + cg;
        int dsto = (dw*64+co)*40 + cg;
        *(bf16x8*)&sWh[dsto] = *(const bf16x8*)&wsh[so];
        *(bf16x8*)&sWl[dsto] = *(const bf16x8*)&wsl[so];
      }
      __syncthreads();
      #pragma unroll
      for (int dw = 0; dw < 3; ++dw){
        bf16x8 ah[2], al[2], bh[2], bl[2];
        #pragma unroll
        for (int t=0;t<2;t++){
          const int co_l = (wm*2+t)*16 + ln;
          const int wo = (dw*64 + co_l)*40 + quad*8;
          ah[t] = *(const bf16x8*)&sWh[wo];
          al[t] = *(const bf16x8*)&sWl[wo];
          const int p = (wn*2+t)*16 + ln;
          const int px = ((p>>3) + dh)*10 + (p&7) + dw;
          const int xo = px*40 + quad*8;
          bh[t] = *(const bf16x8*)&sXh[xo];
          bl[t] = *(const bf16x8*)&sXl[xo];
        }
        #pragma unroll
        for (int mi=0;mi<2;mi++)
          #pragma unroll
          for (int ni=0;ni<2;ni++){
            acc[mi][ni] = __builtin_amdgcn_mfma_f32_16x16x32_bf16(ah[mi], bh[ni], acc[mi][ni], 0, 0, 0);
            acc[mi][ni] = __builtin_amdgcn_mfma_f32_16x16x32_bf16(ah[mi], bl[ni], acc[mi][ni], 0, 0, 0);
            acc[mi][ni] = __builtin_amdgcn_mfma_f32_16x16x32_bf16(al[mi], bh[ni], acc[mi][ni], 0, 0, 0);
          }
      }
    }
  }
  #pragma unroll
  for (int mi=0;mi<2;mi++){
    const int co = co0 + (wm*2+mi)*16 + quad*4;
    #pragma unroll
    for (int ni=0;ni<2;ni++){
      const int p = (wn*2+ni)*16 + ln;
      const int oh = h0 + (p>>3), ow = w0 + (p&7);
      #pragma unroll
      for (int rg=0; rg<4; rg++){
        float v = acc[mi][ni][rg] + bias[co+rg];
        if (relu) v = fmaxf(v, 0.f);
        out[((size_t)(b*Cout + co+rg)*H + oh)*W + ow] = v;
      }
    }
  }
}

__global__ __launch_bounds__(256) void pool2k(const float* __restrict__ in, float* __restrict__ out,
                                              int n, int Ho, int Wo){
  int idx = blockIdx.x*256 + threadIdx.x;
  if (idx >= n) return;
  int wo = idx % Wo; int t = idx / Wo; int ho = t % Ho; int bc = t / Ho;
  const float* p = in + ((size_t)bc*(Ho*2) + ho*2)*(size_t)(Wo*2) + (size_t)wo*2;
  out[idx] = 0.25f*(p[0] + p[1] + p[2*Wo] + p[2*Wo+1]);
}

__global__ __launch_bounds__(256) void up2k(const float* __restrict__ in, float* __restrict__ out,
                                            int n, int Ho, int Wo){
  int idx = blockIdx.x*256 + threadIdx.x;
  if (idx >= n) return;
  int wo = idx % Wo; int t = idx / Wo; int ho = t % Ho; int bc = t / Ho;
  int Hi = Ho >> 1, Wi = Wo >> 1;
  out[idx] = in[((size_t)bc*Hi + (ho>>1))*Wi + (wo>>1)];
}

// per-(b,c) spatial mean & std (ddof=0)
__global__ __launch_bounds__(256) void statsk(const float* __restrict__ x, int HW,
                                              float* __restrict__ mo, float* __restrict__ so){
  int bc = blockIdx.x, tid = threadIdx.x;
  const float* p = x + (size_t)bc*HW;
  double s = 0.0, s2 = 0.0;
  for (int i = tid; i < HW; i += 256){ double v = p[i]; s += v; s2 += v*v; }
  __shared__ double sh[256], sh2[256];
  sh[tid] = s; sh2[tid] = s2; __syncthreads();
  for (int k=128;k>0;k>>=1){ if (tid<k){ sh[tid]+=sh[tid+k]; sh2[tid]+=sh2[tid+k]; } __syncthreads(); }
  if (tid == 0){
    double m = sh[0]/HW;
    double var = sh2[0]/HW - m*m;
    if (var < 0.0) var = 0.0;
    mo[bc] = (float)m;
    so[bc] = (float)sqrt(var);
  }
}

// f4 (C-major, per image 512x1024) -> ptsT [8][1024][512]
__global__ __launch_bounds__(256) void transposek(const float* __restrict__ f4c,
                                                  const float* __restrict__ f4s,
                                                  float* __restrict__ ptsT){
  __shared__ float t[32][33];
  int r = blockIdx.z;
  const float* src = (r < 4) ? (f4c + (size_t)r*524288) : (f4s + (size_t)(r-4)*524288);
  int n0 = blockIdx.x*32, c0 = blockIdx.y*32;
  int lx = threadIdx.x & 31, ly = threadIdx.x >> 5;
  for (int j=0;j<32;j+=8)
    t[ly+j][lx] = src[(size_t)(c0+ly+j)*1024 + n0+lx];
  __syncthreads();
  for (int j=0;j<32;j+=8)
    ptsT[((size_t)r*1024 + n0+ly+j)*512 + c0+lx] = t[lx][ly+j];
}

__global__ __launch_bounds__(256) void initcentk(const float* __restrict__ ptsT, float* __restrict__ cent){
  int i = blockIdx.x*256 + threadIdx.x;
  if (i >= 12288) return;
  int c = i & 511; int k = (i >> 9) % 3; int r = i / 1536;
  cent[i] = ptsT[((size_t)r*1024 + k)*512 + c];
}

// one wave per point; first-min argmin (matches jnp.argmin)
__global__ __launch_bounds__(256) void assignk(const float* __restrict__ ptsT,
                                               const float* __restrict__ cent, int* __restrict__ a){
  int gp = blockIdx.x*4 + (threadIdx.x >> 6);
  int lane = threadIdx.x & 63;
  int r = gp >> 10;
  const float* p = ptsT + (size_t)gp*512;
  const float* ce = cent + r*1536;
  float d0=0.f,d1=0.f,d2=0.f;
  #pragma unroll
  for (int i=0;i<8;i++){
    int c = lane + i*64;
    float v = p[c];
    float e0 = v - ce[c], e1 = v - ce[512+c], e2 = v - ce[1024+c];
    d0 = fmaf(e0,e0,d0); d1 = fmaf(e1,e1,d1); d2 = fmaf(e2,e2,d2);
  }
  #pragma unroll
  for (int off=32; off>0; off>>=1){
    d0 += __shfl_down(d0, off, 64);
    d1 += __shfl_down(d1, off, 64);
    d2 += __shfl_down(d2, off, 64);
  }
  if (lane == 0){
    int bi = 0; float bd = d0;
    if (d1 < bd){ bd = d1; bi = 1; }
    if (d2 < bd){ bd = d2; bi = 2; }
    a[gp] = bi;
  }
}

// parallel centroid update: grid (r=8, cc=16), 256 thr
template<int WRITE>
__global__ __launch_bounds__(256) void updatek(const float* __restrict__ ptsT,
                                               const int* __restrict__ a,
                                               float* __restrict__ dst,
                                               float* __restrict__ counts){
  int r = blockIdx.x, cc = blockIdx.y;
  int tid = threadIdx.x;
  int lane = tid & 31, p = tid >> 5;
  int c = cc*32 + lane;
  __shared__ int sa[1024];
  __shared__ int scnt[3];
  if (tid < 3) scnt[tid] = 0;
  for (int i = tid; i < 1024; i += 256) sa[i] = a[r*1024 + i];
  __syncthreads();
  {
    int l0=0,l1=0,l2=0;
    #pragma unroll
    for (int i=tid*4;i<tid*4+4;i++){ int an=sa[i]; l0+=(an==0); l1+=(an==1); l2+=(an==2); }
    if (l0) atomicAdd(&scnt[0], l0);
    if (l1) atomicAdd(&scnt[1], l1);
    if (l2) atomicAdd(&scnt[2], l2);
  }
  const float* base = ptsT + (size_t)r*524288;
  float s0=0.f,s1=0.f,s2=0.f;
  for (int n = p*128; n < p*128+128; ++n){
    float v = base[(size_t)n*512 + c];
    int an = sa[n];
    s0 += (an==0) ? v : 0.f;
    s1 += (an==1) ? v : 0.f;
    s2 += (an==2) ? v : 0.f;
  }
  __shared__ float red[8][3][32];
  red[p][0][lane]=s0; red[p][1][lane]=s1; red[p][2][lane]=s2;
  __syncthreads();
  if (p == 0){
    float t0=0.f,t1=0.f,t2=0.f;
    #pragma unroll
    for (int q=0;q<8;q++){ t0+=red[q][0][lane]; t1+=red[q][1][lane]; t2+=red[q][2][lane]; }
    float n0 = (float)scnt[0] + 1e-6f, n1 = (float)scnt[1] + 1e-6f, n2 = (float)scnt[2] + 1e-6f;
    if (WRITE == 0){
      dst[r*1536 + c]        = t0/n0;
      dst[r*1536 + 512 + c]  = t1/n1;
      dst[r*1536 + 1024 + c] = t2/n2;
    } else {
      int cs = r >> 2, img = r & 3;
      int i0 = cs*12 + img*3;
      dst[(size_t)(i0+0)*512 + c] = t0/n0;
      dst[(size_t)(i0+1)*512 + c] = t1/n1;
      dst[(size_t)(i0+2)*512 + c] = t2/n2;
      if (cc == 0 && lane == 0){
        counts[i0]   = (float)scnt[0];
        counts[i0+1] = (float)scnt[1];
        counts[i0+2] = (float)scnt[2];
      }
    }
  }
}

// masked centered split planes: P[z][c][n] = (a[n]==k) ? pts[c][n]-mu[z][c] : 0
__global__ __launch_bounds__(256) void maskcenterk(const float* __restrict__ f4c, const float* __restrict__ f4s,
        const int* __restrict__ a, const float* __restrict__ mu,
        u16* __restrict__ Ph, u16* __restrict__ Pl){
  size_t i4 = ((size_t)blockIdx.x*256 + threadIdx.x)*4;
  if (i4 >= (size_t)PL*2) return;   // total elems = 24*512*1024
  int z = (int)(i4 >> 19);
  int rc = (int)(i4 & 524287);
  int c = rc >> 10, n = rc & 1023;
  int cs = z / 12; int rem = z - cs*12; int img = rem / 3; int k = rem - img*3;
  const float* pts = (cs ? f4s : f4c) + (size_t)img*524288;
  float m = mu[(size_t)z*512 + c];
  const int* an = a + (cs*4 + img)*1024 + n;
  float4 v4 = *(const float4*)&pts[(size_t)c*1024 + n];
  float vv[4] = {v4.x, v4.y, v4.z, v4.w};
  u16x4 oh, ol;
  #pragma unroll
  for (int j=0;j<4;j++){
    float v = (an[j] == k) ? (vv[j] - m) : 0.f;
    u16 h = bf16_rne(v);
    oh[j] = (short)h;
    ol[j] = (short)bf16_rne(v - bf16f(h));
  }
  *(u16x4*)&Ph[i4] = oh;
  *(u16x4*)&Pl[i4] = ol;
}

// covariance via MFMA: Ycov[z] = P[z] @ P[z]^T / nc + 0.1 I   (K=1024)
__global__ __launch_bounds__(256) void covgemm(const u16* __restrict__ Ph, const u16* __restrict__ Pl,
        const float* __restrict__ counts, float* __restrict__ Ycov){
  const int z = blockIdx.z;
  const u16* Pbh = Ph + (size_t)z*524288;
  const u16* Pbl = Pl + (size_t)z*524288;
  const int m0 = blockIdx.y*128, n0 = blockIdx.x*128;
  const int tid = threadIdx.x;

  __shared__ __align__(16) u16 sAh[128*40], sAl[128*40];
  __shared__ __align__(16) u16 sBh[128*40], sBl[128*40];

  const int ra = tid >> 2, qa = tid & 3;
  const int wid = tid >> 6, lane = tid & 63;
  const int wm = wid >> 1, wn = wid & 1;
  const int quad = lane >> 4, ln = lane & 15;

  f32x4 acc[4][4];
  #pragma unroll
  for (int i=0;i<4;i++)
    #pragma unroll
    for (int j=0;j<4;j++)
      #pragma unroll
      for (int e=0;e<4;e++) acc[i][j][e] = 0.f;

  for (int k0 = 0; k0 < 1024; k0 += 32){
    *(bf16x8*)&sAh[ra*40 + qa*8]      = *(const bf16x8*)&Pbh[(size_t)(m0+ra)*1024    + k0 + qa*8];
    *(bf16x8*)&sAl[ra*40 + qa*8]      = *(const bf16x8*)&Pbl[(size_t)(m0+ra)*1024    + k0 + qa*8];
    *(bf16x8*)&sAh[(ra+64)*40 + qa*8] = *(const bf16x8*)&Pbh[(size_t)(m0+ra+64)*1024 + k0 + qa*8];
    *(bf16x8*)&sAl[(ra+64)*40 + qa*8] = *(const bf16x8*)&Pbl[(size_t)(m0+ra+64)*1024 + k0 + qa*8];
    *(bf16x8*)&sBh[ra*40 + qa*8]      = *(const bf16x8*)&Pbh[(size_t)(n0+ra)*1024    + k0 + qa*8];
    *(bf16x8*)&sBl[ra*40 + qa*8]      = *(const bf16x8*)&Pbl[(size_t)(n0+ra)*1024    + k0 + qa*8];
    *(bf16x8*)&sBh[(ra+64)*40 + qa*8] = *(const bf16x8*)&Pbh[(size_t)(n0+ra+64)*1024 + k0 + qa*8];
    *(bf16x8*)&sBl[(ra+64)*40 + qa*8] = *(const bf16x8*)&Pbl[(size_t)(n0+ra+64)*1024 + k0 + qa*8];
    __syncthreads();

    bf16x8 ah[4], al[4], bh[4], bl[4];
    #pragma unroll
    for (int t=0;t<4;t++){
      const int moA = ((wm*4+t)*16 + ln)*40 + quad*8;
      const int moB = ((wn*4+t)*16 + ln)*40 + quad*8;
      ah[t] = *(const bf16x8*)&sAh[moA];
      al[t] = *(const bf16x8*)&sAl[moA];
      bh[t] = *(const bf16x8*)&sBh[moB];
      bl[t] = *(const bf16x8*)&sBl[moB];
    }
    #pragma unroll
    for (int mi=0;mi<4;mi++)
      #pragma unroll
      for (int ni=0;ni<4;ni++){
        acc[mi][ni] = __builtin_amdgcn_mfma_f32_16x16x32_bf16(ah[mi], bh[ni], acc[mi][ni], 0, 0, 0);
        acc[mi][ni] = __builtin_amdgcn_mfma_f32_16x16x32_bf16(ah[mi], bl[ni], acc[mi][ni], 0, 0, 0);
        acc[mi][ni] = __builtin_amdgcn_mfma_f32_16x16x32_bf16(al[mi], bh[ni], acc[mi][ni], 0, 0, 0);
      }
    __syncthreads();
  }
  const float inv = 1.f/(counts[z] + 1e-6f);
  #pragma unroll
  for (int mi=0;mi<4;mi++){
    const int mbase = m0 + (wm*4+mi)*16 + quad*4;
    #pragma unroll
    for (int ni=0;ni<4;ni++){
      const int n = n0 + (wn*4+ni)*16 + ln;
      #pragma unroll
      for (int rg=0;rg<4;rg++){
        const int m = mbase + rg;
        Ycov[(size_t)z*MSZ + (size_t)m*512 + n] = acc[mi][ni][rg]*inv + ((m==n)?0.1f:0.f);
      }
    }
  }
}

// power iteration for lambda_max
__global__ __launch_bounds__(256) void powk(const float* __restrict__ Y, float* __restrict__ sval){
  int z = blockIdx.x, tid = threadIdx.x;
  const float* M = Y + (size_t)z*MSZ;
  __shared__ float v[512];
  __shared__ float red[256];
  __shared__ float nrmsh;
  v[tid] = 1.f; v[tid+256] = 1.f;
  __syncthreads();
  float lastn = 0.1f;
  for (int it=0; it<10; ++it){
    float y0=0.f, y1=0.f;
    for (int c=0;c<512;c++){
      float vc = v[c];
      y0 = fmaf(M[(size_t)c*512 + tid      ], vc, y0);
      y1 = fmaf(M[(size_t)c*512 + tid + 256], vc, y1);
    }
    red[tid] = y0*y0 + y1*y1;
    __syncthreads();
    for (int s=128;s>0;s>>=1){ if (tid<s) red[tid]+=red[tid+s]; __syncthreads(); }
    if (tid==0) nrmsh = sqrtf(red[0]) + 1e-30f;
    __syncthreads();
    float nrm = nrmsh;
    v[tid] = y0/nrm; v[tid+256] = y1/nrm;
    lastn = nrm;
    __syncthreads();
  }
  if (tid==0) sval[z] = lastn*1.05f + 1e-12f;
}

// init split planes: Y = Ycov/s (hi+lo bf16), Z = I
__global__ __launch_bounds__(256) void nsinitk(const float* __restrict__ Ycov, const float* __restrict__ sval,
                                               u16* __restrict__ Yh, u16* __restrict__ Yl,
                                               u16* __restrict__ Zh, u16* __restrict__ Zl){
  size_t idx = (size_t)blockIdx.x*256 + threadIdx.x;
  if (idx >= (size_t)PL) return;
  int z = (int)(idx >> 18);
  int rc = (int)(idx & (MSZ-1));
  int rr = rc >> 9, cc = rc & 511;
  float y = Ycov[idx] / sval[z];
  u16 h = bf16_rne(y);
  Yh[idx] = h;
  Yl[idx] = bf16_rne(y - bf16f(h));
  Zh[idx] = (rr==cc) ? (u16)0x3F80 : (u16)0;
  Zl[idx] = 0;
}

// trace-scaled NS factors from split M: g = min(512/tr, 2.7); os = sqrt(g)/2
__global__ __launch_bounds__(256) void scalek(const u16* __restrict__ Mh, const u16* __restrict__ Ml,
                                              float* __restrict__ g, float* __restrict__ os){
  int z = blockIdx.x, tid = threadIdx.x;
  const u16* H = Mh + (size_t)z*MSZ;
  const u16* L = Ml + (size_t)z*MSZ;
  float s = bf16f(H[(size_t)tid*513]) + bf16f(L[(size_t)tid*513])
          + bf16f(H[(size_t)(tid+256)*513]) + bf16f(L[(size_t)(tid+256)*513]);
  __shared__ float sh[256];
  sh[tid] = s; __syncthreads();
  for (int k=128;k>0;k>>=1){ if (tid<k) sh[tid]+=sh[tid+k]; __syncthreads(); }
  if (tid==0){
    float tr = fmaxf(sh[0], 1e-6f);
    float g2 = fminf(512.f/tr, 2.7f);
    g[z] = g2;
    os[z] = 0.5f*sqrtf(g2);
  }
}

// ---- split-bf16 MFMA batched GEMM 512x512x512 ----
// SYMB=1: B symmetric -> stage B^T tile as contiguous B rows (covgemm-verified path)
// SYMB=0: general B, transpose-scatter staging
// MODE 0: C = A@B ; MODE 1: C = os*(3*D - g*(A@B)) ; MODE 2: C = osc*(A@B)
template<int MODE, int SYMB>
__global__ __launch_bounds__(256) void bmms(
    const u16* __restrict__ Ah, const u16* __restrict__ Al,
    const u16* __restrict__ Bh, const u16* __restrict__ Bl,
    const u16* __restrict__ Dh, const u16* __restrict__ Dl,
    u16* __restrict__ Ch, u16* __restrict__ Cl,
    const float* __restrict__ gam, const float* __restrict__ osc,
    int aoff)
{
  const int z = blockIdx.z;
  const u16* Abh = Ah + (size_t)(z+aoff)*MSZ;
  const u16* Abl = Al + (size_t)(z+aoff)*MSZ;
  const u16* Bbh = Bh + (size_t)z*MSZ;
  const u16* Bbl = Bl + (size_t)z*MSZ;
  const int m0 = blockIdx.y*128, n0 = blockIdx.x*128;
  const int tid = threadIdx.x;

  __shared__ __align__(16) u16 sAh[128*40], sAl[128*40];
  __shared__ __align__(16) u16 sBh[128*40], sBl[128*40];

  const int ra = tid >> 2, qa = tid & 3;
  const int kb = tid >> 4, gb = tid & 15;

  const int wid = tid >> 6, lane = tid & 63;
  const int wm = wid >> 1, wn = wid & 1;
  const int quad = lane >> 4, ln = lane & 15;

  f32x4 acc[4][4];
  #pragma unroll
  for (int i=0;i<4;i++)
    #pragma unroll
    for (int j=0;j<4;j++)
      #pragma unroll
      for (int e=0;e<4;e++) acc[i][j][e] = 0.f;

  for (int k0 = 0; k0 < 512; k0 += 32){
    *(bf16x8*)&sAh[ra*40 + qa*8]      = *(const bf16x8*)&Abh[(size_t)(m0+ra)*512    + k0 + qa*8];
    *(bf16x8*)&sAl[ra*40 + qa*8]      = *(const bf16x8*)&Abl[(size_t)(m0+ra)*512    + k0 + qa*8];
    *(bf16x8*)&sAh[(ra+64)*40 + qa*8] = *(const bf16x8*)&Abh[(size_t)(m0+ra+64)*512 + k0 + qa*8];
    *(bf16x8*)&sAl[(ra+64)*40 + qa*8] = *(const bf16x8*)&Abl[(size_t)(m0+ra+64)*512 + k0 + qa*8];
    if constexpr (SYMB){
      *(bf16x8*)&sBh[ra*40 + qa*8]      = *(const bf16x8*)&Bbh[(size_t)(n0+ra)*512    + k0 + qa*8];
      *(bf16x8*)&sBl[ra*40 + qa*8]      = *(const bf16x8*)&Bbl[(size_t)(n0+ra)*512    + k0 + qa*8];
      *(bf16x8*)&sBh[(ra+64)*40 + qa*8] = *(const bf16x8*)&Bbh[(size_t)(n0+ra+64)*512 + k0 + qa*8];
      *(bf16x8*)&sBl[(ra+64)*40 + qa*8] = *(const bf16x8*)&Bbl[(size_t)(n0+ra+64)*512 + k0 + qa*8];
    } else {
      bf16x8 vh = *(const bf16x8*)&Bbh[(size_t)(k0+kb)*512 + n0 + gb*8];
      bf16x8 vl = *(const bf16x8*)&Bbl[(size_t)(k0+kb)*512 + n0 + gb*8];
      #pragma unroll
      for (int j=0;j<8;j++){
        sBh[(gb*8+j)*40 + kb] = (u16)vh[j];
        sBl[(gb*8+j)*40 + kb] = (u16)vl[j];
      }
      vh = *(const bf16x8*)&Bbh[(size_t)(k0+kb+16)*512 + n0 + gb*8];
      vl = *(const bf16x8*)&Bbl[(size_t)(k0+kb+16)*512 + n0 + gb*8];
      #pragma unroll
      for (int j=0;j<8;j++){
        sBh[(gb*8+j)*40 + kb+16] = (u16)vh[j];
        sBl[(gb*8+j)*40 + kb+16] = (u16)vl[j];
      }
    }
    __syncthreads();

    bf16x8 ah[4], al[4], bh[4], bl[4];
    #pragma unroll
    for (int t=0;t<4;t++){
      const int moA = ((wm*4+t)*16 + ln)*40 + quad*8;
      const int moB = ((wn*4+t)*16 + ln)*40 + quad*8;
      ah[t] = *(const bf16x8*)&sAh[moA];
      al[t] = *(const bf16x8*)&sAl[moA];
      bh[t] = *(const bf16x8*)&sBh[moB];
      bl[t] = *(const bf16x8*)&sBl[moB];
    }
    #pragma unroll
    for (int mi=0;mi<4;mi++)
      #pragma unroll
      for (int ni=0;ni<4;ni++){
        acc[mi][ni] = __builtin_amdgcn_mfma_f32_16x16x32_bf16(ah[mi], bh[ni], acc[mi][ni], 0, 0, 0);
        acc[mi][ni] = __builtin_amdgcn_mfma_f32_16x16x32_bf16(ah[mi], bl[ni], acc[mi][ni], 0, 0, 0);
        acc[mi][ni] = __builtin_amdgcn_mfma_f32_16x16x32_bf16(al[mi], bh[ni], acc[mi][ni], 0, 0, 0);
      }
    __syncthreads();
  }

  float alpha = 1.f, beta = 0.f;
  if constexpr (MODE==1){ float gz = gam[z], oz = osc[z]; alpha = -gz*oz; beta = 3.f*oz; }
  if constexpr (MODE==2){ alpha = osc[z]; }

  #pragma unroll
  for (int mi=0;mi<4;mi++){
    const int mbase = m0 + (wm*4+mi)*16 + quad*4;
    #pragma unroll
    for (int ni=0;ni<4;ni++){
      const int n = n0 + (wn*4+ni)*16 + ln;
      #pragma unroll
      for (int rg=0;rg<4;rg++){
        const int m = mbase + rg;
        const size_t off = (size_t)z*MSZ + (size_t)m*512 + n;
        float v = alpha*acc[mi][ni][rg];
        if constexpr (MODE==1)
          v += beta*(bf16f(Dh[off]) + bf16f(Dl[off]));
        u16 h = bf16_rne(v);
        Ch[off] = h;
        Cl[off] = bf16_rne(v - bf16f(h));
      }
    }
  }
}

// tpts = T[z] @ f[img]: M=512, N=1024, K=512, fp32 out (f non-symmetric: transpose-staged)
__global__ __launch_bounds__(256) void bmmt(
    const u16* __restrict__ Th, const u16* __restrict__ Tl,
    const u16* __restrict__ fh, const u16* __restrict__ fl,
    float* __restrict__ Cf)
{
  const int z = blockIdx.z;
  const u16* Abh = Th + (size_t)z*MSZ;
  const u16* Abl = Tl + (size_t)z*MSZ;
  const u16* Bbh = fh + (size_t)(z/3)*524288;
  const u16* Bbl = fl + (size_t)(z/3)*524288;
  const int m0 = blockIdx.y*128, n0 = blockIdx.x*128;
  const int tid = threadIdx.x;

  __shared__ __align__(16) u16 sAh[128*40], sAl[128*40];
  __shared__ __align__(16) u16 sBh[128*40], sBl[128*40];

  const int ra = tid >> 2, qa = tid & 3;
  const int kb = tid >> 4, gb = tid & 15;
  const int wid = tid >> 6, lane = tid & 63;
  const int wm = wid >> 1, wn = wid & 1;
  const int quad = lane >> 4, ln = lane & 15;

  f32x4 acc[4][4];
  #pragma unroll
  for (int i=0;i<4;i++)
    #pragma unroll
    for (int j=0;j<4;j++)
      #pragma unroll
      for (int e=0;e<4;e++) acc[i][j][e] = 0.f;

  for (int k0 = 0; k0 < 512; k0 += 32){
    *(bf16x8*)&sAh[ra*40 + qa*8]      = *(const bf16x8*)&Abh[(size_t)(m0+ra)*512    + k0 + qa*8];
    *(bf16x8*)&sAl[ra*40 + qa*8]      = *(const bf16x8*)&Abl[(size_t)(m0+ra)*512    + k0 + qa*8];
    *(bf16x8*)&sAh[(ra+64)*40 + qa*8] = *(const bf16x8*)&Abh[(size_t)(m0+ra+64)*512 + k0 + qa*8];
    *(bf16x8*)&sAl[(ra+64)*40 + qa*8] = *(const bf16x8*)&Abl[(size_t)(m0+ra+64)*512 + k0 + qa*8];
    {
      bf16x8 vh = *(const bf16x8*)&Bbh[(size_t)(k0+kb)*1024 + n0 + gb*8];
      bf16x8 vl = *(const bf16x8*)&Bbl[(size_t)(k0+kb)*1024 + n0 + gb*8];
      #pragma unroll
      for (int j=0;j<8;j++){
        sBh[(gb*8+j)*40 + kb] = (u16)vh[j];
        sBl[(gb*8+j)*40 + kb] = (u16)vl[j];
      }
      vh = *(const bf16x8*)&Bbh[(size_t)(k0+kb+16)*1024 + n0 + gb*8];
      vl = *(const bf16x8*)&Bbl[(size_t)(k0+kb+16)*1024 + n0 + gb*8];
      #pragma unroll
      for (int j=0;j<8;j++){
        sBh[(gb*8+j)*40 + kb+16] = (u16)vh[j];
        sBl[(gb*8+j)*40 + kb+16] = (u16)vl[j];
      }
    }
    __syncthreads();

    bf16x8 ah[4], al[4], bh[4], bl[4];
    #pragma unroll
    for (int t=0;t<4;t++){
      const int moA = ((wm*4+t)*16 + ln)*40 + quad*8;
      const int moB = ((wn*4+t)*16 + ln)*40 + quad*8;
      ah[t] = *(const bf16x8*)&sAh[moA];
      al[t] = *(const bf16x8*)&sAl[moA];
      bh[t] = *(const bf16x8*)&sBh[moB];
      bl[t] = *(const bf16x8*)&sBl[moB];
    }
    #pragma unroll
    for (int mi=0;mi<4;mi++)
      #pragma unroll
      for (int ni=0;ni<4;ni++){
        acc[mi][ni] = __builtin_amdgcn_mfma_f32_16x16x32_bf16(ah[mi], bh[ni], acc[mi][ni], 0, 0, 0);
        acc[mi][ni] = __builtin_amdgcn_mfma_f32_16x16x32_bf16(ah[mi], bl[ni], acc[mi][ni], 0, 0, 0);
        acc[mi][ni] = __builtin_amdgcn_mfma_f32_16x16x32_bf16(al[mi], bh[ni], acc[mi][ni], 0, 0, 0);
      }
    __syncthreads();
  }
  #pragma unroll
  for (int mi=0;mi<4;mi++){
    const int mbase = m0 + (wm*4+mi)*16 + quad*4;
    #pragma unroll
    for (int ni=0;ni<4;ni++){
      const int n = n0 + (wn*4+ni)*16 + ln;
      #pragma unroll
      for (int rg=0;rg<4;rg++){
        const int m = mbase + rg;
        Cf[(size_t)z*524288 + (size_t)m*1024 + n] = acc[mi][ni][rg];
      }
    }
  }
}

// generic fp32 -> split bf16
__global__ __launch_bounds__(256) void splitk(const float* __restrict__ src,
                                              u16* __restrict__ dh, u16* __restrict__ dl, int n4){
  int i = blockIdx.x*256 + threadIdx.x;
  if (i >= n4) return;
  float4 v4 = *(const float4*)&src[(size_t)i*4];
  float vv[4] = {v4.x, v4.y, v4.z, v4.w};
  u16x4 oh, ol;
  #pragma unroll
  for (int j=0;j<4;j++){
    u16 h = bf16_rne(vv[j]);
    oh[j] = (short)h;
    ol[j] = (short)bf16_rne(vv[j] - bf16f(h));
  }
  *(u16x4*)&dh[(size_t)i*4] = oh;
  *(u16x4*)&dl[(size_t)i*4] = ol;
}

__global__ void make_scalesk(const float* __restrict__ sval, float* __restrict__ scl){
  int i = threadIdx.x;
  if (i < 12) scl[i] = sqrtf(sval[12+i] / sval[i]);
}

// tvec[b] = mu_s[b] - T[b] @ mu_c[b]   (T in split form)
__global__ __launch_bounds__(512) void tveck(const u16* __restrict__ Th, const u16* __restrict__ Tl,
                                             const float* __restrict__ mu, float* __restrict__ tvec){
  int b = blockIdx.x; int c = threadIdx.x;
  __shared__ float mc[512];
  mc[c] = mu[(size_t)b*512 + c];
  __syncthreads();
  const u16* Trh = Th + ((size_t)b*512 + c)*512;
  const u16* Trl = Tl + ((size_t)b*512 + c)*512;
  float s = 0.f;
  for (int d=0; d<512; d++) s = fmaf(bf16f(Trh[d]) + bf16f(Trl[d]), mc[d], s);
  tvec[b*512 + c] = mu[(size_t)(12+b)*512 + c] - s;
}

__global__ __launch_bounds__(256) void selectk(const float* __restrict__ tpts, const float* __restrict__ tvec,
        const int* __restrict__ a, const float* __restrict__ f4c, float* __restrict__ tf){
  size_t idx = (size_t)blockIdx.x*256 + threadIdx.x;
  if (idx >= 2097152ul) return;
  int n = (int)(idx & 1023);
  int c = (int)((idx >> 10) & 511);
  int img = (int)(idx >> 19);
  int k = a[img*1024 + n];
  int b = img*3 + k;
  float v = tpts[((size_t)b*512 + c)*1024 + n] + tvec[b*512 + c];
  tf[idx] = 0.6f*v + 0.4f*f4c[idx];
}

__global__ __launch_bounds__(256) void clossk(const float* __restrict__ x, const float* __restrict__ y,
                                              int n, float* __restrict__ acc){
  int tid = threadIdx.x;
  float s = 0.f;
  for (size_t i = (size_t)blockIdx.x*256 + tid; i < (size_t)n; i += (size_t)gridDim.x*256){
    float d = x[i] - y[i]; s = fmaf(d, d, s);
  }
  __shared__ float sh[256];
  sh[tid] = s; __syncthreads();
  for (int k=128;k>0;k>>=1){ if (tid<k) sh[tid]+=sh[tid+k]; __syncthreads(); }
  if (tid==0) atomicAdd(acc, sh[0]);
}

__global__ __launch_bounds__(256) void finalk(const float* __restrict__ sm, float* __restrict__ out){
  int tid = threadIdx.x;
  const int cnts[4] = {256,512,1024,2048};
  const int offs[4] = {0,256,768,1792};
  const float* mS = sm + SM_STATS_S;
  const float* sS = sm + SM_STATS_S + 3840;
  const float* mD = sm + SM_STATS_D;
  const float* sD = sm + SM_STATS_D + 3840;
  double sl = 0.0;
  for (int L=0; L<4; ++L){
    int cnt = cnts[L], off = offs[L];
    double inv = 1.0/cnt;
    for (int i=tid; i<cnt; i+=256){
      double dm = (double)mD[off+i] - (double)mS[off+i];
      double ds = (double)sD[off+i] - (double)sS[off+i];
      sl += (dm*dm + ds*ds)*inv;
    }
  }
  __shared__ double sh[256];
  sh[tid] = sl; __syncthreads();
  for (int k=128;k>0;k>>=1){ if (tid<k) sh[tid]+=sh[tid+k]; __syncthreads(); }
  if (tid==0){
    double closs = (double)sm[SM_CLOSS] / 2097152.0;
    out[0] = (float)(closs + 0.01*sh[0]);
  }
}

// ---------------- host ----------------

extern "C" void kernel_launch(void* const* d_in, const int* in_sizes, int n_in,
                              void* d_out, int out_size, void* d_ws, size_t ws_size,
                              hipStream_t stream)
{
  const float* content = (const float*)d_in[0];
  const float* style   = (const float*)d_in[1];
  const float* Wm[8]; const float* Bm[8];
  for (int i=0;i<8;i++){ Wm[i] = (const float*)d_in[2+2*i]; Bm[i] = (const float*)d_in[3+2*i]; }
  float* out = (float*)d_out;
  float* ws = (float*)d_ws;

  float* f4c  = ws + OFF_F4C;
  float* f4s  = ws + OFF_F4S;
  float* tf   = ws + OFF_TF;
  float* dec  = ws + OFF_DEC;
  float* sm   = ws + OFF_SMALL;
  float* AR   = ws + OFF_ARENA;
  int*   aPtr = (int*)(sm + SM_ASSIGN);
  float* cent = sm + SM_CENT;
  float* mu   = sm + SM_MU;
  float* counts = sm + SM_COUNTS;
  float* sval = sm + SM_SVAL;
  float* scl  = sm + SM_SCALE;
  float* tvec = sm + SM_TVEC;
  float* gbuf = sm + SM_G;
  float* obuf = sm + SM_OS;

  // pre-split weights region (u16 units within OFF_WSPL's 3145728 floats = 6291456 u16)
  u16* WB = (u16*)(ws + OFF_WSPL);
  u16 *w2h=WB+0,       *w2l=WB+73728;    // e2: 9*128*64
  u16 *w3h=WB+147456,  *w3l=WB+442368;   // e3: 9*256*128
  u16 *w4h=WB+737280,  *w4l=WB+1916928;  // e4: 9*512*256
  u16 *v1h=WB+3096576, *v1l=WB+4276224;  // d1: 9*256*512
  u16 *v2h=WB+5455872, *v2l=WB+5750784;  // d2: 9*128*256
  u16 *v3h=WB+6045696, *v3l=WB+6119424;  // d3: 9*64*128

  float* Ycov = AR;
  u16* Mh  = (u16*)(AR);
  u16* Ml  = (u16*)(AR + 3145728ul);
  u16* Yh  = (u16*)(AR + 6291456ul);
  u16* Yl  = (u16*)(AR + 9437184ul);
  u16* Zh  = (u16*)(AR + 12582912ul);
  u16* Zl  = (u16*)(AR + 15728640ul);
  u16* Y2h = (u16*)(AR + 18874368ul);
  u16* Y2l = (u16*)(AR + 22020096ul);
  u16* Z2h = (u16*)(AR + 25165824ul);
  u16* Z2l = (u16*)(AR + 28311552ul);
  u16* Ph  = (u16*)(AR + 18874368ul);   // aliases Y2 (dead before NS)
  u16* Pl  = (u16*)(AR + 25165824ul);   // aliases Z2
  float* ptsT = AR + 25165824ul;        // dead before maskcenterk writes Pl
  u16* Th  = (u16*)(AR + 18874368ul);   // post-NS (Y2/Z2 free)
  u16* Tl  = (u16*)(AR + 20971520ul);
  u16* fsh = (u16*)(AR + 23068672ul);
  u16* fsl = (u16*)(AR + 24117248ul);

  zerok<<<512,256,0,stream>>>(sm, 131072);

  // pre-split mid-layer weights
  {
    auto wsp = [&](int li, u16* wh, u16* wl, int Co, int Ci){
      int n = 9*Co*Ci;
      wsplitk<<<(n+255)/256,256,0,stream>>>(Wm[li], wh, wl, Co, Ci);
    };
    wsp(1,w2h,w2l,128,64);
    wsp(2,w3h,w3l,256,128);
    wsp(3,w4h,w4l,512,256);
    wsp(4,v1h,v1l,256,512);
    wsp(5,v2h,v2l,128,256);
    wsp(6,v3h,v3l,64,128);
  }

  auto conv = [&](const float* inp, int li, float* outp, int Ci,int Co,int H,int Wd,int relu,int cot){
    dim3 g((H>>5)*(Wd>>5), (Co + cot - 1)/cot, 4);
    if (cot==8) conv3x3<8><<<g,256,0,stream>>>(inp,Wm[li],Bm[li],outp,4,Ci,Co,H,Wd,relu);
    else        conv3x3<4><<<g,256,0,stream>>>(inp,Wm[li],Bm[li],outp,4,Ci,Co,H,Wd,relu);
  };
  auto convM = [&](const float* inp, int li, float* outp, int Ci,int Co,int H,int Wd,int relu){
    const u16 *wh=nullptr,*wl=nullptr;
    switch(li){
      case 1: wh=w2h; wl=w2l; break;
      case 2: wh=w3h; wl=w3l; break;
      case 3: wh=w4h; wl=w4l; break;
      case 4: wh=v1h; wl=v1l; break;
      case 5: wh=v2h; wl=v2l; break;
      case 6: wh=v3h; wl=v3l; break;
    }
    dim3 g((H>>3)*(Wd>>3), Co>>6, 4);
    convm<<<g,256,0,stream>>>(inp,wh,wl,Bm[li],outp,Ci,Co,H,Wd,relu);
  };
  auto pool = [&](const float* inp, float* outp, int C,int Ho,int Wo){
    int n = 4*C*Ho*Wo;
    pool2k<<<(n+255)/256,256,0,stream>>>(inp,outp,n,Ho,Wo);
  };
  auto up = [&](const float* inp, float* outp, int C,int Ho,int Wo){
    int n = 4*C*Ho*Wo;
    up2k<<<(n+255)/256,256,0,stream>>>(inp,outp,n,Ho,Wo);
  };

  // encode scratch (arena)
  float* F1 = AR + 0;
  float* P1 = AR + 16777216ul;
  float* F2 = AR + 0;
  float* P2 = AR + 8388608ul;
  float* F3 = AR + 10485760ul;
  float* P3 = AR + 0;

  // ---- content encode ----
  conv(content, 0, F1, 3,64,256,256,1,8);
  pool(F1,P1,64,128,128);
  convM(P1,1,F2, 64,128,128,128,1);
  pool(F2,P2,128,64,64);
  convM(P2,2,F3, 128,256,64,64,1);
  pool(F3,P3,256,32,32);
  convM(P3,3,f4c, 256,512,32,32,1);

  // ---- style encode + stats ----
  float* mS = sm + SM_STATS_S;
  float* sS = sm + SM_STATS_S + 3840;
  conv(style, 0, F1, 3,64,256,256,1,8);
  statsk<<<256,256,0,stream>>>(F1,65536, mS+0, sS+0);
  pool(F1,P1,64,128,128);
  convM(P1,1,F2, 64,128,128,128,1);
  statsk<<<512,256,0,stream>>>(F2,16384, mS+256, sS+256);
  pool(F2,P2,128,64,64);
  convM(P2,2,F3, 128,256,64,64,1);
  statsk<<<1024,256,0,stream>>>(F3,4096, mS+768, sS+768);
  pool(F3,P3,256,32,32);
  convM(P3,3,f4s, 256,512,32,32,1);
  statsk<<<2048,256,0,stream>>>(f4s,1024, mS+1792, sS+1792);

  // ---- k-means (content r=0..3, style r=4..7) ----
  transposek<<<dim3(32,16,8),256,0,stream>>>(f4c,f4s,ptsT);
  initcentk<<<48,256,0,stream>>>(ptsT,cent);
  for (int it=0; it<10; ++it){
    assignk<<<2048,256,0,stream>>>(ptsT,cent,aPtr);
    updatek<0><<<dim3(8,16),256,0,stream>>>(ptsT,aPtr,cent,nullptr);
  }
  assignk<<<2048,256,0,stream>>>(ptsT,cent,aPtr);
  updatek<1><<<dim3(8,16),256,0,stream>>>(ptsT,aPtr,mu,counts);

  // ---- covariances via MFMA ----
  maskcenterk<<<12288,256,0,stream>>>(f4c,f4s,aPtr,mu,Ph,Pl);
  covgemm<<<dim3(4,4,24),256,0,stream>>>(Ph,Pl,counts,Ycov);
  powk<<<24,256,0,stream>>>(Ycov,sval);
  nsinitk<<<24576,256,0,stream>>>(Ycov,sval,Yh,Yl,Zh,Zl);

  // ---- split-bf16 MFMA Newton-Schulz (symmetric-B staging) ----
  u16 *Ych=Yh,*Ycl=Yl,*Zch=Zh,*Zcl=Zl,*Yah=Y2h,*Yal=Y2l,*Zah=Z2h,*Zal=Z2l;
  for (int it=0; it<NS_ITERS; ++it){
    bmms<0,1><<<dim3(4,4,24),256,0,stream>>>(Zch,Zcl,Ych,Ycl,nullptr,nullptr,Mh,Ml,nullptr,nullptr,0);
    scalek<<<24,256,0,stream>>>(Mh,Ml,gbuf,obuf);
    bmms<1,1><<<dim3(4,4,24),256,0,stream>>>(Ych,Ycl,Mh,Ml,Ych,Ycl,Yah,Yal,gbuf,obuf,0);
    bmms<1,1><<<dim3(4,4,24),256,0,stream>>>(Mh,Ml,Zch,Zcl,Zch,Zcl,Zah,Zal,gbuf,obuf,0);
    u16* t;
    t=Ych;Ych=Yah;Yah=t; t=Ycl;Ycl=Yal;Yal=t;
    t=Zch;Zch=Zah;Zah=t; t=Zcl;Zcl=Zal;Zal=t;
  }
  // T[b] = sqrt(s_s/s_c) * Y_style[b] @ Z_content[b]  (split out; NS_ITERS even -> Ych=Yh, Zch=Zh)
  make_scalesk<<<1,64,0,stream>>>(sval,scl);
  bmms<2,1><<<dim3(4,4,12),256,0,stream>>>(Ych,Ycl,Zch,Zcl,nullptr,nullptr,Th,Tl,nullptr,scl,12);
  tveck<<<12,512,0,stream>>>(Th,Tl,mu,tvec);
  // tpts[b] = T[b] @ f[img]
  splitk<<<2048,256,0,stream>>>(f4c,fsh,fsl,524288);
  float* Mb = AR + 0;
  bmmt<<<dim3(8,4,12),256,0,stream>>>(Th,Tl,fsh,fsl,Mb);
  selectk<<<8192,256,0,stream>>>(Mb,tvec,aPtr,f4c,tf);

  // ---- decode ----
  float* X1 = AR + 0;
  float* U1 = AR + 1048576ul;
  float* X2 = AR + 5242880ul;
  float* U2 = AR + 7340032ul;
  float* X3 = AR + 0;
  float* U3 = AR + 4194304ul;
  convM(tf, 4, X1, 512,256,32,32,1);
  up(X1,U1,256,64,64);
  convM(U1,5,X2, 256,128,64,64,1);
  up(X2,U2,128,128,128);
  convM(U2,6,X3, 128,64,128,128,1);
  up(X3,U3,64,256,256);
  conv(U3,7,dec, 64,3,256,256,0,4);

  // ---- decoded encode + stats + content loss ----
  float* mD = sm + SM_STATS_D;
  float* sD = sm + SM_STATS_D + 3840;
  conv(dec, 0, F1, 3,64,256,256,1,8);
  statsk<<<256,256,0,stream>>>(F1,65536, mD+0, sD+0);
  pool(F1,P1,64,128,128);
  convM(P1,1,F2, 64,128,128,128,1);
  statsk<<<512,256,0,stream>>>(F2,16384, mD+256, sD+256);
  pool(F2,P2,128,64,64);
  convM(P2,2,F3, 128,256,64,64,1);
  statsk<<<1024,256,0,stream>>>(F3,4096, mD+768, sD+768);
  pool(F3,P3,256,32,32);
  convM(P3,3,tf, 256,512,32,32,1);   // f4(dec) reuses tf buffer
  statsk<<<2048,256,0,stream>>>(tf,1024, mD+1792, sD+1792);
  clossk<<<2048,256,0,stream>>>(tf,f4c,2097152, sm+SM_CLOSS);
  finalk<<<1,256,0,stream>>>(sm,out);
}

// Round 8
// 3310.120 us; speedup vs baseline: 2.1006x; 1.0342x over previous
//
#include <hip/hip_runtime.h>
#include <cstddef>

#define NS_ITERS 10
#define MSZ 262144  // 512*512
#define PL  6291456 // 24*MSZ

typedef unsigned short u16;
typedef __attribute__((ext_vector_type(8))) short bf16x8;
typedef __attribute__((ext_vector_type(4))) float f32x4;
typedef __attribute__((ext_vector_type(4))) short u16x4;

__device__ inline u16 bf16_rne(float x){
  unsigned u = __float_as_uint(x);
  unsigned r = u + 0x7fffu + ((u>>16)&1u);
  return (u16)(r>>16);
}
__device__ inline float bf16f(u16 h){
  return __uint_as_float(((unsigned)h)<<16);
}

// ---------------- workspace offsets (in floats) ----------------
#define OFF_F4C   0ul
#define OFF_F4S   2097152ul
#define OFF_TF    4194304ul
#define OFF_DEC   6291456ul
#define OFF_WSPL  7077888ul      // 3145728 floats: pre-split conv weights (u16 hi/lo)
#define OFF_SMALL 10223616ul
#define OFF_ARENA 10354688ul

// SMALL sub-offsets (floats)
#define SM_CENT    0
#define SM_ASSIGN  12288
#define SM_MU      20480
#define SM_COUNTS  32768
#define SM_SVAL    32800
#define SM_SCALE   32832
#define SM_TVEC    32864
#define SM_STATS_S 39008
#define SM_STATS_D 46688
#define SM_CLOSS   54368
#define SM_G       54400
#define SM_OS      54432

// ---------------- kernels ----------------

__global__ __launch_bounds__(256) void zerok(float* p, int n){
  int i = blockIdx.x*256 + threadIdx.x;
  if (i < n) p[i] = 0.f;
}

// direct 3x3 SAME conv (for e1: Cin=3, and d4: Cout=3 — tiny FLOPs, fp32 VALU is fine)
template<int COT>
__global__ __launch_bounds__(256) void conv3x3(
    const float* __restrict__ in, const float* __restrict__ wgt,
    const float* __restrict__ bias, float* __restrict__ out,
    int B, int Cin, int Cout, int H, int W, int relu)
{
  __shared__ float s_in[8][34][34];
  __shared__ float s_w[COT][8][9];
  const int tid = threadIdx.x;
  const int tx = tid & 15, ty = tid >> 4;
  const int tilesW = W >> 5;
  const int h0 = (blockIdx.x / tilesW) << 5;
  const int w0 = (blockIdx.x % tilesW) << 5;
  const int co0 = blockIdx.y * COT;
  const int b = blockIdx.z;
  float acc[COT][2][2];
  #pragma unroll
  for (int o=0;o<COT;o++){acc[o][0][0]=0.f;acc[o][0][1]=0.f;acc[o][1][0]=0.f;acc[o][1][1]=0.f;}
  const int y0 = ty*2, x0 = tx*2;
  for (int ci0 = 0; ci0 < Cin; ci0 += 8){
    const int cic = (Cin - ci0 < 8) ? (Cin - ci0) : 8;
    const int tot = cic*1156;
    for (int e = tid; e < tot; e += 256){
      int c = e / 1156; int r = e - c*1156;
      int lh = r / 34, lw = r - lh*34;
      int ih = h0 + lh - 1, iw = w0 + lw - 1;
      float v = 0.f;
      if ((unsigned)ih < (unsigned)H && (unsigned)iw < (unsigned)W)
        v = in[((size_t)(b*Cin + ci0 + c)*H + ih)*W + iw];
      s_in[c][lh][lw] = v;
    }
    const int wtot = COT*cic*9;
    for (int e = tid; e < wtot; e += 256){
      int o = e / (cic*9); int r = e - o*(cic*9);
      int c = r / 9, t = r - c*9;
      int co = co0 + o;
      float v = 0.f;
      if (co < Cout) v = wgt[(size_t)(co*Cin + ci0 + c)*9 + t];
      s_w[o][c][t] = v;
    }
    __syncthreads();
    for (int c = 0; c < cic; ++c){
      float p[4][4];
      #pragma unroll
      for (int r=0;r<4;r++)
        #pragma unroll
        for (int s=0;s<4;s++)
          p[r][s] = s_in[c][y0+r][x0+s];
      #pragma unroll
      for (int dh=0; dh<3; dh++)
        #pragma unroll
        for (int dw=0; dw<3; dw++){
          #pragma unroll
          for (int o=0;o<COT;o++){
            float wv = s_w[o][c][dh*3+dw];
            acc[o][0][0] = fmaf(p[dh  ][dw  ], wv, acc[o][0][0]);
            acc[o][0][1] = fmaf(p[dh  ][dw+1], wv, acc[o][0][1]);
            acc[o][1][0] = fmaf(p[dh+1][dw  ], wv, acc[o][1][0]);
            acc[o][1][1] = fmaf(p[dh+1][dw+1], wv, acc[o][1][1]);
          }
        }
    }
    __syncthreads();
  }
  #pragma unroll
  for (int o=0;o<COT;o++){
    int co = co0 + o;
    if (co >= Cout) continue;
    float bv = bias[co];
    #pragma unroll
    for (int r=0;r<2;r++)
      #pragma unroll
      for (int s=0;s<2;s++){
        float v = acc[o][r][s] + bv;
        if (relu) v = fmaxf(v, 0.f);
        out[((size_t)(b*Cout + co)*H + h0+y0+r)*W + w0+x0+s] = v;
      }
  }
}

// pre-split conv weights: dst[(dhw*Cout + co)*Cin + ci] = split(wgt[(co*Cin+ci)*9 + dhw])
__global__ __launch_bounds__(256) void wsplitk(const float* __restrict__ wgt,
                                               u16* __restrict__ dh_, u16* __restrict__ dl_,
                                               int Cout, int Cin){
  int idx = blockIdx.x*256 + threadIdx.x;
  int n = 9*Cout*Cin;
  if (idx >= n) return;
  int cc = Cout*Cin;
  int dhw = idx / cc;
  int r = idx - dhw*cc;
  int co = r / Cin, ci = r - co*Cin;
  float v = wgt[((size_t)co*Cin + ci)*9 + dhw];
  u16 h = bf16_rne(v);
  dh_[idx] = h;
  dl_[idx] = bf16_rne(v - bf16f(h));
}

// ---- split-bf16 MFMA direct conv 3x3 SAME; requires Cin%(32*KS)==0, Cout%64==0 ----
// Block: 64 Cout x 64 positions (8x8 px tile, halo 10x10), 4 waves of 32x32.
// KS>1: blockIdx.z = b*KS + ks; each block does Cin/KS channels, writes fp32 partial
// slice [ks][b][Cout][H][W] (no bias/relu); sumk epilogue reduces.
template<int KS>
__global__ __launch_bounds__(256) void convm(
    const float* __restrict__ in, const u16* __restrict__ wsh, const u16* __restrict__ wsl,
    const float* __restrict__ bias, float* __restrict__ out,
    int Cin, int Cout, int H, int W, int relu)
{
  const int tilesW = W >> 3;
  const int h0 = (blockIdx.x / tilesW) << 3;
  const int w0 = (blockIdx.x % tilesW) << 3;
  const int co0 = blockIdx.y << 6;
  const int b  = blockIdx.z / KS;
  const int ks = blockIdx.z % KS;
  const int tid = threadIdx.x;
  const int wid = tid >> 6, lane = tid & 63;
  const int wm = wid >> 1, wn = wid & 1;
  const int quad = lane >> 4, ln = lane & 15;

  __shared__ __align__(16) u16 sXh[100*40], sXl[100*40];
  __shared__ __align__(16) u16 sWh[3*64*40], sWl[3*64*40];

  f32x4 acc[2][2];
  #pragma unroll
  for (int i=0;i<2;i++)
    #pragma unroll
    for (int j=0;j<2;j++)
      #pragma unroll
      for (int e=0;e<4;e++) acc[i][j][e] = 0.f;

  const int ciA = ks*(Cin/KS), ciB = ciA + Cin/KS;
  for (int ci0 = ciA; ci0 < ciB; ci0 += 32){
    __syncthreads();
    for (int e = tid; e < 3200; e += 256){
      int ci = e / 100, px = e - ci*100;
      int pr = px / 10, pc = px - pr*10;
      int ih = h0 + pr - 1, iw = w0 + pc - 1;
      float v = 0.f;
      if ((unsigned)ih < (unsigned)H && (unsigned)iw < (unsigned)W)
        v = in[((size_t)(b*Cin + ci0+ci)*H + ih)*W + iw];
      u16 h = bf16_rne(v);
      sXh[px*40 + ci] = h;
      sXl[px*40 + ci] = bf16_rne(v - bf16f(h));
    }
    for (int dh = 0; dh < 3; ++dh){
      if (dh) __syncthreads();
      for (int e2 = tid; e2 < 768; e2 += 256){
        int dw = e2 >> 8, r = e2 & 255;
        int co = r >> 2, cg = (r & 3) << 3;
        size_t so = ((size_t)((dh*3+dw)*Cout + co0+co))*Cin + ci0 + cg;
        int dsto = (dw*64+co)*40 + cg;
        *(bf16x8*)&sWh[dsto] = *(const bf16x8*)&wsh[so];
        *(bf16x8*)&sWl[dsto] = *(const bf16x8*)&wsl[so];
      }
      __syncthreads();
      #pragma unroll
      for (int dw = 0; dw < 3; ++dw){
        bf16x8 ah[2], al[2], bh[2], bl[2];
        #pragma unroll
        for (int t=0;t<2;t++){
          const int co_l = (wm*2+t)*16 + ln;
          const int wo = (dw*64 + co_l)*40 + quad*8;
          ah[t] = *(const bf16x8*)&sWh[wo];
          al[t] = *(const bf16x8*)&sWl[wo];
          const int p = (wn*2+t)*16 + ln;
          const int px = ((p>>3) + dh)*10 + (p&7) + dw;
          const int xo = px*40 + quad*8;
          bh[t] = *(const bf16x8*)&sXh[xo];
          bl[t] = *(const bf16x8*)&sXl[xo];
        }
        #pragma unroll
        for (int mi=0;mi<2;mi++)
          #pragma unroll
          for (int ni=0;ni<2;ni++){
            acc[mi][ni] = __builtin_amdgcn_mfma_f32_16x16x32_bf16(ah[mi], bh[ni], acc[mi][ni], 0, 0, 0);
            acc[mi][ni] = __builtin_amdgcn_mfma_f32_16x16x32_bf16(ah[mi], bl[ni], acc[mi][ni], 0, 0, 0);
            acc[mi][ni] = __builtin_amdgcn_mfma_f32_16x16x32_bf16(al[mi], bh[ni], acc[mi][ni], 0, 0, 0);
          }
      }
    }
  }
  #pragma unroll
  for (int mi=0;mi<2;mi++){
    const int co = co0 + (wm*2+mi)*16 + quad*4;
    #pragma unroll
    for (int ni=0;ni<2;ni++){
      const int p = (wn*2+ni)*16 + ln;
      const int oh = h0 + (p>>3), ow = w0 + (p&7);
      #pragma unroll
      for (int rg=0; rg<4; rg++){
        const int cog = co + rg;
        if constexpr (KS==1){
          float v = acc[mi][ni][rg] + bias[cog];
          if (relu) v = fmaxf(v, 0.f);
          out[((size_t)(b*Cout + cog)*H + oh)*W + ow] = v;
        } else {
          out[((size_t)((ks*4 + b)*Cout + cog)*H + oh)*W + ow] = acc[mi][ni][rg];
        }
      }
    }
  }
}

// reduce split-K partials + bias + relu
__global__ __launch_bounds__(256) void sumk(const float* __restrict__ part, const float* __restrict__ bias,
                                            float* __restrict__ out, int Cout, int HW, int KS, int relu, int n){
  int idx = blockIdx.x*256 + threadIdx.x;
  if (idx >= n) return;
  int co = (idx / HW) % Cout;
  float v = bias[co];
  for (int k=0;k<KS;k++) v += part[(size_t)k*n + idx];
  if (relu) v = fmaxf(v, 0.f);
  out[idx] = v;
}

__global__ __launch_bounds__(256) void pool2k(const float* __restrict__ in, float* __restrict__ out,
                                              int n, int Ho, int Wo){
  int idx = blockIdx.x*256 + threadIdx.x;
  if (idx >= n) return;
  int wo = idx % Wo; int t = idx / Wo; int ho = t % Ho; int bc = t / Ho;
  const float* p = in + ((size_t)bc*(Ho*2) + ho*2)*(size_t)(Wo*2) + (size_t)wo*2;
  out[idx] = 0.25f*(p[0] + p[1] + p[2*Wo] + p[2*Wo+1]);
}

__global__ __launch_bounds__(256) void up2k(const float* __restrict__ in, float* __restrict__ out,
                                            int n, int Ho, int Wo){
  int idx = blockIdx.x*256 + threadIdx.x;
  if (idx >= n) return;
  int wo = idx % Wo; int t = idx / Wo; int ho = t % Ho; int bc = t / Ho;
  int Hi = Ho >> 1, Wi = Wo >> 1;
  out[idx] = in[((size_t)bc*Hi + (ho>>1))*Wi + (wo>>1)];
}

// per-(b,c) spatial mean & std (ddof=0)
__global__ __launch_bounds__(256) void statsk(const float* __restrict__ x, int HW,
                                              float* __restrict__ mo, float* __restrict__ so){
  int bc = blockIdx.x, tid = threadIdx.x;
  const float* p = x + (size_t)bc*HW;
  double s = 0.0, s2 = 0.0;
  for (int i = tid; i < HW; i += 256){ double v = p[i]; s += v; s2 += v*v; }
  __shared__ double sh[256], sh2[256];
  sh[tid] = s; sh2[tid] = s2; __syncthreads();
  for (int k=128;k>0;k>>=1){ if (tid<k){ sh[tid]+=sh[tid+k]; sh2[tid]+=sh2[tid+k]; } __syncthreads(); }
  if (tid == 0){
    double m = sh[0]/HW;
    double var = sh2[0]/HW - m*m;
    if (var < 0.0) var = 0.0;
    mo[bc] = (float)m;
    so[bc] = (float)sqrt(var);
  }
}

// f4 (C-major, per image 512x1024) -> ptsT [8][1024][512]
__global__ __launch_bounds__(256) void transposek(const float* __restrict__ f4c,
                                                  const float* __restrict__ f4s,
                                                  float* __restrict__ ptsT){
  __shared__ float t[32][33];
  int r = blockIdx.z;
  const float* src = (r < 4) ? (f4c + (size_t)r*524288) : (f4s + (size_t)(r-4)*524288);
  int n0 = blockIdx.x*32, c0 = blockIdx.y*32;
  int lx = threadIdx.x & 31, ly = threadIdx.x >> 5;
  for (int j=0;j<32;j+=8)
    t[ly+j][lx] = src[(size_t)(c0+ly+j)*1024 + n0+lx];
  __syncthreads();
  for (int j=0;j<32;j+=8)
    ptsT[((size_t)r*1024 + n0+ly+j)*512 + c0+lx] = t[lx][ly+j];
}

__global__ __launch_bounds__(256) void initcentk(const float* __restrict__ ptsT, float* __restrict__ cent){
  int i = blockIdx.x*256 + threadIdx.x;
  if (i >= 12288) return;
  int c = i & 511; int k = (i >> 9) % 3; int r = i / 1536;
  cent[i] = ptsT[((size_t)r*1024 + k)*512 + c];
}

// one wave per point; first-min argmin (matches jnp.argmin)
__global__ __launch_bounds__(256) void assignk(const float* __restrict__ ptsT,
                                               const float* __restrict__ cent, int* __restrict__ a){
  int gp = blockIdx.x*4 + (threadIdx.x >> 6);
  int lane = threadIdx.x & 63;
  int r = gp >> 10;
  const float* p = ptsT + (size_t)gp*512;
  const float* ce = cent + r*1536;
  float d0=0.f,d1=0.f,d2=0.f;
  #pragma unroll
  for (int i=0;i<8;i++){
    int c = lane + i*64;
    float v = p[c];
    float e0 = v - ce[c], e1 = v - ce[512+c], e2 = v - ce[1024+c];
    d0 = fmaf(e0,e0,d0); d1 = fmaf(e1,e1,d1); d2 = fmaf(e2,e2,d2);
  }
  #pragma unroll
  for (int off=32; off>0; off>>=1){
    d0 += __shfl_down(d0, off, 64);
    d1 += __shfl_down(d1, off, 64);
    d2 += __shfl_down(d2, off, 64);
  }
  if (lane == 0){
    int bi = 0; float bd = d0;
    if (d1 < bd){ bd = d1; bi = 1; }
    if (d2 < bd){ bd = d2; bi = 2; }
    a[gp] = bi;
  }
}

// parallel centroid update: grid (r=8, cc=16), 256 thr
template<int WRITE>
__global__ __launch_bounds__(256) void updatek(const float* __restrict__ ptsT,
                                               const int* __restrict__ a,
                                               float* __restrict__ dst,
                                               float* __restrict__ counts){
  int r = blockIdx.x, cc = blockIdx.y;
  int tid = threadIdx.x;
  int lane = tid & 31, p = tid >> 5;
  int c = cc*32 + lane;
  __shared__ int sa[1024];
  __shared__ int scnt[3];
  if (tid < 3) scnt[tid] = 0;
  for (int i = tid; i < 1024; i += 256) sa[i] = a[r*1024 + i];
  __syncthreads();
  {
    int l0=0,l1=0,l2=0;
    #pragma unroll
    for (int i=tid*4;i<tid*4+4;i++){ int an=sa[i]; l0+=(an==0); l1+=(an==1); l2+=(an==2); }
    if (l0) atomicAdd(&scnt[0], l0);
    if (l1) atomicAdd(&scnt[1], l1);
    if (l2) atomicAdd(&scnt[2], l2);
  }
  const float* base = ptsT + (size_t)r*524288;
  float s0=0.f,s1=0.f,s2=0.f;
  for (int n = p*128; n < p*128+128; ++n){
    float v = base[(size_t)n*512 + c];
    int an = sa[n];
    s0 += (an==0) ? v : 0.f;
    s1 += (an==1) ? v : 0.f;
    s2 += (an==2) ? v : 0.f;
  }
  __shared__ float red[8][3][32];
  red[p][0][lane]=s0; red[p][1][lane]=s1; red[p][2][lane]=s2;
  __syncthreads();
  if (p == 0){
    float t0=0.f,t1=0.f,t2=0.f;
    #pragma unroll
    for (int q=0;q<8;q++){ t0+=red[q][0][lane]; t1+=red[q][1][lane]; t2+=red[q][2][lane]; }
    float n0 = (float)scnt[0] + 1e-6f, n1 = (float)scnt[1] + 1e-6f, n2 = (float)scnt[2] + 1e-6f;
    if (WRITE == 0){
      dst[r*1536 + c]        = t0/n0;
      dst[r*1536 + 512 + c]  = t1/n1;
      dst[r*1536 + 1024 + c] = t2/n2;
    } else {
      int cs = r >> 2, img = r & 3;
      int i0 = cs*12 + img*3;
      dst[(size_t)(i0+0)*512 + c] = t0/n0;
      dst[(size_t)(i0+1)*512 + c] = t1/n1;
      dst[(size_t)(i0+2)*512 + c] = t2/n2;
      if (cc == 0 && lane == 0){
        counts[i0]   = (float)scnt[0];
        counts[i0+1] = (float)scnt[1];
        counts[i0+2] = (float)scnt[2];
      }
    }
  }
}

// masked centered split planes: P[z][c][n] = (a[n]==k) ? pts[c][n]-mu[z][c] : 0
__global__ __launch_bounds__(256) void maskcenterk(const float* __restrict__ f4c, const float* __restrict__ f4s,
        const int* __restrict__ a, const float* __restrict__ mu,
        u16* __restrict__ Ph, u16* __restrict__ Pl){
  size_t i4 = ((size_t)blockIdx.x*256 + threadIdx.x)*4;
  if (i4 >= (size_t)PL*2) return;   // total elems = 24*512*1024
  int z = (int)(i4 >> 19);
  int rc = (int)(i4 & 524287);
  int c = rc >> 10, n = rc & 1023;
  int cs = z / 12; int rem = z - cs*12; int img = rem / 3; int k = rem - img*3;
  const float* pts = (cs ? f4s : f4c) + (size_t)img*524288;
  float m = mu[(size_t)z*512 + c];
  const int* an = a + (cs*4 + img)*1024 + n;
  float4 v4 = *(const float4*)&pts[(size_t)c*1024 + n];
  float vv[4] = {v4.x, v4.y, v4.z, v4.w};
  u16x4 oh, ol;
  #pragma unroll
  for (int j=0;j<4;j++){
    float v = (an[j] == k) ? (vv[j] - m) : 0.f;
    u16 h = bf16_rne(v);
    oh[j] = (short)h;
    ol[j] = (short)bf16_rne(v - bf16f(h));
  }
  *(u16x4*)&Ph[i4] = oh;
  *(u16x4*)&Pl[i4] = ol;
}

// covariance via MFMA: Ycov[z] = P[z] @ P[z]^T / nc + 0.1 I   (K=1024)
__global__ __launch_bounds__(256) void covgemm(const u16* __restrict__ Ph, const u16* __restrict__ Pl,
        const float* __restrict__ counts, float* __restrict__ Ycov){
  const int z = blockIdx.z;
  const u16* Pbh = Ph + (size_t)z*524288;
  const u16* Pbl = Pl + (size_t)z*524288;
  const int m0 = blockIdx.y*128, n0 = blockIdx.x*128;
  const int tid = threadIdx.x;

  __shared__ __align__(16) u16 sAh[128*40], sAl[128*40];
  __shared__ __align__(16) u16 sBh[128*40], sBl[128*40];

  const int ra = tid >> 2, qa = tid & 3;
  const int wid = tid >> 6, lane = tid & 63;
  const int wm = wid >> 1, wn = wid & 1;
  const int quad = lane >> 4, ln = lane & 15;

  f32x4 acc[4][4];
  #pragma unroll
  for (int i=0;i<4;i++)
    #pragma unroll
    for (int j=0;j<4;j++)
      #pragma unroll
      for (int e=0;e<4;e++) acc[i][j][e] = 0.f;

  for (int k0 = 0; k0 < 1024; k0 += 32){
    *(bf16x8*)&sAh[ra*40 + qa*8]      = *(const bf16x8*)&Pbh[(size_t)(m0+ra)*1024    + k0 + qa*8];
    *(bf16x8*)&sAl[ra*40 + qa*8]      = *(const bf16x8*)&Pbl[(size_t)(m0+ra)*1024    + k0 + qa*8];
    *(bf16x8*)&sAh[(ra+64)*40 + qa*8] = *(const bf16x8*)&Pbh[(size_t)(m0+ra+64)*1024 + k0 + qa*8];
    *(bf16x8*)&sAl[(ra+64)*40 + qa*8] = *(const bf16x8*)&Pbl[(size_t)(m0+ra+64)*1024 + k0 + qa*8];
    *(bf16x8*)&sBh[ra*40 + qa*8]      = *(const bf16x8*)&Pbh[(size_t)(n0+ra)*1024    + k0 + qa*8];
    *(bf16x8*)&sBl[ra*40 + qa*8]      = *(const bf16x8*)&Pbl[(size_t)(n0+ra)*1024    + k0 + qa*8];
    *(bf16x8*)&sBh[(ra+64)*40 + qa*8] = *(const bf16x8*)&Pbh[(size_t)(n0+ra+64)*1024 + k0 + qa*8];
    *(bf16x8*)&sBl[(ra+64)*40 + qa*8] = *(const bf16x8*)&Pbl[(size_t)(n0+ra+64)*1024 + k0 + qa*8];
    __syncthreads();

    bf16x8 ah[4], al[4], bh[4], bl[4];
    #pragma unroll
    for (int t=0;t<4;t++){
      const int moA = ((wm*4+t)*16 + ln)*40 + quad*8;
      const int moB = ((wn*4+t)*16 + ln)*40 + quad*8;
      ah[t] = *(const bf16x8*)&sAh[moA];
      al[t] = *(const bf16x8*)&sAl[moA];
      bh[t] = *(const bf16x8*)&sBh[moB];
      bl[t] = *(const bf16x8*)&sBl[moB];
    }
    #pragma unroll
    for (int mi=0;mi<4;mi++)
      #pragma unroll
      for (int ni=0;ni<4;ni++){
        acc[mi][ni] = __builtin_amdgcn_mfma_f32_16x16x32_bf16(ah[mi], bh[ni], acc[mi][ni], 0, 0, 0);
        acc[mi][ni] = __builtin_amdgcn_mfma_f32_16x16x32_bf16(ah[mi], bl[ni], acc[mi][ni], 0, 0, 0);
        acc[mi][ni] = __builtin_amdgcn_mfma_f32_16x16x32_bf16(al[mi], bh[ni], acc[mi][ni], 0, 0, 0);
      }
    __syncthreads();
  }
  const float inv = 1.f/(counts[z] + 1e-6f);
  #pragma unroll
  for (int mi=0;mi<4;mi++){
    const int mbase = m0 + (wm*4+mi)*16 + quad*4;
    #pragma unroll
    for (int ni=0;ni<4;ni++){
      const int n = n0 + (wn*4+ni)*16 + ln;
      #pragma unroll
      for (int rg=0;rg<4;rg++){
        const int m = mbase + rg;
        Ycov[(size_t)z*MSZ + (size_t)m*512 + n] = acc[mi][ni][rg]*inv + ((m==n)?0.1f:0.f);
      }
    }
  }
}

// power iteration for lambda_max
__global__ __launch_bounds__(256) void powk(const float* __restrict__ Y, float* __restrict__ sval){
  int z = blockIdx.x, tid = threadIdx.x;
  const float* M = Y + (size_t)z*MSZ;
  __shared__ float v[512];
  __shared__ float red[256];
  __shared__ float nrmsh;
  v[tid] = 1.f; v[tid+256] = 1.f;
  __syncthreads();
  float lastn = 0.1f;
  for (int it=0; it<10; ++it){
    float y0=0.f, y1=0.f;
    for (int c=0;c<512;c++){
      float vc = v[c];
      y0 = fmaf(M[(size_t)c*512 + tid      ], vc, y0);
      y1 = fmaf(M[(size_t)c*512 + tid + 256], vc, y1);
    }
    red[tid] = y0*y0 + y1*y1;
    __syncthreads();
    for (int s=128;s>0;s>>=1){ if (tid<s) red[tid]+=red[tid+s]; __syncthreads(); }
    if (tid==0) nrmsh = sqrtf(red[0]) + 1e-30f;
    __syncthreads();
    float nrm = nrmsh;
    v[tid] = y0/nrm; v[tid+256] = y1/nrm;
    lastn = nrm;
    __syncthreads();
  }
  if (tid==0) sval[z] = lastn*1.05f + 1e-12f;
}

// init split planes: Y = Ycov/s (hi+lo bf16), Z = I
__global__ __launch_bounds__(256) void nsinitk(const float* __restrict__ Ycov, const float* __restrict__ sval,
                                               u16* __restrict__ Yh, u16* __restrict__ Yl,
                                               u16* __restrict__ Zh, u16* __restrict__ Zl){
  size_t idx = (size_t)blockIdx.x*256 + threadIdx.x;
  if (idx >= (size_t)PL) return;
  int z = (int)(idx >> 18);
  int rc = (int)(idx & (MSZ-1));
  int rr = rc >> 9, cc = rc & 511;
  float y = Ycov[idx] / sval[z];
  u16 h = bf16_rne(y);
  Yh[idx] = h;
  Yl[idx] = bf16_rne(y - bf16f(h));
  Zh[idx] = (rr==cc) ? (u16)0x3F80 : (u16)0;
  Zl[idx] = 0;
}

// trace-scaled NS factors from split M: g = min(512/tr, 2.7); os = sqrt(g)/2
__global__ __launch_bounds__(256) void scalek(const u16* __restrict__ Mh, const u16* __restrict__ Ml,
                                              float* __restrict__ g, float* __restrict__ os){
  int z = blockIdx.x, tid = threadIdx.x;
  const u16* H = Mh + (size_t)z*MSZ;
  const u16* L = Ml + (size_t)z*MSZ;
  float s = bf16f(H[(size_t)tid*513]) + bf16f(L[(size_t)tid*513])
          + bf16f(H[(size_t)(tid+256)*513]) + bf16f(L[(size_t)(tid+256)*513]);
  __shared__ float sh[256];
  sh[tid] = s; __syncthreads();
  for (int k=128;k>0;k>>=1){ if (tid<k) sh[tid]+=sh[tid+k]; __syncthreads(); }
  if (tid==0){
    float tr = fmaxf(sh[0], 1e-6f);
    float g2 = fminf(512.f/tr, 2.7f);
    g[z] = g2;
    os[z] = 0.5f*sqrtf(g2);
  }
}

// ---- split-bf16 MFMA batched GEMM 512x512x512 ----
// SYMB=1: B symmetric -> stage B^T tile as contiguous B rows
// MODE 0: C = A@B ; MODE 1: C = os*(3*D - g*(A@B)) ; MODE 2: C = osc*(A@B)
template<int MODE, int SYMB>
__global__ __launch_bounds__(256) void bmms(
    const u16* __restrict__ Ah, const u16* __restrict__ Al,
    const u16* __restrict__ Bh, const u16* __restrict__ Bl,
    const u16* __restrict__ Dh, const u16* __restrict__ Dl,
    u16* __restrict__ Ch, u16* __restrict__ Cl,
    const float* __restrict__ gam, const float* __restrict__ osc,
    int aoff)
{
  const int z = blockIdx.z;
  const u16* Abh = Ah + (size_t)(z+aoff)*MSZ;
  const u16* Abl = Al + (size_t)(z+aoff)*MSZ;
  const u16* Bbh = Bh + (size_t)z*MSZ;
  const u16* Bbl = Bl + (size_t)z*MSZ;
  const int m0 = blockIdx.y*128, n0 = blockIdx.x*128;
  const int tid = threadIdx.x;

  __shared__ __align__(16) u16 sAh[128*40], sAl[128*40];
  __shared__ __align__(16) u16 sBh[128*40], sBl[128*40];

  const int ra = tid >> 2, qa = tid & 3;
  const int kb = tid >> 4, gb = tid & 15;

  const int wid = tid >> 6, lane = tid & 63;
  const int wm = wid >> 1, wn = wid & 1;
  const int quad = lane >> 4, ln = lane & 15;

  f32x4 acc[4][4];
  #pragma unroll
  for (int i=0;i<4;i++)
    #pragma unroll
    for (int j=0;j<4;j++)
      #pragma unroll
      for (int e=0;e<4;e++) acc[i][j][e] = 0.f;

  for (int k0 = 0; k0 < 512; k0 += 32){
    *(bf16x8*)&sAh[ra*40 + qa*8]      = *(const bf16x8*)&Abh[(size_t)(m0+ra)*512    + k0 + qa*8];
    *(bf16x8*)&sAl[ra*40 + qa*8]      = *(const bf16x8*)&Abl[(size_t)(m0+ra)*512    + k0 + qa*8];
    *(bf16x8*)&sAh[(ra+64)*40 + qa*8] = *(const bf16x8*)&Abh[(size_t)(m0+ra+64)*512 + k0 + qa*8];
    *(bf16x8*)&sAl[(ra+64)*40 + qa*8] = *(const bf16x8*)&Abl[(size_t)(m0+ra+64)*512 + k0 + qa*8];
    if constexpr (SYMB){
      *(bf16x8*)&sBh[ra*40 + qa*8]      = *(const bf16x8*)&Bbh[(size_t)(n0+ra)*512    + k0 + qa*8];
      *(bf16x8*)&sBl[ra*40 + qa*8]      = *(const bf16x8*)&Bbl[(size_t)(n0+ra)*512    + k0 + qa*8];
      *(bf16x8*)&sBh[(ra+64)*40 + qa*8] = *(const bf16x8*)&Bbh[(size_t)(n0+ra+64)*512 + k0 + qa*8];
      *(bf16x8*)&sBl[(ra+64)*40 + qa*8] = *(const bf16x8*)&Bbl[(size_t)(n0+ra+64)*512 + k0 + qa*8];
    } else {
      bf16x8 vh = *(const bf16x8*)&Bbh[(size_t)(k0+kb)*512 + n0 + gb*8];
      bf16x8 vl = *(const bf16x8*)&Bbl[(size_t)(k0+kb)*512 + n0 + gb*8];
      #pragma unroll
      for (int j=0;j<8;j++){
        sBh[(gb*8+j)*40 + kb] = (u16)vh[j];
        sBl[(gb*8+j)*40 + kb] = (u16)vl[j];
      }
      vh = *(const bf16x8*)&Bbh[(size_t)(k0+kb+16)*512 + n0 + gb*8];
      vl = *(const bf16x8*)&Bbl[(size_t)(k0+kb+16)*512 + n0 + gb*8];
      #pragma unroll
      for (int j=0;j<8;j++){
        sBh[(gb*8+j)*40 + kb+16] = (u16)vh[j];
        sBl[(gb*8+j)*40 + kb+16] = (u16)vl[j];
      }
    }
    __syncthreads();

    bf16x8 ah[4], al[4], bh[4], bl[4];
    #pragma unroll
    for (int t=0;t<4;t++){
      const int moA = ((wm*4+t)*16 + ln)*40 + quad*8;
      const int moB = ((wn*4+t)*16 + ln)*40 + quad*8;
      ah[t] = *(const bf16x8*)&sAh[moA];
      al[t] = *(const bf16x8*)&sAl[moA];
      bh[t] = *(const bf16x8*)&sBh[moB];
      bl[t] = *(const bf16x8*)&sBl[moB];
    }
    #pragma unroll
    for (int mi=0;mi<4;mi++)
      #pragma unroll
      for (int ni=0;ni<4;ni++){
        acc[mi][ni] = __builtin_amdgcn_mfma_f32_16x16x32_bf16(ah[mi], bh[ni], acc[mi][ni], 0, 0, 0);
        acc[mi][ni] = __builtin_amdgcn_mfma_f32_16x16x32_bf16(ah[mi], bl[ni], acc[mi][ni], 0, 0, 0);
        acc[mi][ni] = __builtin_amdgcn_mfma_f32_16x16x32_bf16(al[mi], bh[ni], acc[mi][ni], 0, 0, 0);
      }
    __syncthreads();
  }

  float alpha = 1.f, beta = 0.f;
  if constexpr (MODE==1){ float gz = gam[z], oz = osc[z]; alpha = -gz*oz; beta = 3.f*oz; }
  if constexpr (MODE==2){ alpha = osc[z]; }

  #pragma unroll
  for (int mi=0;mi<4;mi++){
    const int mbase = m0 + (wm*4+mi)*16 + quad*4;
    #pragma unroll
    for (int ni=0;ni<4;ni++){
      const int n = n0 + (wn*4+ni)*16 + ln;
      #pragma unroll
      for (int rg=0;rg<4;rg++){
        const int m = mbase + rg;
        const size_t off = (size_t)z*MSZ + (size_t)m*512 + n;
        float v = alpha*acc[mi][ni][rg];
        if constexpr (MODE==1)
          v += beta*(bf16f(Dh[off]) + bf16f(Dl[off]));
        u16 h = bf16_rne(v);
        Ch[off] = h;
        Cl[off] = bf16_rne(v - bf16f(h));
      }
    }
  }
}

// merged NS update: z<24 -> Y2 = os*(3Y - g*(Y@M)); z>=24 -> Z2 = os*(3Z - g*(M@Z))
// all operands symmetric -> row-staged B^T tiles
__global__ __launch_bounds__(256) void bmmpair(
    const u16* __restrict__ Yh, const u16* __restrict__ Yl,
    const u16* __restrict__ Mh, const u16* __restrict__ Ml,
    const u16* __restrict__ Zh, const u16* __restrict__ Zl,
    u16* __restrict__ Y2h, u16* __restrict__ Y2l,
    u16* __restrict__ Z2h, u16* __restrict__ Z2l,
    const float* __restrict__ gam, const float* __restrict__ osc)
{
  const int z = blockIdx.z;
  const int zz = (z < 24) ? z : (z - 24);
  const size_t zo = (size_t)zz*MSZ;
  const u16 *Abh, *Abl, *Bbh, *Bbl, *Dbh, *Dbl;
  u16 *Cbh, *Cbl;
  if (z < 24){
    Abh = Yh + zo; Abl = Yl + zo;
    Bbh = Mh + zo; Bbl = Ml + zo;
    Dbh = Yh + zo; Dbl = Yl + zo;
    Cbh = Y2h + zo; Cbl = Y2l + zo;
  } else {
    Abh = Mh + zo; Abl = Ml + zo;
    Bbh = Zh + zo; Bbl = Zl + zo;
    Dbh = Zh + zo; Dbl = Zl + zo;
    Cbh = Z2h + zo; Cbl = Z2l + zo;
  }
  const int m0 = blockIdx.y*128, n0 = blockIdx.x*128;
  const int tid = threadIdx.x;

  __shared__ __align__(16) u16 sAh[128*40], sAl[128*40];
  __shared__ __align__(16) u16 sBh[128*40], sBl[128*40];

  const int ra = tid >> 2, qa = tid & 3;
  const int wid = tid >> 6, lane = tid & 63;
  const int wm = wid >> 1, wn = wid & 1;
  const int quad = lane >> 4, ln = lane & 15;

  f32x4 acc[4][4];
  #pragma unroll
  for (int i=0;i<4;i++)
    #pragma unroll
    for (int j=0;j<4;j++)
      #pragma unroll
      for (int e=0;e<4;e++) acc[i][j][e] = 0.f;

  for (int k0 = 0; k0 < 512; k0 += 32){
    *(bf16x8*)&sAh[ra*40 + qa*8]      = *(const bf16x8*)&Abh[(size_t)(m0+ra)*512    + k0 + qa*8];
    *(bf16x8*)&sAl[ra*40 + qa*8]      = *(const bf16x8*)&Abl[(size_t)(m0+ra)*512    + k0 + qa*8];
    *(bf16x8*)&sAh[(ra+64)*40 + qa*8] = *(const bf16x8*)&Abh[(size_t)(m0+ra+64)*512 + k0 + qa*8];
    *(bf16x8*)&sAl[(ra+64)*40 + qa*8] = *(const bf16x8*)&Abl[(size_t)(m0+ra+64)*512 + k0 + qa*8];
    *(bf16x8*)&sBh[ra*40 + qa*8]      = *(const bf16x8*)&Bbh[(size_t)(n0+ra)*512    + k0 + qa*8];
    *(bf16x8*)&sBl[ra*40 + qa*8]      = *(const bf16x8*)&Bbl[(size_t)(n0+ra)*512    + k0 + qa*8];
    *(bf16x8*)&sBh[(ra+64)*40 + qa*8] = *(const bf16x8*)&Bbh[(size_t)(n0+ra+64)*512 + k0 + qa*8];
    *(bf16x8*)&sBl[(ra+64)*40 + qa*8] = *(const bf16x8*)&Bbl[(size_t)(n0+ra+64)*512 + k0 + qa*8];
    __syncthreads();

    bf16x8 ah[4], al[4], bh[4], bl[4];
    #pragma unroll
    for (int t=0;t<4;t++){
      const int moA = ((wm*4+t)*16 + ln)*40 + quad*8;
      const int moB = ((wn*4+t)*16 + ln)*40 + quad*8;
      ah[t] = *(const bf16x8*)&sAh[moA];
      al[t] = *(const bf16x8*)&sAl[moA];
      bh[t] = *(const bf16x8*)&sBh[moB];
      bl[t] = *(const bf16x8*)&sBl[moB];
    }
    #pragma unroll
    for (int mi=0;mi<4;mi++)
      #pragma unroll
      for (int ni=0;ni<4;ni++){
        acc[mi][ni] = __builtin_amdgcn_mfma_f32_16x16x32_bf16(ah[mi], bh[ni], acc[mi][ni], 0, 0, 0);
        acc[mi][ni] = __builtin_amdgcn_mfma_f32_16x16x32_bf16(ah[mi], bl[ni], acc[mi][ni], 0, 0, 0);
        acc[mi][ni] = __builtin_amdgcn_mfma_f32_16x16x32_bf16(al[mi], bh[ni], acc[mi][ni], 0, 0, 0);
      }
    __syncthreads();
  }

  const float gz = gam[zz], oz = osc[zz];
  const float alpha = -gz*oz, beta = 3.f*oz;

  #pragma unroll
  for (int mi=0;mi<4;mi++){
    const int mbase = m0 + (wm*4+mi)*16 + quad*4;
    #pragma unroll
    for (int ni=0;ni<4;ni++){
      const int n = n0 + (wn*4+ni)*16 + ln;
      #pragma unroll
      for (int rg=0;rg<4;rg++){
        const int m = mbase + rg;
        const size_t off = (size_t)m*512 + n;
        float v = alpha*acc[mi][ni][rg] + beta*(bf16f(Dbh[off]) + bf16f(Dbl[off]));
        u16 h = bf16_rne(v);
        Cbh[off] = h;
        Cbl[off] = bf16_rne(v - bf16f(h));
      }
    }
  }
}

// tpts = T[z] @ f[img]: M=512, N=1024, K=512, fp32 out (f non-symmetric: transpose-staged)
__global__ __launch_bounds__(256) void bmmt(
    const u16* __restrict__ Th, const u16* __restrict__ Tl,
    const u16* __restrict__ fh, const u16* __restrict__ fl,
    float* __restrict__ Cf)
{
  const int z = blockIdx.z;
  const u16* Abh = Th + (size_t)z*MSZ;
  const u16* Abl = Tl + (size_t)z*MSZ;
  const u16* Bbh = fh + (size_t)(z/3)*524288;
  const u16* Bbl = fl + (size_t)(z/3)*524288;
  const int m0 = blockIdx.y*128, n0 = blockIdx.x*128;
  const int tid = threadIdx.x;

  __shared__ __align__(16) u16 sAh[128*40], sAl[128*40];
  __shared__ __align__(16) u16 sBh[128*40], sBl[128*40];

  const int ra = tid >> 2, qa = tid & 3;
  const int kb = tid >> 4, gb = tid & 15;
  const int wid = tid >> 6, lane = tid & 63;
  const int wm = wid >> 1, wn = wid & 1;
  const int quad = lane >> 4, ln = lane & 15;

  f32x4 acc[4][4];
  #pragma unroll
  for (int i=0;i<4;i++)
    #pragma unroll
    for (int j=0;j<4;j++)
      #pragma unroll
      for (int e=0;e<4;e++) acc[i][j][e] = 0.f;

  for (int k0 = 0; k0 < 512; k0 += 32){
    *(bf16x8*)&sAh[ra*40 + qa*8]      = *(const bf16x8*)&Abh[(size_t)(m0+ra)*512    + k0 + qa*8];
    *(bf16x8*)&sAl[ra*40 + qa*8]      = *(const bf16x8*)&Abl[(size_t)(m0+ra)*512    + k0 + qa*8];
    *(bf16x8*)&sAh[(ra+64)*40 + qa*8] = *(const bf16x8*)&Abh[(size_t)(m0+ra+64)*512 + k0 + qa*8];
    *(bf16x8*)&sAl[(ra+64)*40 + qa*8] = *(const bf16x8*)&Abl[(size_t)(m0+ra+64)*512 + k0 + qa*8];
    {
      bf16x8 vh = *(const bf16x8*)&Bbh[(size_t)(k0+kb)*1024 + n0 + gb*8];
      bf16x8 vl = *(const bf16x8*)&Bbl[(size_t)(k0+kb)*1024 + n0 + gb*8];
      #pragma unroll
      for (int j=0;j<8;j++){
        sBh[(gb*8+j)*40 + kb] = (u16)vh[j];
        sBl[(gb*8+j)*40 + kb] = (u16)vl[j];
      }
      vh = *(const bf16x8*)&Bbh[(size_t)(k0+kb+16)*1024 + n0 + gb*8];
      vl = *(const bf16x8*)&Bbl[(size_t)(k0+kb+16)*1024 + n0 + gb*8];
      #pragma unroll
      for (int j=0;j<8;j++){
        sBh[(gb*8+j)*40 + kb+16] = (u16)vh[j];
        sBl[(gb*8+j)*40 + kb+16] = (u16)vl[j];
      }
    }
    __syncthreads();

    bf16x8 ah[4], al[4], bh[4], bl[4];
    #pragma unroll
    for (int t=0;t<4;t++){
      const int moA = ((wm*4+t)*16 + ln)*40 + quad*8;
      const int moB = ((wn*4+t)*16 + ln)*40 + quad*8;
      ah[t] = *(const bf16x8*)&sAh[moA];
      al[t] = *(const bf16x8*)&sAl[moA];
      bh[t] = *(const bf16x8*)&sBh[moB];
      bl[t] = *(const bf16x8*)&sBl[moB];
    }
    #pragma unroll
    for (int mi=0;mi<4;mi++)
      #pragma unroll
      for (int ni=0;ni<4;ni++){
        acc[mi][ni] = __builtin_amdgcn_mfma_f32_16x16x32_bf16(ah[mi], bh[ni], acc[mi][ni], 0, 0, 0);
        acc[mi][ni] = __builtin_amdgcn_mfma_f32_16x16x32_bf16(ah[mi], bl[ni], acc[mi][ni], 0, 0, 0);
        acc[mi][ni] = __builtin_amdgcn_mfma_f32_16x16x32_bf16(al[mi], bh[ni], acc[mi][ni], 0, 0, 0);
      }
    __syncthreads();
  }
  #pragma unroll
  for (int mi=0;mi<4;mi++){
    const int mbase = m0 + (wm*4+mi)*16 + quad*4;
    #pragma unroll
    for (int ni=0;ni<4;ni++){
      const int n = n0 + (wn*4+ni)*16 + ln;
      #pragma unroll
      for (int rg=0;rg<4;rg++){
        const int m = mbase + rg;
        Cf[(size_t)z*524288 + (size_t)m*1024 + n] = acc[mi][ni][rg];
      }
    }
  }
}

// generic fp32 -> split bf16
__global__ __launch_bounds__(256) void splitk(const float* __restrict__ src,
                                              u16* __restrict__ dh, u16* __restrict__ dl, int n4){
  int i = blockIdx.x*256 + threadIdx.x;
  if (i >= n4) return;
  float4 v4 = *(const float4*)&src[(size_t)i*4];
  float vv[4] = {v4.x, v4.y, v4.z, v4.w};
  u16x4 oh, ol;
  #pragma unroll
  for (int j=0;j<4;j++){
    u16 h = bf16_rne(vv[j]);
    oh[j] = (short)h;
    ol[j] = (short)bf16_rne(vv[j] - bf16f(h));
  }
  *(u16x4*)&dh[(size_t)i*4] = oh;
  *(u16x4*)&dl[(size_t)i*4] = ol;
}

__global__ void make_scalesk(const float* __restrict__ sval, float* __restrict__ scl){
  int i = threadIdx.x;
  if (i < 12) scl[i] = sqrtf(sval[12+i] / sval[i]);
}

// tvec[b] = mu_s[b] - T[b] @ mu_c[b]   (T in split form)
__global__ __launch_bounds__(512) void tveck(const u16* __restrict__ Th, const u16* __restrict__ Tl,
                                             const float* __restrict__ mu, float* __restrict__ tvec){
  int b = blockIdx.x; int c = threadIdx.x;
  __shared__ float mc[512];
  mc[c] = mu[(size_t)b*512 + c];
  __syncthreads();
  const u16* Trh = Th + ((size_t)b*512 + c)*512;
  const u16* Trl = Tl + ((size_t)b*512 + c)*512;
  float s = 0.f;
  for (int d=0; d<512; d++) s = fmaf(bf16f(Trh[d]) + bf16f(Trl[d]), mc[d], s);
  tvec[b*512 + c] = mu[(size_t)(12+b)*512 + c] - s;
}

__global__ __launch_bounds__(256) void selectk(const float* __restrict__ tpts, const float* __restrict__ tvec,
        const int* __restrict__ a, const float* __restrict__ f4c, float* __restrict__ tf){
  size_t idx = (size_t)blockIdx.x*256 + threadIdx.x;
  if (idx >= 2097152ul) return;
  int n = (int)(idx & 1023);
  int c = (int)((idx >> 10) & 511);
  int img = (int)(idx >> 19);
  int k = a[img*1024 + n];
  int b = img*3 + k;
  float v = tpts[((size_t)b*512 + c)*1024 + n] + tvec[b*512 + c];
  tf[idx] = 0.6f*v + 0.4f*f4c[idx];
}

__global__ __launch_bounds__(256) void clossk(const float* __restrict__ x, const float* __restrict__ y,
                                              int n, float* __restrict__ acc){
  int tid = threadIdx.x;
  float s = 0.f;
  for (size_t i = (size_t)blockIdx.x*256 + tid; i < (size_t)n; i += (size_t)gridDim.x*256){
    float d = x[i] - y[i]; s = fmaf(d, d, s);
  }
  __shared__ float sh[256];
  sh[tid] = s; __syncthreads();
  for (int k=128;k>0;k>>=1){ if (tid<k) sh[tid]+=sh[tid+k]; __syncthreads(); }
  if (tid==0) atomicAdd(acc, sh[0]);
}

__global__ __launch_bounds__(256) void finalk(const float* __restrict__ sm, float* __restrict__ out){
  int tid = threadIdx.x;
  const int cnts[4] = {256,512,1024,2048};
  const int offs[4] = {0,256,768,1792};
  const float* mS = sm + SM_STATS_S;
  const float* sS = sm + SM_STATS_S + 3840;
  const float* mD = sm + SM_STATS_D;
  const float* sD = sm + SM_STATS_D + 3840;
  double sl = 0.0;
  for (int L=0; L<4; ++L){
    int cnt = cnts[L], off = offs[L];
    double inv = 1.0/cnt;
    for (int i=tid; i<cnt; i+=256){
      double dm = (double)mD[off+i] - (double)mS[off+i];
      double ds = (double)sD[off+i] - (double)sS[off+i];
      sl += (dm*dm + ds*ds)*inv;
    }
  }
  __shared__ double sh[256];
  sh[tid] = sl; __syncthreads();
  for (int k=128;k>0;k>>=1){ if (tid<k) sh[tid]+=sh[tid+k]; __syncthreads(); }
  if (tid==0){
    double closs = (double)sm[SM_CLOSS] / 2097152.0;
    out[0] = (float)(closs + 0.01*sh[0]);
  }
}

// ---------------- host ----------------

extern "C" void kernel_launch(void* const* d_in, const int* in_sizes, int n_in,
                              void* d_out, int out_size, void* d_ws, size_t ws_size,
                              hipStream_t stream)
{
  const float* content = (const float*)d_in[0];
  const float* style   = (const float*)d_in[1];
  const float* Wm[8]; const float* Bm[8];
  for (int i=0;i<8;i++){ Wm[i] = (const float*)d_in[2+2*i]; Bm[i] = (const float*)d_in[3+2*i]; }
  float* out = (float*)d_out;
  float* ws = (float*)d_ws;

  float* f4c  = ws + OFF_F4C;
  float* f4s  = ws + OFF_F4S;
  float* tf   = ws + OFF_TF;
  float* dec  = ws + OFF_DEC;
  float* sm   = ws + OFF_SMALL;
  float* AR   = ws + OFF_ARENA;
  int*   aPtr = (int*)(sm + SM_ASSIGN);
  float* cent = sm + SM_CENT;
  float* mu   = sm + SM_MU;
  float* counts = sm + SM_COUNTS;
  float* sval = sm + SM_SVAL;
  float* scl  = sm + SM_SCALE;
  float* tvec = sm + SM_TVEC;
  float* gbuf = sm + SM_G;
  float* obuf = sm + SM_OS;

  // pre-split weights region
  u16* WB = (u16*)(ws + OFF_WSPL);
  u16 *w2h=WB+0,       *w2l=WB+73728;    // e2: 9*128*64
  u16 *w3h=WB+147456,  *w3l=WB+442368;   // e3: 9*256*128
  u16 *w4h=WB+737280,  *w4l=WB+1916928;  // e4: 9*512*256
  u16 *v1h=WB+3096576, *v1l=WB+4276224;  // d1: 9*256*512
  u16 *v2h=WB+5455872, *v2l=WB+5750784;  // d2: 9*128*256
  u16 *v3h=WB+6045696, *v3l=WB+6119424;  // d3: 9*64*128

  float* Ycov = AR;
  u16* Mh  = (u16*)(AR);
  u16* Ml  = (u16*)(AR + 3145728ul);
  u16* Yh  = (u16*)(AR + 6291456ul);
  u16* Yl  = (u16*)(AR + 9437184ul);
  u16* Zh  = (u16*)(AR + 12582912ul);
  u16* Zl  = (u16*)(AR + 15728640ul);
  u16* Y2h = (u16*)(AR + 18874368ul);
  u16* Y2l = (u16*)(AR + 22020096ul);
  u16* Z2h = (u16*)(AR + 25165824ul);
  u16* Z2l = (u16*)(AR + 28311552ul);
  u16* Ph  = (u16*)(AR + 18874368ul);   // aliases Y2 (dead before NS)
  u16* Pl  = (u16*)(AR + 25165824ul);   // aliases Z2
  float* ptsT = AR + 25165824ul;        // dead before maskcenterk writes Pl
  u16* Th  = (u16*)(AR + 18874368ul);   // post-NS (Y2/Z2 free)
  u16* Tl  = (u16*)(AR + 20971520ul);
  u16* fsh = (u16*)(AR + 23068672ul);
  u16* fsl = (u16*)(AR + 24117248ul);

  // split-K partial buffers (fp32, transient)
  float* PARTA = AR + 2097152ul;   // 4.2M floats: e4 (KS=2) & d1 (KS=4)
  float* PARTB = AR + 7340032ul;   // 4.2M floats: d2 (KS=2)

  zerok<<<512,256,0,stream>>>(sm, 131072);

  // pre-split mid-layer weights
  {
    auto wsp = [&](int li, u16* wh, u16* wl, int Co, int Ci){
      int n = 9*Co*Ci;
      wsplitk<<<(n+255)/256,256,0,stream>>>(Wm[li], wh, wl, Co, Ci);
    };
    wsp(1,w2h,w2l,128,64);
    wsp(2,w3h,w3l,256,128);
    wsp(3,w4h,w4l,512,256);
    wsp(4,v1h,v1l,256,512);
    wsp(5,v2h,v2l,128,256);
    wsp(6,v3h,v3l,64,128);
  }

  auto conv = [&](const float* inp, int li, float* outp, int Ci,int Co,int H,int Wd,int relu,int cot){
    dim3 g((H>>5)*(Wd>>5), (Co + cot - 1)/cot, 4);
    if (cot==8) conv3x3<8><<<g,256,0,stream>>>(inp,Wm[li],Bm[li],outp,4,Ci,Co,H,Wd,relu);
    else        conv3x3<4><<<g,256,0,stream>>>(inp,Wm[li],Bm[li],outp,4,Ci,Co,H,Wd,relu);
  };
  auto convM = [&](const float* inp, int li, float* outp, int Ci,int Co,int H,int Wd,int relu,int KS,float* part){
    const u16 *wh=nullptr,*wl=nullptr;
    switch(li){
      case 1: wh=w2h; wl=w2l; break;
      case 2: wh=w3h; wl=w3l; break;
      case 3: wh=w4h; wl=w4l; break;
      case 4: wh=v1h; wl=v1l; break;
      case 5: wh=v2h; wl=v2l; break;
      case 6: wh=v3h; wl=v3l; break;
    }
    int tiles = (H>>3)*(Wd>>3);
    if (KS==1){
      convm<1><<<dim3(tiles,Co>>6,4),256,0,stream>>>(inp,wh,wl,Bm[li],outp,Ci,Co,H,Wd,relu);
    } else {
      int n = 4*Co*H*Wd;
      if (KS==2) convm<2><<<dim3(tiles,Co>>6,8),256,0,stream>>>(inp,wh,wl,nullptr,part,Ci,Co,H,Wd,relu);
      else       convm<4><<<dim3(tiles,Co>>6,16),256,0,stream>>>(inp,wh,wl,nullptr,part,Ci,Co,H,Wd,relu);
      sumk<<<(n+255)/256,256,0,stream>>>(part,Bm[li],outp,Co,H*Wd,KS,relu,n);
    }
  };
  auto pool = [&](const float* inp, float* outp, int C,int Ho,int Wo){
    int n = 4*C*Ho*Wo;
    pool2k<<<(n+255)/256,256,0,stream>>>(inp,outp,n,Ho,Wo);
  };
  auto up = [&](const float* inp, float* outp, int C,int Ho,int Wo){
    int n = 4*C*Ho*Wo;
    up2k<<<(n+255)/256,256,0,stream>>>(inp,outp,n,Ho,Wo);
  };

  // encode scratch (arena)
  float* F1 = AR + 0;
  float* P1 = AR + 16777216ul;
  float* F2 = AR + 0;
  float* P2 = AR + 8388608ul;
  float* F3 = AR + 10485760ul;
  float* P3 = AR + 0;

  // ---- content encode ----
  conv(content, 0, F1, 3,64,256,256,1,8);
  pool(F1,P1,64,128,128);
  convM(P1,1,F2, 64,128,128,128,1,1,nullptr);
  pool(F2,P2,128,64,64);
  convM(P2,2,F3, 128,256,64,64,1,1,nullptr);
  pool(F3,P3,256,32,32);
  convM(P3,3,f4c, 256,512,32,32,1,2,PARTA);

  // ---- style encode + stats ----
  float* mS = sm + SM_STATS_S;
  float* sS = sm + SM_STATS_S + 3840;
  conv(style, 0, F1, 3,64,256,256,1,8);
  statsk<<<256,256,0,stream>>>(F1,65536, mS+0, sS+0);
  pool(F1,P1,64,128,128);
  convM(P1,1,F2, 64,128,128,128,1,1,nullptr);
  statsk<<<512,256,0,stream>>>(F2,16384, mS+256, sS+256);
  pool(F2,P2,128,64,64);
  convM(P2,2,F3, 128,256,64,64,1,1,nullptr);
  statsk<<<1024,256,0,stream>>>(F3,4096, mS+768, sS+768);
  pool(F3,P3,256,32,32);
  convM(P3,3,f4s, 256,512,32,32,1,2,PARTA);
  statsk<<<2048,256,0,stream>>>(f4s,1024, mS+1792, sS+1792);

  // ---- k-means (content r=0..3, style r=4..7) ----
  transposek<<<dim3(32,16,8),256,0,stream>>>(f4c,f4s,ptsT);
  initcentk<<<48,256,0,stream>>>(ptsT,cent);
  for (int it=0; it<10; ++it){
    assignk<<<2048,256,0,stream>>>(ptsT,cent,aPtr);
    updatek<0><<<dim3(8,16),256,0,stream>>>(ptsT,aPtr,cent,nullptr);
  }
  assignk<<<2048,256,0,stream>>>(ptsT,cent,aPtr);
  updatek<1><<<dim3(8,16),256,0,stream>>>(ptsT,aPtr,mu,counts);

  // ---- covariances via MFMA ----
  maskcenterk<<<12288,256,0,stream>>>(f4c,f4s,aPtr,mu,Ph,Pl);
  covgemm<<<dim3(4,4,24),256,0,stream>>>(Ph,Pl,counts,Ycov);
  powk<<<24,256,0,stream>>>(Ycov,sval);
  nsinitk<<<24576,256,0,stream>>>(Ycov,sval,Yh,Yl,Zh,Zl);

  // ---- split-bf16 MFMA Newton-Schulz (symmetric-B staging, merged updates) ----
  u16 *Ych=Yh,*Ycl=Yl,*Zch=Zh,*Zcl=Zl,*Yah=Y2h,*Yal=Y2l,*Zah=Z2h,*Zal=Z2l;
  for (int it=0; it<NS_ITERS; ++it){
    bmms<0,1><<<dim3(4,4,24),256,0,stream>>>(Zch,Zcl,Ych,Ycl,nullptr,nullptr,Mh,Ml,nullptr,nullptr,0);
    scalek<<<24,256,0,stream>>>(Mh,Ml,gbuf,obuf);
    bmmpair<<<dim3(4,4,48),256,0,stream>>>(Ych,Ycl,Mh,Ml,Zch,Zcl,Yah,Yal,Zah,Zal,gbuf,obuf);
    u16* t;
    t=Ych;Ych=Yah;Yah=t; t=Ycl;Ycl=Yal;Yal=t;
    t=Zch;Zch=Zah;Zah=t; t=Zcl;Zcl=Zal;Zal=t;
  }
  // T[b] = sqrt(s_s/s_c) * Y_style[b] @ Z_content[b]  (split out; NS_ITERS even -> Ych=Yh, Zch=Zh)
  make_scalesk<<<1,64,0,stream>>>(sval,scl);
  bmms<2,1><<<dim3(4,4,12),256,0,stream>>>(Ych,Ycl,Zch,Zcl,nullptr,nullptr,Th,Tl,nullptr,scl,12);
  tveck<<<12,512,0,stream>>>(Th,Tl,mu,tvec);
  // tpts[b] = T[b] @ f[img]
  splitk<<<2048,256,0,stream>>>(f4c,fsh,fsl,524288);
  float* Mb = AR + 0;
  bmmt<<<dim3(8,4,12),256,0,stream>>>(Th,Tl,fsh,fsl,Mb);
  selectk<<<8192,256,0,stream>>>(Mb,tvec,aPtr,f4c,tf);

  // ---- decode ----
  float* X1 = AR + 0;
  float* U1 = AR + 1048576ul;
  float* X2 = AR + 5242880ul;
  float* U2 = AR + 7340032ul;
  float* X3 = AR + 0;
  float* U3 = AR + 4194304ul;
  convM(tf, 4, X1, 512,256,32,32,1,4,PARTA);
  up(X1,U1,256,64,64);
  convM(U1,5,X2, 256,128,64,64,1,2,PARTB);
  up(X2,U2,128,128,128);
  convM(U2,6,X3, 128,64,128,128,1,1,nullptr);
  up(X3,U3,64,256,256);
  conv(U3,7,dec, 64,3,256,256,0,4);

  // ---- decoded encode + stats + content loss ----
  float* mD = sm + SM_STATS_D;
  float* sD = sm + SM_STATS_D + 3840;
  conv(dec, 0, F1, 3,64,256,256,1,8);
  statsk<<<256,256,0,stream>>>(F1,65536, mD+0, sD+0);
  pool(F1,P1,64,128,128);
  convM(P1,1,F2, 64,128,128,128,1,1,nullptr);
  statsk<<<512,256,0,stream>>>(F2,16384, mD+256, sD+256);
  pool(F2,P2,128,64,64);
  convM(P2,2,F3, 128,256,64,64,1,1,nullptr);
  statsk<<<1024,256,0,stream>>>(F3,4096, mD+768, sD+768);
  pool(F3,P3,256,32,32);
  convM(P3,3,tf, 256,512,32,32,1,2,PARTA);   // f4(dec) reuses tf buffer
  statsk<<<2048,256,0,stream>>>(tf,1024, mD+1792, sD+1792);
  clossk<<<2048,256,0,stream>>>(tf,f4c,2097152, sm+SM_CLOSS);
  finalk<<<1,256,0,stream>>>(sm,out);
}

// Round 9
// 3093.798 us; speedup vs baseline: 2.2475x; 1.0699x over previous
//
#include <hip/hip_runtime.h>
#include <cstddef>

#define NS_ITERS 10
#define MSZ 262144  // 512*512
#define PL  6291456 // 24*MSZ

typedef unsigned short u16;
typedef __attribute__((ext_vector_type(8))) short bf16x8;
typedef __attribute__((ext_vector_type(4))) float f32x4;
typedef __attribute__((ext_vector_type(4))) short u16x4;

__device__ inline u16 bf16_rne(float x){
  unsigned u = __float_as_uint(x);
  unsigned r = u + 0x7fffu + ((u>>16)&1u);
  return (u16)(r>>16);
}
__device__ inline float bf16f(u16 h){
  return __uint_as_float(((unsigned)h)<<16);
}

// ---------------- workspace offsets (in floats) ----------------
#define OFF_F4C   0ul
#define OFF_F4S   2097152ul
#define OFF_TF    4194304ul
#define OFF_DEC   6291456ul
#define OFF_WSPL  7077888ul      // 3145728 floats: pre-split conv weights (u16 hi/lo)
#define OFF_SMALL 10223616ul
#define OFF_ARENA 10354688ul

// SMALL sub-offsets (floats)
#define SM_CENT    0
#define SM_ASSIGN  12288
#define SM_MU      20480
#define SM_COUNTS  32768
#define SM_SVAL    32800        // 24: trace(Ycov) accumulators
#define SM_SCALE   32832
#define SM_TVEC    32864
#define SM_STATS_S 39008
#define SM_STATS_D 46688
#define SM_CLOSS   54368
#define SM_TR      54464        // 24*NS_ITERS trace-of-M accumulators

// ---------------- kernels ----------------

__global__ __launch_bounds__(256) void zerok(float* p, int n){
  int i = blockIdx.x*256 + threadIdx.x;
  if (i < n) p[i] = 0.f;
}

// direct 3x3 SAME conv (for e1: Cin=3, and d4: Cout=3 — tiny FLOPs, fp32 VALU is fine)
template<int COT>
__global__ __launch_bounds__(256) void conv3x3(
    const float* __restrict__ in, const float* __restrict__ wgt,
    const float* __restrict__ bias, float* __restrict__ out,
    int B, int Cin, int Cout, int H, int W, int relu)
{
  __shared__ float s_in[8][34][34];
  __shared__ float s_w[COT][8][9];
  const int tid = threadIdx.x;
  const int tx = tid & 15, ty = tid >> 4;
  const int tilesW = W >> 5;
  const int h0 = (blockIdx.x / tilesW) << 5;
  const int w0 = (blockIdx.x % tilesW) << 5;
  const int co0 = blockIdx.y * COT;
  const int b = blockIdx.z;
  float acc[COT][2][2];
  #pragma unroll
  for (int o=0;o<COT;o++){acc[o][0][0]=0.f;acc[o][0][1]=0.f;acc[o][1][0]=0.f;acc[o][1][1]=0.f;}
  const int y0 = ty*2, x0 = tx*2;
  for (int ci0 = 0; ci0 < Cin; ci0 += 8){
    const int cic = (Cin - ci0 < 8) ? (Cin - ci0) : 8;
    const int tot = cic*1156;
    for (int e = tid; e < tot; e += 256){
      int c = e / 1156; int r = e - c*1156;
      int lh = r / 34, lw = r - lh*34;
      int ih = h0 + lh - 1, iw = w0 + lw - 1;
      float v = 0.f;
      if ((unsigned)ih < (unsigned)H && (unsigned)iw < (unsigned)W)
        v = in[((size_t)(b*Cin + ci0 + c)*H + ih)*W + iw];
      s_in[c][lh][lw] = v;
    }
    const int wtot = COT*cic*9;
    for (int e = tid; e < wtot; e += 256){
      int o = e / (cic*9); int r = e - o*(cic*9);
      int c = r / 9, t = r - c*9;
      int co = co0 + o;
      float v = 0.f;
      if (co < Cout) v = wgt[(size_t)(co*Cin + ci0 + c)*9 + t];
      s_w[o][c][t] = v;
    }
    __syncthreads();
    for (int c = 0; c < cic; ++c){
      float p[4][4];
      #pragma unroll
      for (int r=0;r<4;r++)
        #pragma unroll
        for (int s=0;s<4;s++)
          p[r][s] = s_in[c][y0+r][x0+s];
      #pragma unroll
      for (int dh=0; dh<3; dh++)
        #pragma unroll
        for (int dw=0; dw<3; dw++){
          #pragma unroll
          for (int o=0;o<COT;o++){
            float wv = s_w[o][c][dh*3+dw];
            acc[o][0][0] = fmaf(p[dh  ][dw  ], wv, acc[o][0][0]);
            acc[o][0][1] = fmaf(p[dh  ][dw+1], wv, acc[o][0][1]);
            acc[o][1][0] = fmaf(p[dh+1][dw  ], wv, acc[o][1][0]);
            acc[o][1][1] = fmaf(p[dh+1][dw+1], wv, acc[o][1][1]);
          }
        }
    }
    __syncthreads();
  }
  #pragma unroll
  for (int o=0;o<COT;o++){
    int co = co0 + o;
    if (co >= Cout) continue;
    float bv = bias[co];
    #pragma unroll
    for (int r=0;r<2;r++)
      #pragma unroll
      for (int s=0;s<2;s++){
        float v = acc[o][r][s] + bv;
        if (relu) v = fmaxf(v, 0.f);
        out[((size_t)(b*Cout + co)*H + h0+y0+r)*W + w0+x0+s] = v;
      }
  }
}

// pre-split conv weights: dst[(dhw*Cout + co)*Cin + ci] = split(wgt[(co*Cin+ci)*9 + dhw])
__global__ __launch_bounds__(256) void wsplitk(const float* __restrict__ wgt,
                                               u16* __restrict__ dh_, u16* __restrict__ dl_,
                                               int Cout, int Cin){
  int idx = blockIdx.x*256 + threadIdx.x;
  int n = 9*Cout*Cin;
  if (idx >= n) return;
  int cc = Cout*Cin;
  int dhw = idx / cc;
  int r = idx - dhw*cc;
  int co = r / Cin, ci = r - co*Cin;
  float v = wgt[((size_t)co*Cin + ci)*9 + dhw];
  u16 h = bf16_rne(v);
  dh_[idx] = h;
  dl_[idx] = bf16_rne(v - bf16f(h));
}

// ---- split-bf16 MFMA direct conv 3x3 SAME; requires Cin%(32*KS)==0, Cout%64==0 ----
// KS>1: blockIdx.z = b*KS + ks; writes fp32 partial [ks][b][Cout][H][W]; sumk reduces.
template<int KS>
__global__ __launch_bounds__(256) void convm(
    const float* __restrict__ in, const u16* __restrict__ wsh, const u16* __restrict__ wsl,
    const float* __restrict__ bias, float* __restrict__ out,
    int Cin, int Cout, int H, int W, int relu)
{
  const int tilesW = W >> 3;
  const int h0 = (blockIdx.x / tilesW) << 3;
  const int w0 = (blockIdx.x % tilesW) << 3;
  const int co0 = blockIdx.y << 6;
  const int b  = blockIdx.z / KS;
  const int ks = blockIdx.z % KS;
  const int NB = gridDim.z / KS;
  const int tid = threadIdx.x;
  const int wid = tid >> 6, lane = tid & 63;
  const int wm = wid >> 1, wn = wid & 1;
  const int quad = lane >> 4, ln = lane & 15;

  __shared__ __align__(16) u16 sXh[100*40], sXl[100*40];
  __shared__ __align__(16) u16 sWh[3*64*40], sWl[3*64*40];

  f32x4 acc[2][2];
  #pragma unroll
  for (int i=0;i<2;i++)
    #pragma unroll
    for (int j=0;j<2;j++)
      #pragma unroll
      for (int e=0;e<4;e++) acc[i][j][e] = 0.f;

  const int ciA = ks*(Cin/KS), ciB = ciA + Cin/KS;
  for (int ci0 = ciA; ci0 < ciB; ci0 += 32){
    __syncthreads();
    for (int e = tid; e < 3200; e += 256){
      int ci = e / 100, px = e - ci*100;
      int pr = px / 10, pc = px - pr*10;
      int ih = h0 + pr - 1, iw = w0 + pc - 1;
      float v = 0.f;
      if ((unsigned)ih < (unsigned)H && (unsigned)iw < (unsigned)W)
        v = in[((size_t)(b*Cin + ci0+ci)*H + ih)*W + iw];
      u16 h = bf16_rne(v);
      sXh[px*40 + ci] = h;
      sXl[px*40 + ci] = bf16_rne(v - bf16f(h));
    }
    for (int dh = 0; dh < 3; ++dh){
      if (dh) __syncthreads();
      for (int e2 = tid; e2 < 768; e2 += 256){
        int dw = e2 >> 8, r = e2 & 255;
        int co = r >> 2, cg = (r & 3) << 3;
        size_t so = ((size_t)((dh*3+dw)*Cout + co0+co))*Cin + ci0 + cg;
        int dsto = (dw*64+co)*40 + cg;
        *(bf16x8*)&sWh[dsto] = *(const bf16x8*)&wsh[so];
        *(bf16x8*)&sWl[dsto] = *(const bf16x8*)&wsl[so];
      }
      __syncthreads();
      #pragma unroll
      for (int dw = 0; dw < 3; ++dw){
        bf16x8 ah[2], al[2], bh[2], bl[2];
        #pragma unroll
        for (int t=0;t<2;t++){
          const int co_l = (wm*2+t)*16 + ln;
          const int wo = (dw*64 + co_l)*40 + quad*8;
          ah[t] = *(const bf16x8*)&sWh[wo];
          al[t] = *(const bf16x8*)&sWl[wo];
          const int p = (wn*2+t)*16 + ln;
          const int px = ((p>>3) + dh)*10 + (p&7) + dw;
          const int xo = px*40 + quad*8;
          bh[t] = *(const bf16x8*)&sXh[xo];
          bl[t] = *(const bf16x8*)&sXl[xo];
        }
        #pragma unroll
        for (int mi=0;mi<2;mi++)
          #pragma unroll
          for (int ni=0;ni<2;ni++){
            acc[mi][ni] = __builtin_amdgcn_mfma_f32_16x16x32_bf16(ah[mi], bh[ni], acc[mi][ni], 0, 0, 0);
            acc[mi][ni] = __builtin_amdgcn_mfma_f32_16x16x32_bf16(ah[mi], bl[ni], acc[mi][ni], 0, 0, 0);
            acc[mi][ni] = __builtin_amdgcn_mfma_f32_16x16x32_bf16(al[mi], bh[ni], acc[mi][ni], 0, 0, 0);
          }
      }
    }
  }
  #pragma unroll
  for (int mi=0;mi<2;mi++){
    const int co = co0 + (wm*2+mi)*16 + quad*4;
    #pragma unroll
    for (int ni=0;ni<2;ni++){
      const int p = (wn*2+ni)*16 + ln;
      const int oh = h0 + (p>>3), ow = w0 + (p&7);
      #pragma unroll
      for (int rg=0; rg<4; rg++){
        const int cog = co + rg;
        if constexpr (KS==1){
          float v = acc[mi][ni][rg] + bias[cog];
          if (relu) v = fmaxf(v, 0.f);
          out[((size_t)(b*Cout + cog)*H + oh)*W + ow] = v;
        } else {
          out[((size_t)((ks*NB + b)*Cout + cog)*H + oh)*W + ow] = acc[mi][ni][rg];
        }
      }
    }
  }
}

// reduce split-K partials + bias + relu
__global__ __launch_bounds__(256) void sumk(const float* __restrict__ part, const float* __restrict__ bias,
                                            float* __restrict__ out, int Cout, int HW, int KS, int relu, int n){
  int idx = blockIdx.x*256 + threadIdx.x;
  if (idx >= n) return;
  int co = (idx / HW) % Cout;
  float v = bias[co];
  for (int k=0;k<KS;k++) v += part[(size_t)k*n + idx];
  if (relu) v = fmaxf(v, 0.f);
  out[idx] = v;
}

__global__ __launch_bounds__(256) void pool2k(const float* __restrict__ in, float* __restrict__ out,
                                              int n, int Ho, int Wo){
  int idx = blockIdx.x*256 + threadIdx.x;
  if (idx >= n) return;
  int wo = idx % Wo; int t = idx / Wo; int ho = t % Ho; int bc = t / Ho;
  const float* p = in + ((size_t)bc*(Ho*2) + ho*2)*(size_t)(Wo*2) + (size_t)wo*2;
  out[idx] = 0.25f*(p[0] + p[1] + p[2*Wo] + p[2*Wo+1]);
}

__global__ __launch_bounds__(256) void up2k(const float* __restrict__ in, float* __restrict__ out,
                                            int n, int Ho, int Wo){
  int idx = blockIdx.x*256 + threadIdx.x;
  if (idx >= n) return;
  int wo = idx % Wo; int t = idx / Wo; int ho = t % Ho; int bc = t / Ho;
  int Hi = Ho >> 1, Wi = Wo >> 1;
  out[idx] = in[((size_t)bc*Hi + (ho>>1))*Wi + (wo>>1)];
}

// per-(b,c) spatial mean & std (ddof=0)
__global__ __launch_bounds__(256) void statsk(const float* __restrict__ x, int HW,
                                              float* __restrict__ mo, float* __restrict__ so){
  int bc = blockIdx.x, tid = threadIdx.x;
  const float* p = x + (size_t)bc*HW;
  double s = 0.0, s2 = 0.0;
  for (int i = tid; i < HW; i += 256){ double v = p[i]; s += v; s2 += v*v; }
  __shared__ double sh[256], sh2[256];
  sh[tid] = s; sh2[tid] = s2; __syncthreads();
  for (int k=128;k>0;k>>=1){ if (tid<k){ sh[tid]+=sh[tid+k]; sh2[tid]+=sh2[tid+k]; } __syncthreads(); }
  if (tid == 0){
    double m = sh[0]/HW;
    double var = sh2[0]/HW - m*m;
    if (var < 0.0) var = 0.0;
    mo[bc] = (float)m;
    so[bc] = (float)sqrt(var);
  }
}

// f4 (C-major, per image 512x1024) -> ptsT [8][1024][512]
__global__ __launch_bounds__(256) void transposek(const float* __restrict__ f4c,
                                                  const float* __restrict__ f4s,
                                                  float* __restrict__ ptsT){
  __shared__ float t[32][33];
  int r = blockIdx.z;
  const float* src = (r < 4) ? (f4c + (size_t)r*524288) : (f4s + (size_t)(r-4)*524288);
  int n0 = blockIdx.x*32, c0 = blockIdx.y*32;
  int lx = threadIdx.x & 31, ly = threadIdx.x >> 5;
  for (int j=0;j<32;j+=8)
    t[ly+j][lx] = src[(size_t)(c0+ly+j)*1024 + n0+lx];
  __syncthreads();
  for (int j=0;j<32;j+=8)
    ptsT[((size_t)r*1024 + n0+ly+j)*512 + c0+lx] = t[lx][ly+j];
}

__global__ __launch_bounds__(256) void initcentk(const float* __restrict__ ptsT, float* __restrict__ cent){
  int i = blockIdx.x*256 + threadIdx.x;
  if (i >= 12288) return;
  int c = i & 511; int k = (i >> 9) % 3; int r = i / 1536;
  cent[i] = ptsT[((size_t)r*1024 + k)*512 + c];
}

// one wave per point; first-min argmin (matches jnp.argmin)
__global__ __launch_bounds__(256) void assignk(const float* __restrict__ ptsT,
                                               const float* __restrict__ cent, int* __restrict__ a){
  int gp = blockIdx.x*4 + (threadIdx.x >> 6);
  int lane = threadIdx.x & 63;
  int r = gp >> 10;
  const float* p = ptsT + (size_t)gp*512;
  const float* ce = cent + r*1536;
  float d0=0.f,d1=0.f,d2=0.f;
  #pragma unroll
  for (int i=0;i<8;i++){
    int c = lane + i*64;
    float v = p[c];
    float e0 = v - ce[c], e1 = v - ce[512+c], e2 = v - ce[1024+c];
    d0 = fmaf(e0,e0,d0); d1 = fmaf(e1,e1,d1); d2 = fmaf(e2,e2,d2);
  }
  #pragma unroll
  for (int off=32; off>0; off>>=1){
    d0 += __shfl_down(d0, off, 64);
    d1 += __shfl_down(d1, off, 64);
    d2 += __shfl_down(d2, off, 64);
  }
  if (lane == 0){
    int bi = 0; float bd = d0;
    if (d1 < bd){ bd = d1; bi = 1; }
    if (d2 < bd){ bd = d2; bi = 2; }
    a[gp] = bi;
  }
}

// parallel centroid update: grid (r=8, cc=16), 256 thr
template<int WRITE>
__global__ __launch_bounds__(256) void updatek(const float* __restrict__ ptsT,
                                               const int* __restrict__ a,
                                               float* __restrict__ dst,
                                               float* __restrict__ counts){
  int r = blockIdx.x, cc = blockIdx.y;
  int tid = threadIdx.x;
  int lane = tid & 31, p = tid >> 5;
  int c = cc*32 + lane;
  __shared__ int sa[1024];
  __shared__ int scnt[3];
  if (tid < 3) scnt[tid] = 0;
  for (int i = tid; i < 1024; i += 256) sa[i] = a[r*1024 + i];
  __syncthreads();
  {
    int l0=0,l1=0,l2=0;
    #pragma unroll
    for (int i=tid*4;i<tid*4+4;i++){ int an=sa[i]; l0+=(an==0); l1+=(an==1); l2+=(an==2); }
    if (l0) atomicAdd(&scnt[0], l0);
    if (l1) atomicAdd(&scnt[1], l1);
    if (l2) atomicAdd(&scnt[2], l2);
  }
  const float* base = ptsT + (size_t)r*524288;
  float s0=0.f,s1=0.f,s2=0.f;
  for (int n = p*128; n < p*128+128; ++n){
    float v = base[(size_t)n*512 + c];
    int an = sa[n];
    s0 += (an==0) ? v : 0.f;
    s1 += (an==1) ? v : 0.f;
    s2 += (an==2) ? v : 0.f;
  }
  __shared__ float red[8][3][32];
  red[p][0][lane]=s0; red[p][1][lane]=s1; red[p][2][lane]=s2;
  __syncthreads();
  if (p == 0){
    float t0=0.f,t1=0.f,t2=0.f;
    #pragma unroll
    for (int q=0;q<8;q++){ t0+=red[q][0][lane]; t1+=red[q][1][lane]; t2+=red[q][2][lane]; }
    float n0 = (float)scnt[0] + 1e-6f, n1 = (float)scnt[1] + 1e-6f, n2 = (float)scnt[2] + 1e-6f;
    if (WRITE == 0){
      dst[r*1536 + c]        = t0/n0;
      dst[r*1536 + 512 + c]  = t1/n1;
      dst[r*1536 + 1024 + c] = t2/n2;
    } else {
      int cs = r >> 2, img = r & 3;
      int i0 = cs*12 + img*3;
      dst[(size_t)(i0+0)*512 + c] = t0/n0;
      dst[(size_t)(i0+1)*512 + c] = t1/n1;
      dst[(size_t)(i0+2)*512 + c] = t2/n2;
      if (cc == 0 && lane == 0){
        counts[i0]   = (float)scnt[0];
        counts[i0+1] = (float)scnt[1];
        counts[i0+2] = (float)scnt[2];
      }
    }
  }
}

// masked centered split planes: P[z][c][n] = (a[n]==k) ? pts[c][n]-mu[z][c] : 0
__global__ __launch_bounds__(256) void maskcenterk(const float* __restrict__ f4c, const float* __restrict__ f4s,
        const int* __restrict__ a, const float* __restrict__ mu,
        u16* __restrict__ Ph, u16* __restrict__ Pl){
  size_t i4 = ((size_t)blockIdx.x*256 + threadIdx.x)*4;
  if (i4 >= (size_t)PL*2) return;   // total elems = 24*512*1024
  int z = (int)(i4 >> 19);
  int rc = (int)(i4 & 524287);
  int c = rc >> 10, n = rc & 1023;
  int cs = z / 12; int rem = z - cs*12; int img = rem / 3; int k = rem - img*3;
  const float* pts = (cs ? f4s : f4c) + (size_t)img*524288;
  float m = mu[(size_t)z*512 + c];
  const int* an = a + (cs*4 + img)*1024 + n;
  float4 v4 = *(const float4*)&pts[(size_t)c*1024 + n];
  float vv[4] = {v4.x, v4.y, v4.z, v4.w};
  u16x4 oh, ol;
  #pragma unroll
  for (int j=0;j<4;j++){
    float v = (an[j] == k) ? (vv[j] - m) : 0.f;
    u16 h = bf16_rne(v);
    oh[j] = (short)h;
    ol[j] = (short)bf16_rne(v - bf16f(h));
  }
  *(u16x4*)&Ph[i4] = oh;
  *(u16x4*)&Pl[i4] = ol;
}

// covariance via MFMA: Ycov[z] = P[z] @ P[z]^T / nc + 0.1 I  (K=1024); diag blocks
// also accumulate trace(Ycov[z]) into trsum[z] (pre-zeroed).
__global__ __launch_bounds__(256) void covgemm(const u16* __restrict__ Ph, const u16* __restrict__ Pl,
        const float* __restrict__ counts, float* __restrict__ Ycov, float* __restrict__ trsum){
  const int z = blockIdx.z;
  const u16* Pbh = Ph + (size_t)z*524288;
  const u16* Pbl = Pl + (size_t)z*524288;
  const int m0 = blockIdx.y*128, n0 = blockIdx.x*128;
  const int tid = threadIdx.x;

  __shared__ __align__(16) u16 sAh[128*40], sAl[128*40];
  __shared__ __align__(16) u16 sBh[128*40], sBl[128*40];

  const int ra = tid >> 2, qa = tid & 3;
  const int wid = tid >> 6, lane = tid & 63;
  const int wm = wid >> 1, wn = wid & 1;
  const int quad = lane >> 4, ln = lane & 15;

  f32x4 acc[4][4];
  #pragma unroll
  for (int i=0;i<4;i++)
    #pragma unroll
    for (int j=0;j<4;j++)
      #pragma unroll
      for (int e=0;e<4;e++) acc[i][j][e] = 0.f;

  for (int k0 = 0; k0 < 1024; k0 += 32){
    *(bf16x8*)&sAh[ra*40 + qa*8]      = *(const bf16x8*)&Pbh[(size_t)(m0+ra)*1024    + k0 + qa*8];
    *(bf16x8*)&sAl[ra*40 + qa*8]      = *(const bf16x8*)&Pbl[(size_t)(m0+ra)*1024    + k0 + qa*8];
    *(bf16x8*)&sAh[(ra+64)*40 + qa*8] = *(const bf16x8*)&Pbh[(size_t)(m0+ra+64)*1024 + k0 + qa*8];
    *(bf16x8*)&sAl[(ra+64)*40 + qa*8] = *(const bf16x8*)&Pbl[(size_t)(m0+ra+64)*1024 + k0 + qa*8];
    *(bf16x8*)&sBh[ra*40 + qa*8]      = *(const bf16x8*)&Pbh[(size_t)(n0+ra)*1024    + k0 + qa*8];
    *(bf16x8*)&sBl[ra*40 + qa*8]      = *(const bf16x8*)&Pbl[(size_t)(n0+ra)*1024    + k0 + qa*8];
    *(bf16x8*)&sBh[(ra+64)*40 + qa*8] = *(const bf16x8*)&Pbh[(size_t)(n0+ra+64)*1024 + k0 + qa*8];
    *(bf16x8*)&sBl[(ra+64)*40 + qa*8] = *(const bf16x8*)&Pbl[(size_t)(n0+ra+64)*1024 + k0 + qa*8];
    __syncthreads();

    bf16x8 ah[4], al[4], bh[4], bl[4];
    #pragma unroll
    for (int t=0;t<4;t++){
      const int moA = ((wm*4+t)*16 + ln)*40 + quad*8;
      const int moB = ((wn*4+t)*16 + ln)*40 + quad*8;
      ah[t] = *(const bf16x8*)&sAh[moA];
      al[t] = *(const bf16x8*)&sAl[moA];
      bh[t] = *(const bf16x8*)&sBh[moB];
      bl[t] = *(const bf16x8*)&sBl[moB];
    }
    #pragma unroll
    for (int mi=0;mi<4;mi++)
      #pragma unroll
      for (int ni=0;ni<4;ni++){
        acc[mi][ni] = __builtin_amdgcn_mfma_f32_16x16x32_bf16(ah[mi], bh[ni], acc[mi][ni], 0, 0, 0);
        acc[mi][ni] = __builtin_amdgcn_mfma_f32_16x16x32_bf16(ah[mi], bl[ni], acc[mi][ni], 0, 0, 0);
        acc[mi][ni] = __builtin_amdgcn_mfma_f32_16x16x32_bf16(al[mi], bh[ni], acc[mi][ni], 0, 0, 0);
      }
    __syncthreads();
  }
  const float inv = 1.f/(counts[z] + 1e-6f);
  float dsum = 0.f; bool anyd = false;
  #pragma unroll
  for (int mi=0;mi<4;mi++){
    const int mbase = m0 + (wm*4+mi)*16 + quad*4;
    #pragma unroll
    for (int ni=0;ni<4;ni++){
      const int n = n0 + (wn*4+ni)*16 + ln;
      #pragma unroll
      for (int rg=0;rg<4;rg++){
        const int m = mbase + rg;
        float v = acc[mi][ni][rg]*inv + ((m==n)?0.1f:0.f);
        Ycov[(size_t)z*MSZ + (size_t)m*512 + n] = v;
        if (m0==n0 && m==n){ dsum += v; anyd = true; }
      }
    }
  }
  if (anyd) atomicAdd(&trsum[z], dsum);
}

// init split planes: Y = Ycov/trace (hi+lo bf16), Z = I
__global__ __launch_bounds__(256) void nsinitk(const float* __restrict__ Ycov, const float* __restrict__ sval,
                                               u16* __restrict__ Yh, u16* __restrict__ Yl,
                                               u16* __restrict__ Zh, u16* __restrict__ Zl){
  size_t idx = (size_t)blockIdx.x*256 + threadIdx.x;
  if (idx >= (size_t)PL) return;
  int z = (int)(idx >> 18);
  int rc = (int)(idx & (MSZ-1));
  int rr = rc >> 9, cc = rc & 511;
  float y = Ycov[idx] / sval[z];
  u16 h = bf16_rne(y);
  Yh[idx] = h;
  Yl[idx] = bf16_rne(y - bf16f(h));
  Zh[idx] = (rr==cc) ? (u16)0x3F80 : (u16)0;
  Zl[idx] = 0;
}

// ---- split-bf16 MFMA batched GEMM 512x512x512 ----
// SYMB=1: B symmetric -> stage B^T tile as contiguous B rows
// MODE 0: C = A@B (+ trace accumulation into trAcc[z] if trAcc) ; MODE 2: C = osc*(A@B)
template<int MODE, int SYMB>
__global__ __launch_bounds__(256) void bmms(
    const u16* __restrict__ Ah, const u16* __restrict__ Al,
    const u16* __restrict__ Bh, const u16* __restrict__ Bl,
    u16* __restrict__ Ch, u16* __restrict__ Cl,
    const float* __restrict__ osc,
    int aoff, float* __restrict__ trAcc)
{
  const int z = blockIdx.z;
  const u16* Abh = Ah + (size_t)(z+aoff)*MSZ;
  const u16* Abl = Al + (size_t)(z+aoff)*MSZ;
  const u16* Bbh = Bh + (size_t)z*MSZ;
  const u16* Bbl = Bl + (size_t)z*MSZ;
  const int m0 = blockIdx.y*128, n0 = blockIdx.x*128;
  const int tid = threadIdx.x;

  __shared__ __align__(16) u16 sAh[128*40], sAl[128*40];
  __shared__ __align__(16) u16 sBh[128*40], sBl[128*40];

  const int ra = tid >> 2, qa = tid & 3;
  const int kb = tid >> 4, gb = tid & 15;

  const int wid = tid >> 6, lane = tid & 63;
  const int wm = wid >> 1, wn = wid & 1;
  const int quad = lane >> 4, ln = lane & 15;

  f32x4 acc[4][4];
  #pragma unroll
  for (int i=0;i<4;i++)
    #pragma unroll
    for (int j=0;j<4;j++)
      #pragma unroll
      for (int e=0;e<4;e++) acc[i][j][e] = 0.f;

  for (int k0 = 0; k0 < 512; k0 += 32){
    *(bf16x8*)&sAh[ra*40 + qa*8]      = *(const bf16x8*)&Abh[(size_t)(m0+ra)*512    + k0 + qa*8];
    *(bf16x8*)&sAl[ra*40 + qa*8]      = *(const bf16x8*)&Abl[(size_t)(m0+ra)*512    + k0 + qa*8];
    *(bf16x8*)&sAh[(ra+64)*40 + qa*8] = *(const bf16x8*)&Abh[(size_t)(m0+ra+64)*512 + k0 + qa*8];
    *(bf16x8*)&sAl[(ra+64)*40 + qa*8] = *(const bf16x8*)&Abl[(size_t)(m0+ra+64)*512 + k0 + qa*8];
    if constexpr (SYMB){
      *(bf16x8*)&sBh[ra*40 + qa*8]      = *(const bf16x8*)&Bbh[(size_t)(n0+ra)*512    + k0 + qa*8];
      *(bf16x8*)&sBl[ra*40 + qa*8]      = *(const bf16x8*)&Bbl[(size_t)(n0+ra)*512    + k0 + qa*8];
      *(bf16x8*)&sBh[(ra+64)*40 + qa*8] = *(const bf16x8*)&Bbh[(size_t)(n0+ra+64)*512 + k0 + qa*8];
      *(bf16x8*)&sBl[(ra+64)*40 + qa*8] = *(const bf16x8*)&Bbl[(size_t)(n0+ra+64)*512 + k0 + qa*8];
    } else {
      bf16x8 vh = *(const bf16x8*)&Bbh[(size_t)(k0+kb)*512 + n0 + gb*8];
      bf16x8 vl = *(const bf16x8*)&Bbl[(size_t)(k0+kb)*512 + n0 + gb*8];
      #pragma unroll
      for (int j=0;j<8;j++){
        sBh[(gb*8+j)*40 + kb] = (u16)vh[j];
        sBl[(gb*8+j)*40 + kb] = (u16)vl[j];
      }
      vh = *(const bf16x8*)&Bbh[(size_t)(k0+kb+16)*512 + n0 + gb*8];
      vl = *(const bf16x8*)&Bbl[(size_t)(k0+kb+16)*512 + n0 + gb*8];
      #pragma unroll
      for (int j=0;j<8;j++){
        sBh[(gb*8+j)*40 + kb+16] = (u16)vh[j];
        sBl[(gb*8+j)*40 + kb+16] = (u16)vl[j];
      }
    }
    __syncthreads();

    bf16x8 ah[4], al[4], bh[4], bl[4];
    #pragma unroll
    for (int t=0;t<4;t++){
      const int moA = ((wm*4+t)*16 + ln)*40 + quad*8;
      const int moB = ((wn*4+t)*16 + ln)*40 + quad*8;
      ah[t] = *(const bf16x8*)&sAh[moA];
      al[t] = *(const bf16x8*)&sAl[moA];
      bh[t] = *(const bf16x8*)&sBh[moB];
      bl[t] = *(const bf16x8*)&sBl[moB];
    }
    #pragma unroll
    for (int mi=0;mi<4;mi++)
      #pragma unroll
      for (int ni=0;ni<4;ni++){
        acc[mi][ni] = __builtin_amdgcn_mfma_f32_16x16x32_bf16(ah[mi], bh[ni], acc[mi][ni], 0, 0, 0);
        acc[mi][ni] = __builtin_amdgcn_mfma_f32_16x16x32_bf16(ah[mi], bl[ni], acc[mi][ni], 0, 0, 0);
        acc[mi][ni] = __builtin_amdgcn_mfma_f32_16x16x32_bf16(al[mi], bh[ni], acc[mi][ni], 0, 0, 0);
      }
    __syncthreads();
  }

  float alpha = 1.f;
  if constexpr (MODE==2){ alpha = osc[z]; }

  float dsum = 0.f; bool anyd = false;
  #pragma unroll
  for (int mi=0;mi<4;mi++){
    const int mbase = m0 + (wm*4+mi)*16 + quad*4;
    #pragma unroll
    for (int ni=0;ni<4;ni++){
      const int n = n0 + (wn*4+ni)*16 + ln;
      #pragma unroll
      for (int rg=0;rg<4;rg++){
        const int m = mbase + rg;
        const size_t off = (size_t)z*MSZ + (size_t)m*512 + n;
        float v = alpha*acc[mi][ni][rg];
        u16 h = bf16_rne(v);
        Ch[off] = h;
        Cl[off] = bf16_rne(v - bf16f(h));
        if (MODE==0 && trAcc && m0==n0 && m==n){ dsum += v; anyd = true; }
      }
    }
  }
  if (MODE==0 && anyd) atomicAdd(&trAcc[z], dsum);
}

// merged NS update: z<24 -> Y2 = os*(3Y - g*(Y@M)); z>=24 -> Z2 = os*(3Z - g*(M@Z))
// g/os computed inline from trAcc[zz] = trace(M) (accumulated by the preceding bmms<0>)
__global__ __launch_bounds__(256) void bmmpair(
    const u16* __restrict__ Yh, const u16* __restrict__ Yl,
    const u16* __restrict__ Mh, const u16* __restrict__ Ml,
    const u16* __restrict__ Zh, const u16* __restrict__ Zl,
    u16* __restrict__ Y2h, u16* __restrict__ Y2l,
    u16* __restrict__ Z2h, u16* __restrict__ Z2l,
    const float* __restrict__ trAcc)
{
  const int z = blockIdx.z;
  const int zz = (z < 24) ? z : (z - 24);
  const size_t zo = (size_t)zz*MSZ;
  const u16 *Abh, *Abl, *Bbh, *Bbl, *Dbh, *Dbl;
  u16 *Cbh, *Cbl;
  if (z < 24){
    Abh = Yh + zo; Abl = Yl + zo;
    Bbh = Mh + zo; Bbl = Ml + zo;
    Dbh = Yh + zo; Dbl = Yl + zo;
    Cbh = Y2h + zo; Cbl = Y2l + zo;
  } else {
    Abh = Mh + zo; Abl = Ml + zo;
    Bbh = Zh + zo; Bbl = Zl + zo;
    Dbh = Zh + zo; Dbl = Zl + zo;
    Cbh = Z2h + zo; Cbl = Z2l + zo;
  }
  const int m0 = blockIdx.y*128, n0 = blockIdx.x*128;
  const int tid = threadIdx.x;

  __shared__ __align__(16) u16 sAh[128*40], sAl[128*40];
  __shared__ __align__(16) u16 sBh[128*40], sBl[128*40];

  const int ra = tid >> 2, qa = tid & 3;
  const int wid = tid >> 6, lane = tid & 63;
  const int wm = wid >> 1, wn = wid & 1;
  const int quad = lane >> 4, ln = lane & 15;

  f32x4 acc[4][4];
  #pragma unroll
  for (int i=0;i<4;i++)
    #pragma unroll
    for (int j=0;j<4;j++)
      #pragma unroll
      for (int e=0;e<4;e++) acc[i][j][e] = 0.f;

  for (int k0 = 0; k0 < 512; k0 += 32){
    *(bf16x8*)&sAh[ra*40 + qa*8]      = *(const bf16x8*)&Abh[(size_t)(m0+ra)*512    + k0 + qa*8];
    *(bf16x8*)&sAl[ra*40 + qa*8]      = *(const bf16x8*)&Abl[(size_t)(m0+ra)*512    + k0 + qa*8];
    *(bf16x8*)&sAh[(ra+64)*40 + qa*8] = *(const bf16x8*)&Abh[(size_t)(m0+ra+64)*512 + k0 + qa*8];
    *(bf16x8*)&sAl[(ra+64)*40 + qa*8] = *(const bf16x8*)&Abl[(size_t)(m0+ra+64)*512 + k0 + qa*8];
    *(bf16x8*)&sBh[ra*40 + qa*8]      = *(const bf16x8*)&Bbh[(size_t)(n0+ra)*512    + k0 + qa*8];
    *(bf16x8*)&sBl[ra*40 + qa*8]      = *(const bf16x8*)&Bbl[(size_t)(n0+ra)*512    + k0 + qa*8];
    *(bf16x8*)&sBh[(ra+64)*40 + qa*8] = *(const bf16x8*)&Bbh[(size_t)(n0+ra+64)*512 + k0 + qa*8];
    *(bf16x8*)&sBl[(ra+64)*40 + qa*8] = *(const bf16x8*)&Bbl[(size_t)(n0+ra+64)*512 + k0 + qa*8];
    __syncthreads();

    bf16x8 ah[4], al[4], bh[4], bl[4];
    #pragma unroll
    for (int t=0;t<4;t++){
      const int moA = ((wm*4+t)*16 + ln)*40 + quad*8;
      const int moB = ((wn*4+t)*16 + ln)*40 + quad*8;
      ah[t] = *(const bf16x8*)&sAh[moA];
      al[t] = *(const bf16x8*)&sAl[moA];
      bh[t] = *(const bf16x8*)&sBh[moB];
      bl[t] = *(const bf16x8*)&sBl[moB];
    }
    #pragma unroll
    for (int mi=0;mi<4;mi++)
      #pragma unroll
      for (int ni=0;ni<4;ni++){
        acc[mi][ni] = __builtin_amdgcn_mfma_f32_16x16x32_bf16(ah[mi], bh[ni], acc[mi][ni], 0, 0, 0);
        acc[mi][ni] = __builtin_amdgcn_mfma_f32_16x16x32_bf16(ah[mi], bl[ni], acc[mi][ni], 0, 0, 0);
        acc[mi][ni] = __builtin_amdgcn_mfma_f32_16x16x32_bf16(al[mi], bh[ni], acc[mi][ni], 0, 0, 0);
      }
    __syncthreads();
  }

  const float tr = trAcc[zz];
  const float g2 = fminf(512.f/fmaxf(tr, 1e-6f), 2.7f);
  const float oz = 0.5f*sqrtf(g2);
  const float alpha = -g2*oz, beta = 3.f*oz;

  #pragma unroll
  for (int mi=0;mi<4;mi++){
    const int mbase = m0 + (wm*4+mi)*16 + quad*4;
    #pragma unroll
    for (int ni=0;ni<4;ni++){
      const int n = n0 + (wn*4+ni)*16 + ln;
      #pragma unroll
      for (int rg=0;rg<4;rg++){
        const int m = mbase + rg;
        const size_t off = (size_t)m*512 + n;
        float v = alpha*acc[mi][ni][rg] + beta*(bf16f(Dbh[off]) + bf16f(Dbl[off]));
        u16 h = bf16_rne(v);
        Cbh[off] = h;
        Cbl[off] = bf16_rne(v - bf16f(h));
      }
    }
  }
}

// tpts = T[z] @ f[img]: M=512, N=1024, K=512, fp32 out (f non-symmetric: transpose-staged)
__global__ __launch_bounds__(256) void bmmt(
    const u16* __restrict__ Th, const u16* __restrict__ Tl,
    const u16* __restrict__ fh, const u16* __restrict__ fl,
    float* __restrict__ Cf)
{
  const int z = blockIdx.z;
  const u16* Abh = Th + (size_t)z*MSZ;
  const u16* Abl = Tl + (size_t)z*MSZ;
  const u16* Bbh = fh + (size_t)(z/3)*524288;
  const u16* Bbl = fl + (size_t)(z/3)*524288;
  const int m0 = blockIdx.y*128, n0 = blockIdx.x*128;
  const int tid = threadIdx.x;

  __shared__ __align__(16) u16 sAh[128*40], sAl[128*40];
  __shared__ __align__(16) u16 sBh[128*40], sBl[128*40];

  const int ra = tid >> 2, qa = tid & 3;
  const int kb = tid >> 4, gb = tid & 15;
  const int wid = tid >> 6, lane = tid & 63;
  const int wm = wid >> 1, wn = wid & 1;
  const int quad = lane >> 4, ln = lane & 15;

  f32x4 acc[4][4];
  #pragma unroll
  for (int i=0;i<4;i++)
    #pragma unroll
    for (int j=0;j<4;j++)
      #pragma unroll
      for (int e=0;e<4;e++) acc[i][j][e] = 0.f;

  for (int k0 = 0; k0 < 512; k0 += 32){
    *(bf16x8*)&sAh[ra*40 + qa*8]      = *(const bf16x8*)&Abh[(size_t)(m0+ra)*512    + k0 + qa*8];
    *(bf16x8*)&sAl[ra*40 + qa*8]      = *(const bf16x8*)&Abl[(size_t)(m0+ra)*512    + k0 + qa*8];
    *(bf16x8*)&sAh[(ra+64)*40 + qa*8] = *(const bf16x8*)&Abh[(size_t)(m0+ra+64)*512 + k0 + qa*8];
    *(bf16x8*)&sAl[(ra+64)*40 + qa*8] = *(const bf16x8*)&Abl[(size_t)(m0+ra+64)*512 + k0 + qa*8];
    {
      bf16x8 vh = *(const bf16x8*)&Bbh[(size_t)(k0+kb)*1024 + n0 + gb*8];
      bf16x8 vl = *(const bf16x8*)&Bbl[(size_t)(k0+kb)*1024 + n0 + gb*8];
      #pragma unroll
      for (int j=0;j<8;j++){
        sBh[(gb*8+j)*40 + kb] = (u16)vh[j];
        sBl[(gb*8+j)*40 + kb] = (u16)vl[j];
      }
      vh = *(const bf16x8*)&Bbh[(size_t)(k0+kb+16)*1024 + n0 + gb*8];
      vl = *(const bf16x8*)&Bbl[(size_t)(k0+kb+16)*1024 + n0 + gb*8];
      #pragma unroll
      for (int j=0;j<8;j++){
        sBh[(gb*8+j)*40 + kb+16] = (u16)vh[j];
        sBl[(gb*8+j)*40 + kb+16] = (u16)vl[j];
      }
    }
    __syncthreads();

    bf16x8 ah[4], al[4], bh[4], bl[4];
    #pragma unroll
    for (int t=0;t<4;t++){
      const int moA = ((wm*4+t)*16 + ln)*40 + quad*8;
      const int moB = ((wn*4+t)*16 + ln)*40 + quad*8;
      ah[t] = *(const bf16x8*)&sAh[moA];
      al[t] = *(const bf16x8*)&sAl[moA];
      bh[t] = *(const bf16x8*)&sBh[moB];
      bl[t] = *(const bf16x8*)&sBl[moB];
    }
    #pragma unroll
    for (int mi=0;mi<4;mi++)
      #pragma unroll
      for (int ni=0;ni<4;ni++){
        acc[mi][ni] = __builtin_amdgcn_mfma_f32_16x16x32_bf16(ah[mi], bh[ni], acc[mi][ni], 0, 0, 0);
        acc[mi][ni] = __builtin_amdgcn_mfma_f32_16x16x32_bf16(ah[mi], bl[ni], acc[mi][ni], 0, 0, 0);
        acc[mi][ni] = __builtin_amdgcn_mfma_f32_16x16x32_bf16(al[mi], bh[ni], acc[mi][ni], 0, 0, 0);
      }
    __syncthreads();
  }
  #pragma unroll
  for (int mi=0;mi<4;mi++){
    const int mbase = m0 + (wm*4+mi)*16 + quad*4;
    #pragma unroll
    for (int ni=0;ni<4;ni++){
      const int n = n0 + (wn*4+ni)*16 + ln;
      #pragma unroll
      for (int rg=0;rg<4;rg++){
        const int m = mbase + rg;
        Cf[(size_t)z*524288 + (size_t)m*1024 + n] = acc[mi][ni][rg];
      }
    }
  }
}

// generic fp32 -> split bf16
__global__ __launch_bounds__(256) void splitk(const float* __restrict__ src,
                                              u16* __restrict__ dh, u16* __restrict__ dl, int n4){
  int i = blockIdx.x*256 + threadIdx.x;
  if (i >= n4) return;
  float4 v4 = *(const float4*)&src[(size_t)i*4];
  float vv[4] = {v4.x, v4.y, v4.z, v4.w};
  u16x4 oh, ol;
  #pragma unroll
  for (int j=0;j<4;j++){
    u16 h = bf16_rne(vv[j]);
    oh[j] = (short)h;
    ol[j] = (short)bf16_rne(vv[j] - bf16f(h));
  }
  *(u16x4*)&dh[(size_t)i*4] = oh;
  *(u16x4*)&dl[(size_t)i*4] = ol;
}

__global__ void make_scalesk(const float* __restrict__ sval, float* __restrict__ scl){
  int i = threadIdx.x;
  if (i < 12) scl[i] = sqrtf(sval[12+i] / sval[i]);
}

// tvec[b] = mu_s[b] - T[b] @ mu_c[b]   (T in split form)
__global__ __launch_bounds__(512) void tveck(const u16* __restrict__ Th, const u16* __restrict__ Tl,
                                             const float* __restrict__ mu, float* __restrict__ tvec){
  int b = blockIdx.x; int c = threadIdx.x;
  __shared__ float mc[512];
  mc[c] = mu[(size_t)b*512 + c];
  __syncthreads();
  const u16* Trh = Th + ((size_t)b*512 + c)*512;
  const u16* Trl = Tl + ((size_t)b*512 + c)*512;
  float s = 0.f;
  for (int d=0; d<512; d++) s = fmaf(bf16f(Trh[d]) + bf16f(Trl[d]), mc[d], s);
  tvec[b*512 + c] = mu[(size_t)(12+b)*512 + c] - s;
}

__global__ __launch_bounds__(256) void selectk(const float* __restrict__ tpts, const float* __restrict__ tvec,
        const int* __restrict__ a, const float* __restrict__ f4c, float* __restrict__ tf){
  size_t idx = (size_t)blockIdx.x*256 + threadIdx.x;
  if (idx >= 2097152ul) return;
  int n = (int)(idx & 1023);
  int c = (int)((idx >> 10) & 511);
  int img = (int)(idx >> 19);
  int k = a[img*1024 + n];
  int b = img*3 + k;
  float v = tpts[((size_t)b*512 + c)*1024 + n] + tvec[b*512 + c];
  tf[idx] = 0.6f*v + 0.4f*f4c[idx];
}

__global__ __launch_bounds__(256) void clossk(const float* __restrict__ x, const float* __restrict__ y,
                                              int n, float* __restrict__ acc){
  int tid = threadIdx.x;
  float s = 0.f;
  for (size_t i = (size_t)blockIdx.x*256 + tid; i < (size_t)n; i += (size_t)gridDim.x*256){
    float d = x[i] - y[i]; s = fmaf(d, d, s);
  }
  __shared__ float sh[256];
  sh[tid] = s; __syncthreads();
  for (int k=128;k>0;k>>=1){ if (tid<k) sh[tid]+=sh[tid+k]; __syncthreads(); }
  if (tid==0) atomicAdd(acc, sh[0]);
}

__global__ __launch_bounds__(256) void finalk(const float* __restrict__ sm, float* __restrict__ out){
  int tid = threadIdx.x;
  const int cnts[4] = {256,512,1024,2048};
  const int offs[4] = {0,256,768,1792};
  const float* mS = sm + SM_STATS_S;
  const float* sS = sm + SM_STATS_S + 3840;
  const float* mD = sm + SM_STATS_D;
  const float* sD = sm + SM_STATS_D + 3840;
  double sl = 0.0;
  for (int L=0; L<4; ++L){
    int cnt = cnts[L], off = offs[L];
    double inv = 1.0/cnt;
    for (int i=tid; i<cnt; i+=256){
      double dm = (double)mD[off+i] - (double)mS[off+i];
      double ds = (double)sD[off+i] - (double)sS[off+i];
      sl += (dm*dm + ds*ds)*inv;
    }
  }
  __shared__ double sh[256];
  sh[tid] = sl; __syncthreads();
  for (int k=128;k>0;k>>=1){ if (tid<k) sh[tid]+=sh[tid+k]; __syncthreads(); }
  if (tid==0){
    double closs = (double)sm[SM_CLOSS] / 2097152.0;
    out[0] = (float)(closs + 0.01*sh[0]);
  }
}

// ---------------- host ----------------

extern "C" void kernel_launch(void* const* d_in, const int* in_sizes, int n_in,
                              void* d_out, int out_size, void* d_ws, size_t ws_size,
                              hipStream_t stream)
{
  const float* content = (const float*)d_in[0];
  const float* style   = (const float*)d_in[1];
  const float* Wm[8]; const float* Bm[8];
  for (int i=0;i<8;i++){ Wm[i] = (const float*)d_in[2+2*i]; Bm[i] = (const float*)d_in[3+2*i]; }
  float* out = (float*)d_out;
  float* ws = (float*)d_ws;

  float* f4c  = ws + OFF_F4C;
  float* f4s  = ws + OFF_F4S;
  float* tf   = ws + OFF_TF;
  float* dec  = ws + OFF_DEC;
  float* sm   = ws + OFF_SMALL;
  float* AR   = ws + OFF_ARENA;
  int*   aPtr = (int*)(sm + SM_ASSIGN);
  float* cent = sm + SM_CENT;
  float* mu   = sm + SM_MU;
  float* counts = sm + SM_COUNTS;
  float* sval = sm + SM_SVAL;
  float* scl  = sm + SM_SCALE;
  float* tvec = sm + SM_TVEC;
  float* trbuf = sm + SM_TR;

  // pre-split weights region
  u16* WB = (u16*)(ws + OFF_WSPL);
  u16 *w2h=WB+0,       *w2l=WB+73728;    // e2: 9*128*64
  u16 *w3h=WB+147456,  *w3l=WB+442368;   // e3: 9*256*128
  u16 *w4h=WB+737280,  *w4l=WB+1916928;  // e4: 9*512*256
  u16 *v1h=WB+3096576, *v1l=WB+4276224;  // d1: 9*256*512
  u16 *v2h=WB+5455872, *v2l=WB+5750784;  // d2: 9*128*256
  u16 *v3h=WB+6045696, *v3l=WB+6119424;  // d3: 9*64*128

  float* Ycov = AR;
  u16* Mh  = (u16*)(AR);
  u16* Ml  = (u16*)(AR + 3145728ul);
  u16* Yh  = (u16*)(AR + 6291456ul);
  u16* Yl  = (u16*)(AR + 9437184ul);
  u16* Zh  = (u16*)(AR + 12582912ul);
  u16* Zl  = (u16*)(AR + 15728640ul);
  u16* Y2h = (u16*)(AR + 18874368ul);
  u16* Y2l = (u16*)(AR + 22020096ul);
  u16* Z2h = (u16*)(AR + 25165824ul);
  u16* Z2l = (u16*)(AR + 28311552ul);
  u16* Ph  = (u16*)(AR + 18874368ul);   // aliases Y2 (dead before NS)
  u16* Pl  = (u16*)(AR + 25165824ul);   // aliases Z2
  float* ptsT = AR + 25165824ul;        // dead before maskcenterk writes Pl
  u16* Th  = (u16*)(AR + 18874368ul);   // post-NS (Y2/Z2 free)
  u16* Tl  = (u16*)(AR + 20971520ul);
  u16* fsh = (u16*)(AR + 23068672ul);
  u16* fsl = (u16*)(AR + 24117248ul);

  zerok<<<512,256,0,stream>>>(sm, 131072);

  // pre-split mid-layer weights
  {
    auto wsp = [&](int li, u16* wh, u16* wl, int Co, int Ci){
      int n = 9*Co*Ci;
      wsplitk<<<(n+255)/256,256,0,stream>>>(Wm[li], wh, wl, Co, Ci);
    };
    wsp(1,w2h,w2l,128,64);
    wsp(2,w3h,w3l,256,128);
    wsp(3,w4h,w4l,512,256);
    wsp(4,v1h,v1l,256,512);
    wsp(5,v2h,v2l,128,256);
    wsp(6,v3h,v3l,64,128);
  }

  auto conv = [&](const float* inp, int li, float* outp, int B,int Ci,int Co,int H,int Wd,int relu,int cot){
    dim3 g((H>>5)*(Wd>>5), (Co + cot - 1)/cot, B);
    if (cot==8) conv3x3<8><<<g,256,0,stream>>>(inp,Wm[li],Bm[li],outp,B,Ci,Co,H,Wd,relu);
    else        conv3x3<4><<<g,256,0,stream>>>(inp,Wm[li],Bm[li],outp,B,Ci,Co,H,Wd,relu);
  };
  auto convM = [&](const float* inp, int li, float* outp, int B,int Ci,int Co,int H,int Wd,int relu,int KS,float* part){
    const u16 *wh=nullptr,*wl=nullptr;
    switch(li){
      case 1: wh=w2h; wl=w2l; break;
      case 2: wh=w3h; wl=w3l; break;
      case 3: wh=w4h; wl=w4l; break;
      case 4: wh=v1h; wl=v1l; break;
      case 5: wh=v2h; wl=v2l; break;
      case 6: wh=v3h; wl=v3l; break;
    }
    int tiles = (H>>3)*(Wd>>3);
    if (KS==1){
      convm<1><<<dim3(tiles,Co>>6,B),256,0,stream>>>(inp,wh,wl,Bm[li],outp,Ci,Co,H,Wd,relu);
    } else {
      int n = B*Co*H*Wd;
      if (KS==2) convm<2><<<dim3(tiles,Co>>6,B*2),256,0,stream>>>(inp,wh,wl,nullptr,part,Ci,Co,H,Wd,relu);
      else       convm<4><<<dim3(tiles,Co>>6,B*4),256,0,stream>>>(inp,wh,wl,nullptr,part,Ci,Co,H,Wd,relu);
      sumk<<<(n+255)/256,256,0,stream>>>(part,Bm[li],outp,Co,H*Wd,KS,relu,n);
    }
  };
  auto pool = [&](const float* inp, float* outp, int B,int C,int Ho,int Wo){
    int n = B*C*Ho*Wo;
    pool2k<<<(n+255)/256,256,0,stream>>>(inp,outp,n,Ho,Wo);
  };
  auto up = [&](const float* inp, float* outp, int B,int C,int Ho,int Wo){
    int n = B*C*Ho*Wo;
    up2k<<<(n+255)/256,256,0,stream>>>(inp,outp,n,Ho,Wo);
  };

  float* mS = sm + SM_STATS_S;
  float* sS = sm + SM_STATS_S + 3840;

  // ---- batched content+style encode (B=8 from e2 down) ----
  float* F1   = AR + 0;          // 16.7M, one image-set at a time
  float* P1_8 = AR + 16777216ul; // 8.4M
  float* F2_8 = AR + 0;          // 16.7M
  float* P2_8 = AR + 25165824ul; // 4.2M
  float* F3_8 = AR + 0;          // 8.4M
  float* P3_8 = AR + 8388608ul;  // 2.1M
  float* PART8 = AR + 10485760ul;// 8.4M (e4 KS=2 partials)

  conv(content, 0, F1, 4, 3,64,256,256,1,8);
  pool(F1, P1_8, 4, 64,128,128);
  conv(style, 0, F1, 4, 3,64,256,256,1,8);
  statsk<<<256,256,0,stream>>>(F1,65536, mS+0, sS+0);
  pool(F1, P1_8 + 4194304ul, 4, 64,128,128);

  convM(P1_8, 1, F2_8, 8, 64,128,128,128,1,1,nullptr);
  statsk<<<512,256,0,stream>>>(F2_8 + 8388608ul, 16384, mS+256, sS+256);
  pool(F2_8, P2_8, 8, 128,64,64);
  convM(P2_8, 2, F3_8, 8, 128,256,64,64,1,1,nullptr);
  statsk<<<1024,256,0,stream>>>(F3_8 + 4194304ul, 4096, mS+768, sS+768);
  pool(F3_8, P3_8, 8, 256,32,32);
  convM(P3_8, 3, f4c /* [f4c|f4s] contiguous */, 8, 256,512,32,32,1,2,PART8);
  statsk<<<2048,256,0,stream>>>(f4s,1024, mS+1792, sS+1792);

  // ---- k-means (content r=0..3, style r=4..7) ----
  transposek<<<dim3(32,16,8),256,0,stream>>>(f4c,f4s,ptsT);
  initcentk<<<48,256,0,stream>>>(ptsT,cent);
  for (int it=0; it<10; ++it){
    assignk<<<2048,256,0,stream>>>(ptsT,cent,aPtr);
    updatek<0><<<dim3(8,16),256,0,stream>>>(ptsT,aPtr,cent,nullptr);
  }
  assignk<<<2048,256,0,stream>>>(ptsT,cent,aPtr);
  updatek<1><<<dim3(8,16),256,0,stream>>>(ptsT,aPtr,mu,counts);

  // ---- covariances via MFMA (trace accumulated into sval) ----
  maskcenterk<<<12288,256,0,stream>>>(f4c,f4s,aPtr,mu,Ph,Pl);
  covgemm<<<dim3(4,4,24),256,0,stream>>>(Ph,Pl,counts,Ycov,sval);
  nsinitk<<<24576,256,0,stream>>>(Ycov,sval,Yh,Yl,Zh,Zl);

  // ---- split-bf16 MFMA Newton-Schulz (trace-adaptive gamma, fused) ----
  u16 *Ych=Yh,*Ycl=Yl,*Zch=Zh,*Zcl=Zl,*Yah=Y2h,*Yal=Y2l,*Zah=Z2h,*Zal=Z2l;
  for (int it=0; it<NS_ITERS; ++it){
    bmms<0,1><<<dim3(4,4,24),256,0,stream>>>(Zch,Zcl,Ych,Ycl,Mh,Ml,nullptr,0,trbuf+it*24);
    bmmpair<<<dim3(4,4,48),256,0,stream>>>(Ych,Ycl,Mh,Ml,Zch,Zcl,Yah,Yal,Zah,Zal,trbuf+it*24);
    u16* t;
    t=Ych;Ych=Yah;Yah=t; t=Ycl;Ycl=Yal;Yal=t;
    t=Zch;Zch=Zah;Zah=t; t=Zcl;Zcl=Zal;Zal=t;
  }
  // T[b] = sqrt(t_s/t_c) * Y_style[b] @ Z_content[b]  (split out; NS_ITERS even -> Ych=Yh, Zch=Zh)
  make_scalesk<<<1,64,0,stream>>>(sval,scl);
  bmms<2,1><<<dim3(4,4,12),256,0,stream>>>(Ych,Ycl,Zch,Zcl,Th,Tl,scl,12,nullptr);
  tveck<<<12,512,0,stream>>>(Th,Tl,mu,tvec);
  // tpts[b] = T[b] @ f[img]
  splitk<<<2048,256,0,stream>>>(f4c,fsh,fsl,524288);
  float* Mb = AR + 0;
  bmmt<<<dim3(8,4,12),256,0,stream>>>(Th,Tl,fsh,fsl,Mb);
  selectk<<<8192,256,0,stream>>>(Mb,tvec,aPtr,f4c,tf);

  // ---- decode (B=4) ----
  float* X1 = AR + 0;
  float* U1 = AR + 1048576ul;
  float* X2 = AR + 5242880ul;
  float* U2 = AR + 7340032ul;
  float* X3 = AR + 0;
  float* U3 = AR + 4194304ul;
  float* PARTA = AR + 2097152ul;
  float* PARTB = AR + 7340032ul;
  convM(tf, 4, X1, 4, 512,256,32,32,1,4,PARTA);
  up(X1,U1, 4, 256,64,64);
  convM(U1,5,X2, 4, 256,128,64,64,1,2,PARTB);
  up(X2,U2, 4, 128,128,128);
  convM(U2,6,X3, 4, 128,64,128,128,1,1,nullptr);
  up(X3,U3, 4, 64,256,256);
  conv(U3,7,dec, 4, 64,3,256,256,0,4);

  // ---- decoded encode + stats + content loss (B=4) ----
  float* mD = sm + SM_STATS_D;
  float* sD = sm + SM_STATS_D + 3840;
  float* F1d = AR + 0;
  float* P1d = AR + 16777216ul;
  float* F2d = AR + 0;
  float* P2d = AR + 8388608ul;
  float* F3d = AR + 10485760ul;
  float* P3d = AR + 0;
  conv(dec, 0, F1d, 4, 3,64,256,256,1,8);
  statsk<<<256,256,0,stream>>>(F1d,65536, mD+0, sD+0);
  pool(F1d,P1d, 4, 64,128,128);
  convM(P1d,1,F2d, 4, 64,128,128,128,1,1,nullptr);
  statsk<<<512,256,0,stream>>>(F2d,16384, mD+256, sD+256);
  pool(F2d,P2d, 4, 128,64,64);
  convM(P2d,2,F3d, 4, 128,256,64,64,1,1,nullptr);
  statsk<<<1024,256,0,stream>>>(F3d,4096, mD+768, sD+768);
  pool(F3d,P3d, 4, 256,32,32);
  convM(P3d,3,tf, 4, 256,512,32,32,1,2,PARTA);   // f4(dec) reuses tf buffer
  statsk<<<2048,256,0,stream>>>(tf,1024, mD+1792, sD+1792);
  clossk<<<2048,256,0,stream>>>(tf,f4c,2097152, sm+SM_CLOSS);
  finalk<<<1,256,0,stream>>>(sm,out);
}

// Round 10
// 2926.786 us; speedup vs baseline: 2.3758x; 1.0571x over previous
//
#include <hip/hip_runtime.h>
#include <cstddef>

#define NS_ITERS 8
#define MSZ 262144  // 512*512
#define PL  6291456 // 24*MSZ
#define KSLOT 12312 // k-means accumulator slot stride (floats)

typedef unsigned short u16;
typedef __attribute__((ext_vector_type(8))) short bf16x8;
typedef __attribute__((ext_vector_type(4))) float f32x4;
typedef __attribute__((ext_vector_type(4))) short u16x4;

__device__ inline u16 bf16_rne(float x){
  unsigned u = __float_as_uint(x);
  unsigned r = u + 0x7fffu + ((u>>16)&1u);
  return (u16)(r>>16);
}
__device__ inline float bf16f(u16 h){
  return __uint_as_float(((unsigned)h)<<16);
}

// ---------------- workspace offsets (in floats) ----------------
#define OFF_F4C   0ul
#define OFF_F4S   2097152ul
#define OFF_TF    4194304ul
#define OFF_DEC   6291456ul
#define OFF_WSPL  7077888ul      // 3145728 floats: pre-split conv weights (u16 hi/lo)
#define OFF_SMALL 10223616ul
#define OFF_ARENA 10354688ul

// SMALL sub-offsets (floats)
#define SM_ASSIGN  12288
#define SM_MU      20480
#define SM_COUNTS  32768
#define SM_SVAL    32800        // 24: trace(Ycov) accumulators
#define SM_SCALE   32832
#define SM_TVEC    32864
#define SM_STATS_S 39008
#define SM_STATS_D 46688
#define SM_CLOSS   54368
#define SM_TR      54464        // 24*NS_ITERS trace-of-M accumulators

// ---------------- kernels ----------------

__global__ __launch_bounds__(256) void zerok(float* p, int n){
  int i = blockIdx.x*256 + threadIdx.x;
  if (i < n) p[i] = 0.f;
}

// direct 3x3 SAME conv (for e1: Cin=3, and d4: Cout=3 — tiny FLOPs, fp32 VALU is fine)
template<int COT>
__global__ __launch_bounds__(256) void conv3x3(
    const float* __restrict__ in, const float* __restrict__ wgt,
    const float* __restrict__ bias, float* __restrict__ out,
    int B, int Cin, int Cout, int H, int W, int relu)
{
  __shared__ float s_in[8][34][34];
  __shared__ float s_w[COT][8][9];
  const int tid = threadIdx.x;
  const int tx = tid & 15, ty = tid >> 4;
  const int tilesW = W >> 5;
  const int h0 = (blockIdx.x / tilesW) << 5;
  const int w0 = (blockIdx.x % tilesW) << 5;
  const int co0 = blockIdx.y * COT;
  const int b = blockIdx.z;
  float acc[COT][2][2];
  #pragma unroll
  for (int o=0;o<COT;o++){acc[o][0][0]=0.f;acc[o][0][1]=0.f;acc[o][1][0]=0.f;acc[o][1][1]=0.f;}
  const int y0 = ty*2, x0 = tx*2;
  for (int ci0 = 0; ci0 < Cin; ci0 += 8){
    const int cic = (Cin - ci0 < 8) ? (Cin - ci0) : 8;
    const int tot = cic*1156;
    for (int e = tid; e < tot; e += 256){
      int c = e / 1156; int r = e - c*1156;
      int lh = r / 34, lw = r - lh*34;
      int ih = h0 + lh - 1, iw = w0 + lw - 1;
      float v = 0.f;
      if ((unsigned)ih < (unsigned)H && (unsigned)iw < (unsigned)W)
        v = in[((size_t)(b*Cin + ci0 + c)*H + ih)*W + iw];
      s_in[c][lh][lw] = v;
    }
    const int wtot = COT*cic*9;
    for (int e = tid; e < wtot; e += 256){
      int o = e / (cic*9); int r = e - o*(cic*9);
      int c = r / 9, t = r - c*9;
      int co = co0 + o;
      float v = 0.f;
      if (co < Cout) v = wgt[(size_t)(co*Cin + ci0 + c)*9 + t];
      s_w[o][c][t] = v;
    }
    __syncthreads();
    for (int c = 0; c < cic; ++c){
      float p[4][4];
      #pragma unroll
      for (int r=0;r<4;r++)
        #pragma unroll
        for (int s=0;s<4;s++)
          p[r][s] = s_in[c][y0+r][x0+s];
      #pragma unroll
      for (int dh=0; dh<3; dh++)
        #pragma unroll
        for (int dw=0; dw<3; dw++){
          #pragma unroll
          for (int o=0;o<COT;o++){
            float wv = s_w[o][c][dh*3+dw];
            acc[o][0][0] = fmaf(p[dh  ][dw  ], wv, acc[o][0][0]);
            acc[o][0][1] = fmaf(p[dh  ][dw+1], wv, acc[o][0][1]);
            acc[o][1][0] = fmaf(p[dh+1][dw  ], wv, acc[o][1][0]);
            acc[o][1][1] = fmaf(p[dh+1][dw+1], wv, acc[o][1][1]);
          }
        }
    }
    __syncthreads();
  }
  #pragma unroll
  for (int o=0;o<COT;o++){
    int co = co0 + o;
    if (co >= Cout) continue;
    float bv = bias[co];
    #pragma unroll
    for (int r=0;r<2;r++)
      #pragma unroll
      for (int s=0;s<2;s++){
        float v = acc[o][r][s] + bv;
        if (relu) v = fmaxf(v, 0.f);
        out[((size_t)(b*Cout + co)*H + h0+y0+r)*W + w0+x0+s] = v;
      }
  }
}

// pre-split conv weights: dst[(dhw*Cout + co)*Cin + ci] = split(wgt[(co*Cin+ci)*9 + dhw])
__global__ __launch_bounds__(256) void wsplitk(const float* __restrict__ wgt,
                                               u16* __restrict__ dh_, u16* __restrict__ dl_,
                                               int Cout, int Cin){
  int idx = blockIdx.x*256 + threadIdx.x;
  int n = 9*Cout*Cin;
  if (idx >= n) return;
  int cc = Cout*Cin;
  int dhw = idx / cc;
  int r = idx - dhw*cc;
  int co = r / Cin, ci = r - co*Cin;
  float v = wgt[((size_t)co*Cin + ci)*9 + dhw];
  u16 h = bf16_rne(v);
  dh_[idx] = h;
  dl_[idx] = bf16_rne(v - bf16f(h));
}

// ---- split-bf16 MFMA direct conv 3x3 SAME; requires Cin%(32*KS)==0, Cout%64==0 ----
// KS>1: blockIdx.z = b*KS + ks; writes fp32 partial [ks][b][Cout][H][W]; sumk reduces.
template<int KS>
__global__ __launch_bounds__(256) void convm(
    const float* __restrict__ in, const u16* __restrict__ wsh, const u16* __restrict__ wsl,
    const float* __restrict__ bias, float* __restrict__ out,
    int Cin, int Cout, int H, int W, int relu)
{
  const int tilesW = W >> 3;
  const int h0 = (blockIdx.x / tilesW) << 3;
  const int w0 = (blockIdx.x % tilesW) << 3;
  const int co0 = blockIdx.y << 6;
  const int b  = blockIdx.z / KS;
  const int ks = blockIdx.z % KS;
  const int NB = gridDim.z / KS;
  const int tid = threadIdx.x;
  const int wid = tid >> 6, lane = tid & 63;
  const int wm = wid >> 1, wn = wid & 1;
  const int quad = lane >> 4, ln = lane & 15;

  __shared__ __align__(16) u16 sXh[100*40], sXl[100*40];
  __shared__ __align__(16) u16 sWh[3*64*40], sWl[3*64*40];

  f32x4 acc[2][2];
  #pragma unroll
  for (int i=0;i<2;i++)
    #pragma unroll
    for (int j=0;j<2;j++)
      #pragma unroll
      for (int e=0;e<4;e++) acc[i][j][e] = 0.f;

  const int ciA = ks*(Cin/KS), ciB = ciA + Cin/KS;
  for (int ci0 = ciA; ci0 < ciB; ci0 += 32){
    __syncthreads();
    for (int e = tid; e < 3200; e += 256){
      int ci = e / 100, px = e - ci*100;
      int pr = px / 10, pc = px - pr*10;
      int ih = h0 + pr - 1, iw = w0 + pc - 1;
      float v = 0.f;
      if ((unsigned)ih < (unsigned)H && (unsigned)iw < (unsigned)W)
        v = in[((size_t)(b*Cin + ci0+ci)*H + ih)*W + iw];
      u16 h = bf16_rne(v);
      sXh[px*40 + ci] = h;
      sXl[px*40 + ci] = bf16_rne(v - bf16f(h));
    }
    for (int dh = 0; dh < 3; ++dh){
      if (dh) __syncthreads();
      for (int e2 = tid; e2 < 768; e2 += 256){
        int dw = e2 >> 8, r = e2 & 255;
        int co = r >> 2, cg = (r & 3) << 3;
        size_t so = ((size_t)((dh*3+dw)*Cout + co0+co))*Cin + ci0 + cg;
        int dsto = (dw*64+co)*40 + cg;
        *(bf16x8*)&sWh[dsto] = *(const bf16x8*)&wsh[so];
        *(bf16x8*)&sWl[dsto] = *(const bf16x8*)&wsl[so];
      }
      __syncthreads();
      #pragma unroll
      for (int dw = 0; dw < 3; ++dw){
        bf16x8 ah[2], al[2], bh[2], bl[2];
        #pragma unroll
        for (int t=0;t<2;t++){
          const int co_l = (wm*2+t)*16 + ln;
          const int wo = (dw*64 + co_l)*40 + quad*8;
          ah[t] = *(const bf16x8*)&sWh[wo];
          al[t] = *(const bf16x8*)&sWl[wo];
          const int p = (wn*2+t)*16 + ln;
          const int px = ((p>>3) + dh)*10 + (p&7) + dw;
          const int xo = px*40 + quad*8;
          bh[t] = *(const bf16x8*)&sXh[xo];
          bl[t] = *(const bf16x8*)&sXl[xo];
        }
        #pragma unroll
        for (int mi=0;mi<2;mi++)
          #pragma unroll
          for (int ni=0;ni<2;ni++){
            acc[mi][ni] = __builtin_amdgcn_mfma_f32_16x16x32_bf16(ah[mi], bh[ni], acc[mi][ni], 0, 0, 0);
            acc[mi][ni] = __builtin_amdgcn_mfma_f32_16x16x32_bf16(ah[mi], bl[ni], acc[mi][ni], 0, 0, 0);
            acc[mi][ni] = __builtin_amdgcn_mfma_f32_16x16x32_bf16(al[mi], bh[ni], acc[mi][ni], 0, 0, 0);
          }
      }
    }
  }
  #pragma unroll
  for (int mi=0;mi<2;mi++){
    const int co = co0 + (wm*2+mi)*16 + quad*4;
    #pragma unroll
    for (int ni=0;ni<2;ni++){
      const int p = (wn*2+ni)*16 + ln;
      const int oh = h0 + (p>>3), ow = w0 + (p&7);
      #pragma unroll
      for (int rg=0; rg<4; rg++){
        const int cog = co + rg;
        if constexpr (KS==1){
          float v = acc[mi][ni][rg] + bias[cog];
          if (relu) v = fmaxf(v, 0.f);
          out[((size_t)(b*Cout + cog)*H + oh)*W + ow] = v;
        } else {
          out[((size_t)((ks*NB + b)*Cout + cog)*H + oh)*W + ow] = acc[mi][ni][rg];
        }
      }
    }
  }
}

// reduce split-K partials + bias + relu
__global__ __launch_bounds__(256) void sumk(const float* __restrict__ part, const float* __restrict__ bias,
                                            float* __restrict__ out, int Cout, int HW, int KS, int relu, int n){
  int idx = blockIdx.x*256 + threadIdx.x;
  if (idx >= n) return;
  int co = (idx / HW) % Cout;
  float v = bias[co];
  for (int k=0;k<KS;k++) v += part[(size_t)k*n + idx];
  if (relu) v = fmaxf(v, 0.f);
  out[idx] = v;
}

__global__ __launch_bounds__(256) void pool2k(const float* __restrict__ in, float* __restrict__ out,
                                              int n, int Ho, int Wo){
  int idx = blockIdx.x*256 + threadIdx.x;
  if (idx >= n) return;
  int wo = idx % Wo; int t = idx / Wo; int ho = t % Ho; int bc = t / Ho;
  const float* p = in + ((size_t)bc*(Ho*2) + ho*2)*(size_t)(Wo*2) + (size_t)wo*2;
  out[idx] = 0.25f*(p[0] + p[1] + p[2*Wo] + p[2*Wo+1]);
}

__global__ __launch_bounds__(256) void up2k(const float* __restrict__ in, float* __restrict__ out,
                                            int n, int Ho, int Wo){
  int idx = blockIdx.x*256 + threadIdx.x;
  if (idx >= n) return;
  int wo = idx % Wo; int t = idx / Wo; int ho = t % Ho; int bc = t / Ho;
  int Hi = Ho >> 1, Wi = Wo >> 1;
  out[idx] = in[((size_t)bc*Hi + (ho>>1))*Wi + (wo>>1)];
}

// per-(b,c) spatial mean & std (ddof=0)
__global__ __launch_bounds__(256) void statsk(const float* __restrict__ x, int HW,
                                              float* __restrict__ mo, float* __restrict__ so){
  int bc = blockIdx.x, tid = threadIdx.x;
  const float* p = x + (size_t)bc*HW;
  double s = 0.0, s2 = 0.0;
  for (int i = tid; i < HW; i += 256){ double v = p[i]; s += v; s2 += v*v; }
  __shared__ double sh[256], sh2[256];
  sh[tid] = s; sh2[tid] = s2; __syncthreads();
  for (int k=128;k>0;k>>=1){ if (tid<k){ sh[tid]+=sh[tid+k]; sh2[tid]+=sh2[tid+k]; } __syncthreads(); }
  if (tid == 0){
    double m = sh[0]/HW;
    double var = sh2[0]/HW - m*m;
    if (var < 0.0) var = 0.0;
    mo[bc] = (float)m;
    so[bc] = (float)sqrt(var);
  }
}

// f4 (C-major, per image 512x1024) -> ptsT [8][1024][512]
__global__ __launch_bounds__(256) void transposek(const float* __restrict__ f4c,
                                                  const float* __restrict__ f4s,
                                                  float* __restrict__ ptsT){
  __shared__ float t[32][33];
  int r = blockIdx.z;
  const float* src = (r < 4) ? (f4c + (size_t)r*524288) : (f4s + (size_t)(r-4)*524288);
  int n0 = blockIdx.x*32, c0 = blockIdx.y*32;
  int lx = threadIdx.x & 31, ly = threadIdx.x >> 5;
  for (int j=0;j<32;j+=8)
    t[ly+j][lx] = src[(size_t)(c0+ly+j)*1024 + n0+lx];
  __syncthreads();
  for (int j=0;j<32;j+=8)
    ptsT[((size_t)r*1024 + n0+ly+j)*512 + c0+lx] = t[lx][ly+j];
}

// slot0 init: sums = first 3 points (centroids), counts = 1
__global__ __launch_bounds__(256) void initcent2k(const float* __restrict__ ptsT, float* __restrict__ KACC){
  int i = blockIdx.x*256 + threadIdx.x;
  if (i < 12288){
    int c = i & 511; int k = (i >> 9) % 3; int r = i / 1536;
    KACC[r*1536 + k*512 + c] = ptsT[((size_t)r*1024 + k)*512 + c];
  }
  if (i < 24) KACC[12288 + i] = 1.f;
}

// fused k-means step: build centroids from prev slot, assign 32 points, accumulate next slot.
// grid (r=8, slice=32), 256 thr.
__global__ __launch_bounds__(256) void kstepk(const float* __restrict__ ptsT,
    const float* __restrict__ prev, float* __restrict__ next,
    int* __restrict__ a, int nodiv)
{
  const int r = blockIdx.x, sl = blockIdx.y;
  const int tid = threadIdx.x;
  __shared__ float sc[1536];
  __shared__ int sa[32];
  __shared__ float red[3][8][32];
  __shared__ int scnt[3];
  if (tid < 3) scnt[tid] = 0;
  for (int i = tid; i < 1536; i += 256){
    float s = prev[r*1536 + i];
    float cnt = nodiv ? 1.f : (prev[12288 + r*3 + (i>>9)] + 1e-6f);
    sc[i] = s / cnt;
  }
  __syncthreads();
  const float* base = ptsT + (size_t)r*524288;
  const int wid = tid >> 6, lane = tid & 63;
  for (int rep = 0; rep < 8; ++rep){
    int p = wid*8 + rep;
    int n = sl*32 + p;
    const float* pp = base + (size_t)n*512;
    float d0=0.f,d1=0.f,d2=0.f;
    #pragma unroll
    for (int i=0;i<8;i++){
      int c = lane + i*64;
      float v = pp[c];
      float e0 = v - sc[c], e1 = v - sc[512+c], e2 = v - sc[1024+c];
      d0 = fmaf(e0,e0,d0); d1 = fmaf(e1,e1,d1); d2 = fmaf(e2,e2,d2);
    }
    #pragma unroll
    for (int off=32; off>0; off>>=1){
      d0 += __shfl_down(d0, off, 64);
      d1 += __shfl_down(d1, off, 64);
      d2 += __shfl_down(d2, off, 64);
    }
    if (lane == 0){
      int bi = 0; float bd = d0;
      if (d1 < bd){ bd = d1; bi = 1; }
      if (d2 < bd){ bd = d2; bi = 2; }
      sa[p] = bi;
      a[r*1024 + n] = bi;
    }
  }
  __syncthreads();
  if (tid < 32) atomicAdd(&scnt[sa[tid]], 1);
  __syncthreads();
  if (tid < 3) atomicAdd(&next[12288 + r*3 + tid], (float)scnt[tid]);
  const int g = tid >> 5, lc = tid & 31;
  for (int cj = 0; cj < 16; ++cj){
    int c = cj*32 + lc;
    float s0=0.f,s1=0.f,s2=0.f;
    #pragma unroll
    for (int q=0;q<4;q++){
      int nl = g*4 + q;
      float v = base[(size_t)(sl*32+nl)*512 + c];
      int an = sa[nl];
      s0 += (an==0)?v:0.f;
      s1 += (an==1)?v:0.f;
      s2 += (an==2)?v:0.f;
    }
    red[0][g][lc]=s0; red[1][g][lc]=s1; red[2][g][lc]=s2;
    __syncthreads();
    if (g == 0){
      float t0=0.f,t1=0.f,t2=0.f;
      #pragma unroll
      for (int q2=0;q2<8;q2++){ t0+=red[0][q2][lc]; t1+=red[1][q2][lc]; t2+=red[2][q2][lc]; }
      atomicAdd(&next[r*1536 +          c], t0);
      atomicAdd(&next[r*1536 +  512 +   c], t1);
      atomicAdd(&next[r*1536 + 1024 +   c], t2);
    }
    __syncthreads();
  }
}

// final mu/counts from slot 11
__global__ __launch_bounds__(256) void mufink(const float* __restrict__ slot,
                                              float* __restrict__ mu, float* __restrict__ counts){
  int i = blockIdx.x*256 + threadIdx.x;
  if (i >= 12288) return;
  int c = i & 511; int k = (i >> 9) % 3; int r = i / 1536;
  int cs = r >> 2, img = r & 3;
  int i0 = cs*12 + img*3;
  float cnt = slot[12288 + r*3 + k];
  mu[(size_t)(i0+k)*512 + c] = slot[r*1536 + k*512 + c] / (cnt + 1e-6f);
  if (c == 0) counts[i0+k] = cnt;
}

// masked centered split planes: P[z][c][n] = (a[n]==k) ? pts[c][n]-mu[z][c] : 0
__global__ __launch_bounds__(256) void maskcenterk(const float* __restrict__ f4c, const float* __restrict__ f4s,
        const int* __restrict__ a, const float* __restrict__ mu,
        u16* __restrict__ Ph, u16* __restrict__ Pl){
  size_t i4 = ((size_t)blockIdx.x*256 + threadIdx.x)*4;
  if (i4 >= (size_t)PL*2) return;   // total elems = 24*512*1024
  int z = (int)(i4 >> 19);
  int rc = (int)(i4 & 524287);
  int c = rc >> 10, n = rc & 1023;
  int cs = z / 12; int rem = z - cs*12; int img = rem / 3; int k = rem - img*3;
  const float* pts = (cs ? f4s : f4c) + (size_t)img*524288;
  float m = mu[(size_t)z*512 + c];
  const int* an = a + (cs*4 + img)*1024 + n;
  float4 v4 = *(const float4*)&pts[(size_t)c*1024 + n];
  float vv[4] = {v4.x, v4.y, v4.z, v4.w};
  u16x4 oh, ol;
  #pragma unroll
  for (int j=0;j<4;j++){
    float v = (an[j] == k) ? (vv[j] - m) : 0.f;
    u16 h = bf16_rne(v);
    oh[j] = (short)h;
    ol[j] = (short)bf16_rne(v - bf16f(h));
  }
  *(u16x4*)&Ph[i4] = oh;
  *(u16x4*)&Pl[i4] = ol;
}

// covariance via MFMA: Ycov[z] = P[z] @ P[z]^T / nc + 0.1 I  (K=1024); diag blocks
// also accumulate trace(Ycov[z]) into trsum[z] (pre-zeroed).
__global__ __launch_bounds__(256) void covgemm(const u16* __restrict__ Ph, const u16* __restrict__ Pl,
        const float* __restrict__ counts, float* __restrict__ Ycov, float* __restrict__ trsum){
  const int z = blockIdx.z;
  const u16* Pbh = Ph + (size_t)z*524288;
  const u16* Pbl = Pl + (size_t)z*524288;
  const int m0 = blockIdx.y*128, n0 = blockIdx.x*128;
  const int tid = threadIdx.x;

  __shared__ __align__(16) u16 sAh[128*40], sAl[128*40];
  __shared__ __align__(16) u16 sBh[128*40], sBl[128*40];

  const int ra = tid >> 2, qa = tid & 3;
  const int wid = tid >> 6, lane = tid & 63;
  const int wm = wid >> 1, wn = wid & 1;
  const int quad = lane >> 4, ln = lane & 15;

  f32x4 acc[4][4];
  #pragma unroll
  for (int i=0;i<4;i++)
    #pragma unroll
    for (int j=0;j<4;j++)
      #pragma unroll
      for (int e=0;e<4;e++) acc[i][j][e] = 0.f;

  for (int k0 = 0; k0 < 1024; k0 += 32){
    *(bf16x8*)&sAh[ra*40 + qa*8]      = *(const bf16x8*)&Pbh[(size_t)(m0+ra)*1024    + k0 + qa*8];
    *(bf16x8*)&sAl[ra*40 + qa*8]      = *(const bf16x8*)&Pbl[(size_t)(m0+ra)*1024    + k0 + qa*8];
    *(bf16x8*)&sAh[(ra+64)*40 + qa*8] = *(const bf16x8*)&Pbh[(size_t)(m0+ra+64)*1024 + k0 + qa*8];
    *(bf16x8*)&sAl[(ra+64)*40 + qa*8] = *(const bf16x8*)&Pbl[(size_t)(m0+ra+64)*1024 + k0 + qa*8];
    *(bf16x8*)&sBh[ra*40 + qa*8]      = *(const bf16x8*)&Pbh[(size_t)(n0+ra)*1024    + k0 + qa*8];
    *(bf16x8*)&sBl[ra*40 + qa*8]      = *(const bf16x8*)&Pbl[(size_t)(n0+ra)*1024    + k0 + qa*8];
    *(bf16x8*)&sBh[(ra+64)*40 + qa*8] = *(const bf16x8*)&Pbh[(size_t)(n0+ra+64)*1024 + k0 + qa*8];
    *(bf16x8*)&sBl[(ra+64)*40 + qa*8] = *(const bf16x8*)&Pbl[(size_t)(n0+ra+64)*1024 + k0 + qa*8];
    __syncthreads();

    bf16x8 ah[4], al[4], bh[4], bl[4];
    #pragma unroll
    for (int t=0;t<4;t++){
      const int moA = ((wm*4+t)*16 + ln)*40 + quad*8;
      const int moB = ((wn*4+t)*16 + ln)*40 + quad*8;
      ah[t] = *(const bf16x8*)&sAh[moA];
      al[t] = *(const bf16x8*)&sAl[moA];
      bh[t] = *(const bf16x8*)&sBh[moB];
      bl[t] = *(const bf16x8*)&sBl[moB];
    }
    #pragma unroll
    for (int mi=0;mi<4;mi++)
      #pragma unroll
      for (int ni=0;ni<4;ni++){
        acc[mi][ni] = __builtin_amdgcn_mfma_f32_16x16x32_bf16(ah[mi], bh[ni], acc[mi][ni], 0, 0, 0);
        acc[mi][ni] = __builtin_amdgcn_mfma_f32_16x16x32_bf16(ah[mi], bl[ni], acc[mi][ni], 0, 0, 0);
        acc[mi][ni] = __builtin_amdgcn_mfma_f32_16x16x32_bf16(al[mi], bh[ni], acc[mi][ni], 0, 0, 0);
      }
    __syncthreads();
  }
  const float inv = 1.f/(counts[z] + 1e-6f);
  float dsum = 0.f; bool anyd = false;
  #pragma unroll
  for (int mi=0;mi<4;mi++){
    const int mbase = m0 + (wm*4+mi)*16 + quad*4;
    #pragma unroll
    for (int ni=0;ni<4;ni++){
      const int n = n0 + (wn*4+ni)*16 + ln;
      #pragma unroll
      for (int rg=0;rg<4;rg++){
        const int m = mbase + rg;
        float v = acc[mi][ni][rg]*inv + ((m==n)?0.1f:0.f);
        Ycov[(size_t)z*MSZ + (size_t)m*512 + n] = v;
        if (m0==n0 && m==n){ dsum += v; anyd = true; }
      }
    }
  }
  if (anyd) atomicAdd(&trsum[z], dsum);
}

// init split planes: Y = Ycov/trace (hi+lo bf16), Z = I
__global__ __launch_bounds__(256) void nsinitk(const float* __restrict__ Ycov, const float* __restrict__ sval,
                                               u16* __restrict__ Yh, u16* __restrict__ Yl,
                                               u16* __restrict__ Zh, u16* __restrict__ Zl){
  size_t idx = (size_t)blockIdx.x*256 + threadIdx.x;
  if (idx >= (size_t)PL) return;
  int z = (int)(idx >> 18);
  int rc = (int)(idx & (MSZ-1));
  int rr = rc >> 9, cc = rc & 511;
  float y = Ycov[idx] / sval[z];
  u16 h = bf16_rne(y);
  Yh[idx] = h;
  Yl[idx] = bf16_rne(y - bf16f(h));
  Zh[idx] = (rr==cc) ? (u16)0x3F80 : (u16)0;
  Zl[idx] = 0;
}

// ---- split-bf16 MFMA batched GEMM 512x512x512 ----
// SYMB=1: B symmetric -> stage B^T tile as contiguous B rows
// MODE 0: C = A@B (+ trace accumulation into trAcc[z] if trAcc) ; MODE 2: C = osc*(A@B)
template<int MODE, int SYMB>
__global__ __launch_bounds__(256) void bmms(
    const u16* __restrict__ Ah, const u16* __restrict__ Al,
    const u16* __restrict__ Bh, const u16* __restrict__ Bl,
    u16* __restrict__ Ch, u16* __restrict__ Cl,
    const float* __restrict__ osc,
    int aoff, float* __restrict__ trAcc)
{
  const int z = blockIdx.z;
  const u16* Abh = Ah + (size_t)(z+aoff)*MSZ;
  const u16* Abl = Al + (size_t)(z+aoff)*MSZ;
  const u16* Bbh = Bh + (size_t)z*MSZ;
  const u16* Bbl = Bl + (size_t)z*MSZ;
  const int m0 = blockIdx.y*128, n0 = blockIdx.x*128;
  const int tid = threadIdx.x;

  __shared__ __align__(16) u16 sAh[128*40], sAl[128*40];
  __shared__ __align__(16) u16 sBh[128*40], sBl[128*40];

  const int ra = tid >> 2, qa = tid & 3;
  const int kb = tid >> 4, gb = tid & 15;

  const int wid = tid >> 6, lane = tid & 63;
  const int wm = wid >> 1, wn = wid & 1;
  const int quad = lane >> 4, ln = lane & 15;

  f32x4 acc[4][4];
  #pragma unroll
  for (int i=0;i<4;i++)
    #pragma unroll
    for (int j=0;j<4;j++)
      #pragma unroll
      for (int e=0;e<4;e++) acc[i][j][e] = 0.f;

  for (int k0 = 0; k0 < 512; k0 += 32){
    *(bf16x8*)&sAh[ra*40 + qa*8]      = *(const bf16x8*)&Abh[(size_t)(m0+ra)*512    + k0 + qa*8];
    *(bf16x8*)&sAl[ra*40 + qa*8]      = *(const bf16x8*)&Abl[(size_t)(m0+ra)*512    + k0 + qa*8];
    *(bf16x8*)&sAh[(ra+64)*40 + qa*8] = *(const bf16x8*)&Abh[(size_t)(m0+ra+64)*512 + k0 + qa*8];
    *(bf16x8*)&sAl[(ra+64)*40 + qa*8] = *(const bf16x8*)&Abl[(size_t)(m0+ra+64)*512 + k0 + qa*8];
    if constexpr (SYMB){
      *(bf16x8*)&sBh[ra*40 + qa*8]      = *(const bf16x8*)&Bbh[(size_t)(n0+ra)*512    + k0 + qa*8];
      *(bf16x8*)&sBl[ra*40 + qa*8]      = *(const bf16x8*)&Bbl[(size_t)(n0+ra)*512    + k0 + qa*8];
      *(bf16x8*)&sBh[(ra+64)*40 + qa*8] = *(const bf16x8*)&Bbh[(size_t)(n0+ra+64)*512 + k0 + qa*8];
      *(bf16x8*)&sBl[(ra+64)*40 + qa*8] = *(const bf16x8*)&Bbl[(size_t)(n0+ra+64)*512 + k0 + qa*8];
    } else {
      bf16x8 vh = *(const bf16x8*)&Bbh[(size_t)(k0+kb)*512 + n0 + gb*8];
      bf16x8 vl = *(const bf16x8*)&Bbl[(size_t)(k0+kb)*512 + n0 + gb*8];
      #pragma unroll
      for (int j=0;j<8;j++){
        sBh[(gb*8+j)*40 + kb] = (u16)vh[j];
        sBl[(gb*8+j)*40 + kb] = (u16)vl[j];
      }
      vh = *(const bf16x8*)&Bbh[(size_t)(k0+kb+16)*512 + n0 + gb*8];
      vl = *(const bf16x8*)&Bbl[(size_t)(k0+kb+16)*512 + n0 + gb*8];
      #pragma unroll
      for (int j=0;j<8;j++){
        sBh[(gb*8+j)*40 + kb+16] = (u16)vh[j];
        sBl[(gb*8+j)*40 + kb+16] = (u16)vl[j];
      }
    }
    __syncthreads();

    bf16x8 ah[4], al[4], bh[4], bl[4];
    #pragma unroll
    for (int t=0;t<4;t++){
      const int moA = ((wm*4+t)*16 + ln)*40 + quad*8;
      const int moB = ((wn*4+t)*16 + ln)*40 + quad*8;
      ah[t] = *(const bf16x8*)&sAh[moA];
      al[t] = *(const bf16x8*)&sAl[moA];
      bh[t] = *(const bf16x8*)&sBh[moB];
      bl[t] = *(const bf16x8*)&sBl[moB];
    }
    #pragma unroll
    for (int mi=0;mi<4;mi++)
      #pragma unroll
      for (int ni=0;ni<4;ni++){
        acc[mi][ni] = __builtin_amdgcn_mfma_f32_16x16x32_bf16(ah[mi], bh[ni], acc[mi][ni], 0, 0, 0);
        acc[mi][ni] = __builtin_amdgcn_mfma_f32_16x16x32_bf16(ah[mi], bl[ni], acc[mi][ni], 0, 0, 0);
        acc[mi][ni] = __builtin_amdgcn_mfma_f32_16x16x32_bf16(al[mi], bh[ni], acc[mi][ni], 0, 0, 0);
      }
    __syncthreads();
  }

  float alpha = 1.f;
  if constexpr (MODE==2){ alpha = osc[z]; }

  float dsum = 0.f; bool anyd = false;
  #pragma unroll
  for (int mi=0;mi<4;mi++){
    const int mbase = m0 + (wm*4+mi)*16 + quad*4;
    #pragma unroll
    for (int ni=0;ni<4;ni++){
      const int n = n0 + (wn*4+ni)*16 + ln;
      #pragma unroll
      for (int rg=0;rg<4;rg++){
        const int m = mbase + rg;
        const size_t off = (size_t)z*MSZ + (size_t)m*512 + n;
        float v = alpha*acc[mi][ni][rg];
        u16 h = bf16_rne(v);
        Ch[off] = h;
        Cl[off] = bf16_rne(v - bf16f(h));
        if (MODE==0 && trAcc && m0==n0 && m==n){ dsum += v; anyd = true; }
      }
    }
  }
  if (MODE==0 && anyd) atomicAdd(&trAcc[z], dsum);
}

// merged NS update: z<24 -> Y2 = os*(3Y - g*(Y@M)); z>=24 -> Z2 = os*(3Z - g*(M@Z))
// g/os computed inline from trAcc[zz] = trace(M)
__global__ __launch_bounds__(256) void bmmpair(
    const u16* __restrict__ Yh, const u16* __restrict__ Yl,
    const u16* __restrict__ Mh, const u16* __restrict__ Ml,
    const u16* __restrict__ Zh, const u16* __restrict__ Zl,
    u16* __restrict__ Y2h, u16* __restrict__ Y2l,
    u16* __restrict__ Z2h, u16* __restrict__ Z2l,
    const float* __restrict__ trAcc)
{
  const int z = blockIdx.z;
  const int zz = (z < 24) ? z : (z - 24);
  const size_t zo = (size_t)zz*MSZ;
  const u16 *Abh, *Abl, *Bbh, *Bbl, *Dbh, *Dbl;
  u16 *Cbh, *Cbl;
  if (z < 24){
    Abh = Yh + zo; Abl = Yl + zo;
    Bbh = Mh + zo; Bbl = Ml + zo;
    Dbh = Yh + zo; Dbl = Yl + zo;
    Cbh = Y2h + zo; Cbl = Y2l + zo;
  } else {
    Abh = Mh + zo; Abl = Ml + zo;
    Bbh = Zh + zo; Bbl = Zl + zo;
    Dbh = Zh + zo; Dbl = Zl + zo;
    Cbh = Z2h + zo; Cbl = Z2l + zo;
  }
  const int m0 = blockIdx.y*128, n0 = blockIdx.x*128;
  const int tid = threadIdx.x;

  __shared__ __align__(16) u16 sAh[128*40], sAl[128*40];
  __shared__ __align__(16) u16 sBh[128*40], sBl[128*40];

  const int ra = tid >> 2, qa = tid & 3;
  const int wid = tid >> 6, lane = tid & 63;
  const int wm = wid >> 1, wn = wid & 1;
  const int quad = lane >> 4, ln = lane & 15;

  f32x4 acc[4][4];
  #pragma unroll
  for (int i=0;i<4;i++)
    #pragma unroll
    for (int j=0;j<4;j++)
      #pragma unroll
      for (int e=0;e<4;e++) acc[i][j][e] = 0.f;

  for (int k0 = 0; k0 < 512; k0 += 32){
    *(bf16x8*)&sAh[ra*40 + qa*8]      = *(const bf16x8*)&Abh[(size_t)(m0+ra)*512    + k0 + qa*8];
    *(bf16x8*)&sAl[ra*40 + qa*8]      = *(const bf16x8*)&Abl[(size_t)(m0+ra)*512    + k0 + qa*8];
    *(bf16x8*)&sAh[(ra+64)*40 + qa*8] = *(const bf16x8*)&Abh[(size_t)(m0+ra+64)*512 + k0 + qa*8];
    *(bf16x8*)&sAl[(ra+64)*40 + qa*8] = *(const bf16x8*)&Abl[(size_t)(m0+ra+64)*512 + k0 + qa*8];
    *(bf16x8*)&sBh[ra*40 + qa*8]      = *(const bf16x8*)&Bbh[(size_t)(n0+ra)*512    + k0 + qa*8];
    *(bf16x8*)&sBl[ra*40 + qa*8]      = *(const bf16x8*)&Bbl[(size_t)(n0+ra)*512    + k0 + qa*8];
    *(bf16x8*)&sBh[(ra+64)*40 + qa*8] = *(const bf16x8*)&Bbh[(size_t)(n0+ra+64)*512 + k0 + qa*8];
    *(bf16x8*)&sBl[(ra+64)*40 + qa*8] = *(const bf16x8*)&Bbl[(size_t)(n0+ra+64)*512 + k0 + qa*8];
    __syncthreads();

    bf16x8 ah[4], al[4], bh[4], bl[4];
    #pragma unroll
    for (int t=0;t<4;t++){
      const int moA = ((wm*4+t)*16 + ln)*40 + quad*8;
      const int moB = ((wn*4+t)*16 + ln)*40 + quad*8;
      ah[t] = *(const bf16x8*)&sAh[moA];
      al[t] = *(const bf16x8*)&sAl[moA];
      bh[t] = *(const bf16x8*)&sBh[moB];
      bl[t] = *(const bf16x8*)&sBl[moB];
    }
    #pragma unroll
    for (int mi=0;mi<4;mi++)
      #pragma unroll
      for (int ni=0;ni<4;ni++){
        acc[mi][ni] = __builtin_amdgcn_mfma_f32_16x16x32_bf16(ah[mi], bh[ni], acc[mi][ni], 0, 0, 0);
        acc[mi][ni] = __builtin_amdgcn_mfma_f32_16x16x32_bf16(ah[mi], bl[ni], acc[mi][ni], 0, 0, 0);
        acc[mi][ni] = __builtin_amdgcn_mfma_f32_16x16x32_bf16(al[mi], bh[ni], acc[mi][ni], 0, 0, 0);
      }
    __syncthreads();
  }

  const float tr = trAcc[zz];
  const float g2 = fminf(512.f/fmaxf(tr, 1e-6f), 2.7f);
  const float oz = 0.5f*sqrtf(g2);
  const float alpha = -g2*oz, beta = 3.f*oz;

  #pragma unroll
  for (int mi=0;mi<4;mi++){
    const int mbase = m0 + (wm*4+mi)*16 + quad*4;
    #pragma unroll
    for (int ni=0;ni<4;ni++){
      const int n = n0 + (wn*4+ni)*16 + ln;
      #pragma unroll
      for (int rg=0;rg<4;rg++){
        const int m = mbase + rg;
        const size_t off = (size_t)m*512 + n;
        float v = alpha*acc[mi][ni][rg] + beta*(bf16f(Dbh[off]) + bf16f(Dbl[off]));
        u16 h = bf16_rne(v);
        Cbh[off] = h;
        Cbl[off] = bf16_rne(v - bf16f(h));
      }
    }
  }
}

// tpts = T[z] @ f[img]: M=512, N=1024, K=512, fp32 out (f non-symmetric: transpose-staged)
__global__ __launch_bounds__(256) void bmmt(
    const u16* __restrict__ Th, const u16* __restrict__ Tl,
    const u16* __restrict__ fh, const u16* __restrict__ fl,
    float* __restrict__ Cf)
{
  const int z = blockIdx.z;
  const u16* Abh = Th + (size_t)z*MSZ;
  const u16* Abl = Tl + (size_t)z*MSZ;
  const u16* Bbh = fh + (size_t)(z/3)*524288;
  const u16* Bbl = fl + (size_t)(z/3)*524288;
  const int m0 = blockIdx.y*128, n0 = blockIdx.x*128;
  const int tid = threadIdx.x;

  __shared__ __align__(16) u16 sAh[128*40], sAl[128*40];
  __shared__ __align__(16) u16 sBh[128*40], sBl[128*40];

  const int ra = tid >> 2, qa = tid & 3;
  const int kb = tid >> 4, gb = tid & 15;
  const int wid = tid >> 6, lane = tid & 63;
  const int wm = wid >> 1, wn = wid & 1;
  const int quad = lane >> 4, ln = lane & 15;

  f32x4 acc[4][4];
  #pragma unroll
  for (int i=0;i<4;i++)
    #pragma unroll
    for (int j=0;j<4;j++)
      #pragma unroll
      for (int e=0;e<4;e++) acc[i][j][e] = 0.f;

  for (int k0 = 0; k0 < 512; k0 += 32){
    *(bf16x8*)&sAh[ra*40 + qa*8]      = *(const bf16x8*)&Abh[(size_t)(m0+ra)*512    + k0 + qa*8];
    *(bf16x8*)&sAl[ra*40 + qa*8]      = *(const bf16x8*)&Abl[(size_t)(m0+ra)*512    + k0 + qa*8];
    *(bf16x8*)&sAh[(ra+64)*40 + qa*8] = *(const bf16x8*)&Abh[(size_t)(m0+ra+64)*512 + k0 + qa*8];
    *(bf16x8*)&sAl[(ra+64)*40 + qa*8] = *(const bf16x8*)&Abl[(size_t)(m0+ra+64)*512 + k0 + qa*8];
    {
      bf16x8 vh = *(const bf16x8*)&Bbh[(size_t)(k0+kb)*1024 + n0 + gb*8];
      bf16x8 vl = *(const bf16x8*)&Bbl[(size_t)(k0+kb)*1024 + n0 + gb*8];
      #pragma unroll
      for (int j=0;j<8;j++){
        sBh[(gb*8+j)*40 + kb] = (u16)vh[j];
        sBl[(gb*8+j)*40 + kb] = (u16)vl[j];
      }
      vh = *(const bf16x8*)&Bbh[(size_t)(k0+kb+16)*1024 + n0 + gb*8];
      vl = *(const bf16x8*)&Bbl[(size_t)(k0+kb+16)*1024 + n0 + gb*8];
      #pragma unroll
      for (int j=0;j<8;j++){
        sBh[(gb*8+j)*40 + kb+16] = (u16)vh[j];
        sBl[(gb*8+j)*40 + kb+16] = (u16)vl[j];
      }
    }
    __syncthreads();

    bf16x8 ah[4], al[4], bh[4], bl[4];
    #pragma unroll
    for (int t=0;t<4;t++){
      const int moA = ((wm*4+t)*16 + ln)*40 + quad*8;
      const int moB = ((wn*4+t)*16 + ln)*40 + quad*8;
      ah[t] = *(const bf16x8*)&sAh[moA];
      al[t] = *(const bf16x8*)&sAl[moA];
      bh[t] = *(const bf16x8*)&sBh[moB];
      bl[t] = *(const bf16x8*)&sBl[moB];
    }
    #pragma unroll
    for (int mi=0;mi<4;mi++)
      #pragma unroll
      for (int ni=0;ni<4;ni++){
        acc[mi][ni] = __builtin_amdgcn_mfma_f32_16x16x32_bf16(ah[mi], bh[ni], acc[mi][ni], 0, 0, 0);
        acc[mi][ni] = __builtin_amdgcn_mfma_f32_16x16x32_bf16(ah[mi], bl[ni], acc[mi][ni], 0, 0, 0);
        acc[mi][ni] = __builtin_amdgcn_mfma_f32_16x16x32_bf16(al[mi], bh[ni], acc[mi][ni], 0, 0, 0);
      }
    __syncthreads();
  }
  #pragma unroll
  for (int mi=0;mi<4;mi++){
    const int mbase = m0 + (wm*4+mi)*16 + quad*4;
    #pragma unroll
    for (int ni=0;ni<4;ni++){
      const int n = n0 + (wn*4+ni)*16 + ln;
      #pragma unroll
      for (int rg=0;rg<4;rg++){
        const int m = mbase + rg;
        Cf[(size_t)z*524288 + (size_t)m*1024 + n] = acc[mi][ni][rg];
      }
    }
  }
}

// generic fp32 -> split bf16
__global__ __launch_bounds__(256) void splitk(const float* __restrict__ src,
                                              u16* __restrict__ dh, u16* __restrict__ dl, int n4){
  int i = blockIdx.x*256 + threadIdx.x;
  if (i >= n4) return;
  float4 v4 = *(const float4*)&src[(size_t)i*4];
  float vv[4] = {v4.x, v4.y, v4.z, v4.w};
  u16x4 oh, ol;
  #pragma unroll
  for (int j=0;j<4;j++){
    u16 h = bf16_rne(vv[j]);
    oh[j] = (short)h;
    ol[j] = (short)bf16_rne(vv[j] - bf16f(h));
  }
  *(u16x4*)&dh[(size_t)i*4] = oh;
  *(u16x4*)&dl[(size_t)i*4] = ol;
}

__global__ void make_scalesk(const float* __restrict__ sval, float* __restrict__ scl){
  int i = threadIdx.x;
  if (i < 12) scl[i] = sqrtf(sval[12+i] / sval[i]);
}

// tvec[b] = mu_s[b] - T[b] @ mu_c[b]   (T in split form)
__global__ __launch_bounds__(512) void tveck(const u16* __restrict__ Th, const u16* __restrict__ Tl,
                                             const float* __restrict__ mu, float* __restrict__ tvec){
  int b = blockIdx.x; int c = threadIdx.x;
  __shared__ float mc[512];
  mc[c] = mu[(size_t)b*512 + c];
  __syncthreads();
  const u16* Trh = Th + ((size_t)b*512 + c)*512;
  const u16* Trl = Tl + ((size_t)b*512 + c)*512;
  float s = 0.f;
  for (int d=0; d<512; d++) s = fmaf(bf16f(Trh[d]) + bf16f(Trl[d]), mc[d], s);
  tvec[b*512 + c] = mu[(size_t)(12+b)*512 + c] - s;
}

__global__ __launch_bounds__(256) void selectk(const float* __restrict__ tpts, const float* __restrict__ tvec,
        const int* __restrict__ a, const float* __restrict__ f4c, float* __restrict__ tf){
  size_t idx = (size_t)blockIdx.x*256 + threadIdx.x;
  if (idx >= 2097152ul) return;
  int n = (int)(idx & 1023);
  int c = (int)((idx >> 10) & 511);
  int img = (int)(idx >> 19);
  int k = a[img*1024 + n];
  int b = img*3 + k;
  float v = tpts[((size_t)b*512 + c)*1024 + n] + tvec[b*512 + c];
  tf[idx] = 0.6f*v + 0.4f*f4c[idx];
}

__global__ __launch_bounds__(256) void clossk(const float* __restrict__ x, const float* __restrict__ y,
                                              int n, float* __restrict__ acc){
  int tid = threadIdx.x;
  float s = 0.f;
  for (size_t i = (size_t)blockIdx.x*256 + tid; i < (size_t)n; i += (size_t)gridDim.x*256){
    float d = x[i] - y[i]; s = fmaf(d, d, s);
  }
  __shared__ float sh[256];
  sh[tid] = s; __syncthreads();
  for (int k=128;k>0;k>>=1){ if (tid<k) sh[tid]+=sh[tid+k]; __syncthreads(); }
  if (tid==0) atomicAdd(acc, sh[0]);
}

__global__ __launch_bounds__(256) void finalk(const float* __restrict__ sm, float* __restrict__ out){
  int tid = threadIdx.x;
  const int cnts[4] = {256,512,1024,2048};
  const int offs[4] = {0,256,768,1792};
  const float* mS = sm + SM_STATS_S;
  const float* sS = sm + SM_STATS_S + 3840;
  const float* mD = sm + SM_STATS_D;
  const float* sD = sm + SM_STATS_D + 3840;
  double sl = 0.0;
  for (int L=0; L<4; ++L){
    int cnt = cnts[L], off = offs[L];
    double inv = 1.0/cnt;
    for (int i=tid; i<cnt; i+=256){
      double dm = (double)mD[off+i] - (double)mS[off+i];
      double ds = (double)sD[off+i] - (double)sS[off+i];
      sl += (dm*dm + ds*ds)*inv;
    }
  }
  __shared__ double sh[256];
  sh[tid] = sl; __syncthreads();
  for (int k=128;k>0;k>>=1){ if (tid<k) sh[tid]+=sh[tid+k]; __syncthreads(); }
  if (tid==0){
    double closs = (double)sm[SM_CLOSS] / 2097152.0;
    out[0] = (float)(closs + 0.01*sh[0]);
  }
}

// ---------------- host ----------------

extern "C" void kernel_launch(void* const* d_in, const int* in_sizes, int n_in,
                              void* d_out, int out_size, void* d_ws, size_t ws_size,
                              hipStream_t stream)
{
  const float* content = (const float*)d_in[0];
  const float* style   = (const float*)d_in[1];
  const float* Wm[8]; const float* Bm[8];
  for (int i=0;i<8;i++){ Wm[i] = (const float*)d_in[2+2*i]; Bm[i] = (const float*)d_in[3+2*i]; }
  float* out = (float*)d_out;
  float* ws = (float*)d_ws;

  float* f4c  = ws + OFF_F4C;
  float* f4s  = ws + OFF_F4S;
  float* tf   = ws + OFF_TF;
  float* dec  = ws + OFF_DEC;
  float* sm   = ws + OFF_SMALL;
  float* AR   = ws + OFF_ARENA;
  int*   aPtr = (int*)(sm + SM_ASSIGN);
  float* mu   = sm + SM_MU;
  float* counts = sm + SM_COUNTS;
  float* sval = sm + SM_SVAL;
  float* scl  = sm + SM_SCALE;
  float* tvec = sm + SM_TVEC;
  float* trbuf = sm + SM_TR;

  // pre-split weights region
  u16* WB = (u16*)(ws + OFF_WSPL);
  u16 *w2h=WB+0,       *w2l=WB+73728;    // e2: 9*128*64
  u16 *w3h=WB+147456,  *w3l=WB+442368;   // e3: 9*256*128
  u16 *w4h=WB+737280,  *w4l=WB+1916928;  // e4: 9*512*256
  u16 *v1h=WB+3096576, *v1l=WB+4276224;  // d1: 9*256*512
  u16 *v2h=WB+5455872, *v2l=WB+5750784;  // d2: 9*128*256
  u16 *v3h=WB+6045696, *v3l=WB+6119424;  // d3: 9*64*128

  float* Ycov = AR;
  u16* Mh  = (u16*)(AR);
  u16* Ml  = (u16*)(AR + 3145728ul);
  u16* Yh  = (u16*)(AR + 6291456ul);
  u16* Yl  = (u16*)(AR + 9437184ul);
  u16* Zh  = (u16*)(AR + 12582912ul);
  u16* Zl  = (u16*)(AR + 15728640ul);
  u16* Y2h = (u16*)(AR + 18874368ul);
  u16* Y2l = (u16*)(AR + 22020096ul);
  u16* Z2h = (u16*)(AR + 25165824ul);
  u16* Z2l = (u16*)(AR + 28311552ul);
  u16* Ph  = (u16*)(AR + 18874368ul);   // aliases Y2 (dead before NS)
  u16* Pl  = (u16*)(AR + 25165824ul);   // aliases Z2
  float* ptsT = AR + 25165824ul;        // dead before maskcenterk writes Pl
  u16* Th  = (u16*)(AR + 18874368ul);   // post-NS (Y2/Z2 free)
  u16* Tl  = (u16*)(AR + 20971520ul);
  u16* fsh = (u16*)(AR + 23068672ul);
  u16* fsl = (u16*)(AR + 24117248ul);
  float* KACC = AR + 0;                 // 12 slots * KSLOT floats, free after encode, dead before covgemm

  zerok<<<512,256,0,stream>>>(sm, 131072);

  // pre-split mid-layer weights
  {
    auto wsp = [&](int li, u16* wh, u16* wl, int Co, int Ci){
      int n = 9*Co*Ci;
      wsplitk<<<(n+255)/256,256,0,stream>>>(Wm[li], wh, wl, Co, Ci);
    };
    wsp(1,w2h,w2l,128,64);
    wsp(2,w3h,w3l,256,128);
    wsp(3,w4h,w4l,512,256);
    wsp(4,v1h,v1l,256,512);
    wsp(5,v2h,v2l,128,256);
    wsp(6,v3h,v3l,64,128);
  }

  auto conv = [&](const float* inp, int li, float* outp, int B,int Ci,int Co,int H,int Wd,int relu,int cot){
    dim3 g((H>>5)*(Wd>>5), (Co + cot - 1)/cot, B);
    if (cot==8)      conv3x3<8><<<g,256,0,stream>>>(inp,Wm[li],Bm[li],outp,B,Ci,Co,H,Wd,relu);
    else if (cot==4) conv3x3<4><<<g,256,0,stream>>>(inp,Wm[li],Bm[li],outp,B,Ci,Co,H,Wd,relu);
    else             conv3x3<1><<<g,256,0,stream>>>(inp,Wm[li],Bm[li],outp,B,Ci,Co,H,Wd,relu);
  };
  auto convM = [&](const float* inp, int li, float* outp, int B,int Ci,int Co,int H,int Wd,int relu,int KS,float* part){
    const u16 *wh=nullptr,*wl=nullptr;
    switch(li){
      case 1: wh=w2h; wl=w2l; break;
      case 2: wh=w3h; wl=w3l; break;
      case 3: wh=w4h; wl=w4l; break;
      case 4: wh=v1h; wl=v1l; break;
      case 5: wh=v2h; wl=v2l; break;
      case 6: wh=v3h; wl=v3l; break;
    }
    int tiles = (H>>3)*(Wd>>3);
    if (KS==1){
      convm<1><<<dim3(tiles,Co>>6,B),256,0,stream>>>(inp,wh,wl,Bm[li],outp,Ci,Co,H,Wd,relu);
    } else {
      int n = B*Co*H*Wd;
      if (KS==2) convm<2><<<dim3(tiles,Co>>6,B*2),256,0,stream>>>(inp,wh,wl,nullptr,part,Ci,Co,H,Wd,relu);
      else       convm<4><<<dim3(tiles,Co>>6,B*4),256,0,stream>>>(inp,wh,wl,nullptr,part,Ci,Co,H,Wd,relu);
      sumk<<<(n+255)/256,256,0,stream>>>(part,Bm[li],outp,Co,H*Wd,KS,relu,n);
    }
  };
  auto pool = [&](const float* inp, float* outp, int B,int C,int Ho,int Wo){
    int n = B*C*Ho*Wo;
    pool2k<<<(n+255)/256,256,0,stream>>>(inp,outp,n,Ho,Wo);
  };
  auto up = [&](const float* inp, float* outp, int B,int C,int Ho,int Wo){
    int n = B*C*Ho*Wo;
    up2k<<<(n+255)/256,256,0,stream>>>(inp,outp,n,Ho,Wo);
  };

  float* mS = sm + SM_STATS_S;
  float* sS = sm + SM_STATS_S + 3840;

  // ---- batched content+style encode (B=8 from e2 down) ----
  float* F1   = AR + 0;
  float* P1_8 = AR + 16777216ul;
  float* F2_8 = AR + 0;
  float* P2_8 = AR + 25165824ul;
  float* F3_8 = AR + 0;
  float* P3_8 = AR + 8388608ul;
  float* PART8 = AR + 10485760ul;

  conv(content, 0, F1, 4, 3,64,256,256,1,8);
  pool(F1, P1_8, 4, 64,128,128);
  conv(style, 0, F1, 4, 3,64,256,256,1,8);
  statsk<<<256,256,0,stream>>>(F1,65536, mS+0, sS+0);
  pool(F1, P1_8 + 4194304ul, 4, 64,128,128);

  convM(P1_8, 1, F2_8, 8, 64,128,128,128,1,1,nullptr);
  statsk<<<512,256,0,stream>>>(F2_8 + 8388608ul, 16384, mS+256, sS+256);
  pool(F2_8, P2_8, 8, 128,64,64);
  convM(P2_8, 2, F3_8, 8, 128,256,64,64,1,1,nullptr);
  statsk<<<1024,256,0,stream>>>(F3_8 + 4194304ul, 4096, mS+768, sS+768);
  pool(F3_8, P3_8, 8, 256,32,32);
  convM(P3_8, 3, f4c /* [f4c|f4s] contiguous */, 8, 256,512,32,32,1,2,PART8);
  statsk<<<2048,256,0,stream>>>(f4s,1024, mS+1792, sS+1792);

  // ---- fused k-means (content r=0..3, style r=4..7) ----
  transposek<<<dim3(32,16,8),256,0,stream>>>(f4c,f4s,ptsT);
  zerok<<<(12*KSLOT+255)/256,256,0,stream>>>(KACC, 12*KSLOT);
  initcent2k<<<48,256,0,stream>>>(ptsT,KACC);
  for (int it=0; it<=10; ++it){
    kstepk<<<dim3(8,32),256,0,stream>>>(ptsT, KACC + (size_t)it*KSLOT, KACC + (size_t)(it+1)*KSLOT, aPtr, it==0 ? 1 : 0);
  }
  mufink<<<48,256,0,stream>>>(KACC + 11ul*KSLOT, mu, counts);

  // ---- covariances via MFMA (trace accumulated into sval) ----
  maskcenterk<<<12288,256,0,stream>>>(f4c,f4s,aPtr,mu,Ph,Pl);
  covgemm<<<dim3(4,4,24),256,0,stream>>>(Ph,Pl,counts,Ycov,sval);
  nsinitk<<<24576,256,0,stream>>>(Ycov,sval,Yh,Yl,Zh,Zl);

  // ---- split-bf16 MFMA Newton-Schulz (trace-adaptive gamma, fused) ----
  u16 *Ych=Yh,*Ycl=Yl,*Zch=Zh,*Zcl=Zl,*Yah=Y2h,*Yal=Y2l,*Zah=Z2h,*Zal=Z2l;
  for (int it=0; it<NS_ITERS; ++it){
    bmms<0,1><<<dim3(4,4,24),256,0,stream>>>(Zch,Zcl,Ych,Ycl,Mh,Ml,nullptr,0,trbuf+it*24);
    bmmpair<<<dim3(4,4,48),256,0,stream>>>(Ych,Ycl,Mh,Ml,Zch,Zcl,Yah,Yal,Zah,Zal,trbuf+it*24);
    u16* t;
    t=Ych;Ych=Yah;Yah=t; t=Ycl;Ycl=Yal;Yal=t;
    t=Zch;Zch=Zah;Zah=t; t=Zcl;Zcl=Zal;Zal=t;
  }
  // T[b] = sqrt(t_s/t_c) * Y_style[b] @ Z_content[b]  (split out; NS_ITERS even -> Ych=Yh, Zch=Zh)
  make_scalesk<<<1,64,0,stream>>>(sval,scl);
  bmms<2,1><<<dim3(4,4,12),256,0,stream>>>(Ych,Ycl,Zch,Zcl,Th,Tl,scl,12,nullptr);
  tveck<<<12,512,0,stream>>>(Th,Tl,mu,tvec);
  // tpts[b] = T[b] @ f[img]
  splitk<<<2048,256,0,stream>>>(f4c,fsh,fsl,524288);
  float* Mb = AR + 0;
  bmmt<<<dim3(8,4,12),256,0,stream>>>(Th,Tl,fsh,fsl,Mb);
  selectk<<<8192,256,0,stream>>>(Mb,tvec,aPtr,f4c,tf);

  // ---- decode (B=4) ----
  float* X1 = AR + 0;
  float* U1 = AR + 1048576ul;
  float* X2 = AR + 5242880ul;
  float* U2 = AR + 7340032ul;
  float* X3 = AR + 0;
  float* U3 = AR + 4194304ul;
  float* PARTA = AR + 2097152ul;
  float* PARTB = AR + 7340032ul;
  convM(tf, 4, X1, 4, 512,256,32,32,1,4,PARTA);
  up(X1,U1, 4, 256,64,64);
  convM(U1,5,X2, 4, 256,128,64,64,1,2,PARTB);
  up(X2,U2, 4, 128,128,128);
  convM(U2,6,X3, 4, 128,64,128,128,1,1,nullptr);
  up(X3,U3, 4, 64,256,256);
  conv(U3,7,dec, 4, 64,3,256,256,0,1);

  // ---- decoded encode + stats + content loss (B=4) ----
  float* mD = sm + SM_STATS_D;
  float* sD = sm + SM_STATS_D + 3840;
  float* F1d = AR + 0;
  float* P1d = AR + 16777216ul;
  float* F2d = AR + 0;
  float* P2d = AR + 8388608ul;
  float* F3d = AR + 10485760ul;
  float* P3d = AR + 0;
  conv(dec, 0, F1d, 4, 3,64,256,256,1,8);
  statsk<<<256,256,0,stream>>>(F1d,65536, mD+0, sD+0);
  pool(F1d,P1d, 4, 64,128,128);
  convM(P1d,1,F2d, 4, 64,128,128,128,1,1,nullptr);
  statsk<<<512,256,0,stream>>>(F2d,16384, mD+256, sD+256);
  pool(F2d,P2d, 4, 128,64,64);
  convM(P2d,2,F3d, 4, 128,256,64,64,1,1,nullptr);
  statsk<<<1024,256,0,stream>>>(F3d,4096, mD+768, sD+768);
  pool(F3d,P3d, 4, 256,32,32);
  convM(P3d,3,tf, 4, 256,512,32,32,1,2,PARTA);   // f4(dec) reuses tf buffer
  statsk<<<2048,256,0,stream>>>(tf,1024, mD+1792, sD+1792);
  clossk<<<2048,256,0,stream>>>(tf,f4c,2097152, sm+SM_CLOSS);
  finalk<<<1,256,0,stream>>>(sm,out);
}

// Round 11
// 2874.792 us; speedup vs baseline: 2.4187x; 1.0181x over previous
//
#include <hip/hip_runtime.h>
#include <cstddef>

#define NS_ITERS 8
#define MSZ 262144  // 512*512
#define PL  6291456 // 24*MSZ
#define KSLOT 12312 // k-means accumulator slot stride (floats)

typedef unsigned short u16;
typedef __attribute__((ext_vector_type(8))) short bf16x8;
typedef __attribute__((ext_vector_type(4))) float f32x4;
typedef __attribute__((ext_vector_type(4))) short u16x4;

__device__ inline u16 bf16_rne(float x){
  unsigned u = __float_as_uint(x);
  unsigned r = u + 0x7fffu + ((u>>16)&1u);
  return (u16)(r>>16);
}
__device__ inline float bf16f(u16 h){
  return __uint_as_float(((unsigned)h)<<16);
}

// ---------------- workspace offsets (in floats) ----------------
#define OFF_F4C   0ul
#define OFF_F4S   2097152ul
#define OFF_TF    4194304ul
#define OFF_DEC   6291456ul
#define OFF_WSPL  7077888ul
#define OFF_SMALL 10223616ul
#define OFF_ARENA 10354688ul

// SMALL sub-offsets (floats)
#define SM_ASSIGN  12288
#define SM_MU      20480
#define SM_COUNTS  32768
#define SM_SVAL    32800
#define SM_SCALE   32832
#define SM_TVEC    32864
#define SM_STATS_S 39008
#define SM_STATS_D 46688
#define SM_CLOSS   54368
#define SM_TR      54464

// ---------------- kernels ----------------

__global__ __launch_bounds__(256) void zerok(float* p, int n){
  int i = blockIdx.x*256 + threadIdx.x;
  if (i < n) p[i] = 0.f;
}

// direct 3x3 SAME conv (for e1: Cin=3, and d4: Cout=3)
template<int COT>
__global__ __launch_bounds__(256) void conv3x3(
    const float* __restrict__ in, const float* __restrict__ wgt,
    const float* __restrict__ bias, float* __restrict__ out,
    int B, int Cin, int Cout, int H, int W, int relu)
{
  __shared__ float s_in[8][34][34];
  __shared__ float s_w[COT][8][9];
  const int tid = threadIdx.x;
  const int tx = tid & 15, ty = tid >> 4;
  const int tilesW = W >> 5;
  const int h0 = (blockIdx.x / tilesW) << 5;
  const int w0 = (blockIdx.x % tilesW) << 5;
  const int co0 = blockIdx.y * COT;
  const int b = blockIdx.z;
  float acc[COT][2][2];
  #pragma unroll
  for (int o=0;o<COT;o++){acc[o][0][0]=0.f;acc[o][0][1]=0.f;acc[o][1][0]=0.f;acc[o][1][1]=0.f;}
  const int y0 = ty*2, x0 = tx*2;
  for (int ci0 = 0; ci0 < Cin; ci0 += 8){
    const int cic = (Cin - ci0 < 8) ? (Cin - ci0) : 8;
    const int tot = cic*1156;
    for (int e = tid; e < tot; e += 256){
      int c = e / 1156; int r = e - c*1156;
      int lh = r / 34, lw = r - lh*34;
      int ih = h0 + lh - 1, iw = w0 + lw - 1;
      float v = 0.f;
      if ((unsigned)ih < (unsigned)H && (unsigned)iw < (unsigned)W)
        v = in[((size_t)(b*Cin + ci0 + c)*H + ih)*W + iw];
      s_in[c][lh][lw] = v;
    }
    const int wtot = COT*cic*9;
    for (int e = tid; e < wtot; e += 256){
      int o = e / (cic*9); int r = e - o*(cic*9);
      int c = r / 9, t = r - c*9;
      int co = co0 + o;
      float v = 0.f;
      if (co < Cout) v = wgt[(size_t)(co*Cin + ci0 + c)*9 + t];
      s_w[o][c][t] = v;
    }
    __syncthreads();
    for (int c = 0; c < cic; ++c){
      float p[4][4];
      #pragma unroll
      for (int r=0;r<4;r++)
        #pragma unroll
        for (int s=0;s<4;s++)
          p[r][s] = s_in[c][y0+r][x0+s];
      #pragma unroll
      for (int dh=0; dh<3; dh++)
        #pragma unroll
        for (int dw=0; dw<3; dw++){
          #pragma unroll
          for (int o=0;o<COT;o++){
            float wv = s_w[o][c][dh*3+dw];
            acc[o][0][0] = fmaf(p[dh  ][dw  ], wv, acc[o][0][0]);
            acc[o][0][1] = fmaf(p[dh  ][dw+1], wv, acc[o][0][1]);
            acc[o][1][0] = fmaf(p[dh+1][dw  ], wv, acc[o][1][0]);
            acc[o][1][1] = fmaf(p[dh+1][dw+1], wv, acc[o][1][1]);
          }
        }
    }
    __syncthreads();
  }
  #pragma unroll
  for (int o=0;o<COT;o++){
    int co = co0 + o;
    if (co >= Cout) continue;
    float bv = bias[co];
    #pragma unroll
    for (int r=0;r<2;r++)
      #pragma unroll
      for (int s=0;s<2;s++){
        float v = acc[o][r][s] + bv;
        if (relu) v = fmaxf(v, 0.f);
        out[((size_t)(b*Cout + co)*H + h0+y0+r)*W + w0+x0+s] = v;
      }
  }
}

// pre-split conv weights: dst[(dhw*Cout + co)*Cin + ci]
__global__ __launch_bounds__(256) void wsplitk(const float* __restrict__ wgt,
                                               u16* __restrict__ dh_, u16* __restrict__ dl_,
                                               int Cout, int Cin){
  int idx = blockIdx.x*256 + threadIdx.x;
  int n = 9*Cout*Cin;
  if (idx >= n) return;
  int cc = Cout*Cin;
  int dhw = idx / cc;
  int r = idx - dhw*cc;
  int co = r / Cin, ci = r - co*Cin;
  float v = wgt[((size_t)co*Cin + ci)*9 + dhw];
  u16 h = bf16_rne(v);
  dh_[idx] = h;
  dl_[idx] = bf16_rne(v - bf16f(h));
}

// ---- split-bf16 MFMA direct conv 3x3 SAME; Cin%(32*KS)==0, Cout%64==0 ----
// RESIZE: 0 none; 1 avg-pool2 input (input dims 2H x 2W); 2 nearest-up2 input (H/2 x W/2)
// KS>1: blockIdx.z = b*KS + ks; writes fp32 partial [ks][b][Cout][H][W]; sumk reduces.
template<int KS, int RESIZE>
__global__ __launch_bounds__(256) void convm(
    const float* __restrict__ in, const u16* __restrict__ wsh, const u16* __restrict__ wsl,
    const float* __restrict__ bias, float* __restrict__ out,
    int Cin, int Cout, int H, int W, int relu)
{
  const int tilesW = W >> 3;
  const int h0 = (blockIdx.x / tilesW) << 3;
  const int w0 = (blockIdx.x % tilesW) << 3;
  const int co0 = blockIdx.y << 6;
  const int b  = blockIdx.z / KS;
  const int ks = blockIdx.z % KS;
  const int NB = gridDim.z / KS;
  const int tid = threadIdx.x;
  const int wid = tid >> 6, lane = tid & 63;
  const int wm = wid >> 1, wn = wid & 1;
  const int quad = lane >> 4, ln = lane & 15;

  __shared__ __align__(16) u16 sXh[100*40], sXl[100*40];
  __shared__ __align__(16) u16 sWh[3*64*40], sWl[3*64*40];

  f32x4 acc[2][2];
  #pragma unroll
  for (int i=0;i<2;i++)
    #pragma unroll
    for (int j=0;j<2;j++)
      #pragma unroll
      for (int e=0;e<4;e++) acc[i][j][e] = 0.f;

  const int ciA = ks*(Cin/KS), ciB = ciA + Cin/KS;
  for (int ci0 = ciA; ci0 < ciB; ci0 += 32){
    __syncthreads();
    for (int e = tid; e < 3200; e += 256){
      int ci = e / 100, px = e - ci*100;
      int pr = px / 10, pc = px - pr*10;
      int ih = h0 + pr - 1, iw = w0 + pc - 1;
      float v = 0.f;
      if ((unsigned)ih < (unsigned)H && (unsigned)iw < (unsigned)W){
        if constexpr (RESIZE==0){
          v = in[((size_t)(b*Cin + ci0+ci)*H + ih)*W + iw];
        } else if constexpr (RESIZE==1){
          const float* p = in + ((size_t)(b*Cin + ci0+ci)*(H*2) + ih*2)*(size_t)(W*2) + (size_t)iw*2;
          v = 0.25f*(p[0] + p[1] + p[2*W] + p[2*W+1]);
        } else {
          v = in[((size_t)(b*Cin + ci0+ci)*(H>>1) + (ih>>1))*(W>>1) + (iw>>1)];
        }
      }
      u16 h = bf16_rne(v);
      sXh[px*40 + ci] = h;
      sXl[px*40 + ci] = bf16_rne(v - bf16f(h));
    }
    for (int dh = 0; dh < 3; ++dh){
      if (dh) __syncthreads();
      for (int e2 = tid; e2 < 768; e2 += 256){
        int dw = e2 >> 8, r = e2 & 255;
        int co = r >> 2, cg = (r & 3) << 3;
        size_t so = ((size_t)((dh*3+dw)*Cout + co0+co))*Cin + ci0 + cg;
        int dsto = (dw*64+co)*40 + cg;
        *(bf16x8*)&sWh[dsto] = *(const bf16x8*)&wsh[so];
        *(bf16x8*)&sWl[dsto] = *(const bf16x8*)&wsl[so];
      }
      __syncthreads();
      #pragma unroll
      for (int dw = 0; dw < 3; ++dw){
        bf16x8 ah[2], al[2], bh[2], bl[2];
        #pragma unroll
        for (int t=0;t<2;t++){
          const int co_l = (wm*2+t)*16 + ln;
          const int wo = (dw*64 + co_l)*40 + quad*8;
          ah[t] = *(const bf16x8*)&sWh[wo];
          al[t] = *(const bf16x8*)&sWl[wo];
          const int p = (wn*2+t)*16 + ln;
          const int px = ((p>>3) + dh)*10 + (p&7) + dw;
          const int xo = px*40 + quad*8;
          bh[t] = *(const bf16x8*)&sXh[xo];
          bl[t] = *(const bf16x8*)&sXl[xo];
        }
        #pragma unroll
        for (int mi=0;mi<2;mi++)
          #pragma unroll
          for (int ni=0;ni<2;ni++){
            acc[mi][ni] = __builtin_amdgcn_mfma_f32_16x16x32_bf16(ah[mi], bh[ni], acc[mi][ni], 0, 0, 0);
            acc[mi][ni] = __builtin_amdgcn_mfma_f32_16x16x32_bf16(ah[mi], bl[ni], acc[mi][ni], 0, 0, 0);
            acc[mi][ni] = __builtin_amdgcn_mfma_f32_16x16x32_bf16(al[mi], bh[ni], acc[mi][ni], 0, 0, 0);
          }
      }
    }
  }
  #pragma unroll
  for (int mi=0;mi<2;mi++){
    const int co = co0 + (wm*2+mi)*16 + quad*4;
    #pragma unroll
    for (int ni=0;ni<2;ni++){
      const int p = (wn*2+ni)*16 + ln;
      const int oh = h0 + (p>>3), ow = w0 + (p&7);
      #pragma unroll
      for (int rg=0; rg<4; rg++){
        const int cog = co + rg;
        if constexpr (KS==1){
          float v = acc[mi][ni][rg] + bias[cog];
          if (relu) v = fmaxf(v, 0.f);
          out[((size_t)(b*Cout + cog)*H + oh)*W + ow] = v;
        } else {
          out[((size_t)((ks*NB + b)*Cout + cog)*H + oh)*W + ow] = acc[mi][ni][rg];
        }
      }
    }
  }
}

// reduce split-K partials + bias + relu
__global__ __launch_bounds__(256) void sumk(const float* __restrict__ part, const float* __restrict__ bias,
                                            float* __restrict__ out, int Cout, int HW, int KS, int relu, int n){
  int idx = blockIdx.x*256 + threadIdx.x;
  if (idx >= n) return;
  int co = (idx / HW) % Cout;
  float v = bias[co];
  for (int k=0;k<KS;k++) v += part[(size_t)k*n + idx];
  if (relu) v = fmaxf(v, 0.f);
  out[idx] = v;
}

__global__ __launch_bounds__(256) void pool2k(const float* __restrict__ in, float* __restrict__ out,
                                              int n, int Ho, int Wo){
  int idx = blockIdx.x*256 + threadIdx.x;
  if (idx >= n) return;
  int wo = idx % Wo; int t = idx / Wo; int ho = t % Ho; int bc = t / Ho;
  const float* p = in + ((size_t)bc*(Ho*2) + ho*2)*(size_t)(Wo*2) + (size_t)wo*2;
  out[idx] = 0.25f*(p[0] + p[1] + p[2*Wo] + p[2*Wo+1]);
}

__global__ __launch_bounds__(256) void up2k(const float* __restrict__ in, float* __restrict__ out,
                                            int n, int Ho, int Wo){
  int idx = blockIdx.x*256 + threadIdx.x;
  if (idx >= n) return;
  int wo = idx % Wo; int t = idx / Wo; int ho = t % Ho; int bc = t / Ho;
  int Hi = Ho >> 1, Wi = Wo >> 1;
  out[idx] = in[((size_t)bc*Hi + (ho>>1))*Wi + (wo>>1)];
}

// per-(b,c) spatial mean & std (ddof=0)
__global__ __launch_bounds__(256) void statsk(const float* __restrict__ x, int HW,
                                              float* __restrict__ mo, float* __restrict__ so){
  int bc = blockIdx.x, tid = threadIdx.x;
  const float* p = x + (size_t)bc*HW;
  double s = 0.0, s2 = 0.0;
  for (int i = tid; i < HW; i += 256){ double v = p[i]; s += v; s2 += v*v; }
  __shared__ double sh[256], sh2[256];
  sh[tid] = s; sh2[tid] = s2; __syncthreads();
  for (int k=128;k>0;k>>=1){ if (tid<k){ sh[tid]+=sh[tid+k]; sh2[tid]+=sh2[tid+k]; } __syncthreads(); }
  if (tid == 0){
    double m = sh[0]/HW;
    double var = sh2[0]/HW - m*m;
    if (var < 0.0) var = 0.0;
    mo[bc] = (float)m;
    so[bc] = (float)sqrt(var);
  }
}

// f4 (C-major, per image 512x1024) -> ptsT [8][1024][512]
__global__ __launch_bounds__(256) void transposek(const float* __restrict__ f4c,
                                                  const float* __restrict__ f4s,
                                                  float* __restrict__ ptsT){
  __shared__ float t[32][33];
  int r = blockIdx.z;
  const float* src = (r < 4) ? (f4c + (size_t)r*524288) : (f4s + (size_t)(r-4)*524288);
  int n0 = blockIdx.x*32, c0 = blockIdx.y*32;
  int lx = threadIdx.x & 31, ly = threadIdx.x >> 5;
  for (int j=0;j<32;j+=8)
    t[ly+j][lx] = src[(size_t)(c0+ly+j)*1024 + n0+lx];
  __syncthreads();
  for (int j=0;j<32;j+=8)
    ptsT[((size_t)r*1024 + n0+ly+j)*512 + c0+lx] = t[lx][ly+j];
}

// slot0 init: sums = first 3 points (centroids), counts = 1
__global__ __launch_bounds__(256) void initcent2k(const float* __restrict__ ptsT, float* __restrict__ KACC){
  int i = blockIdx.x*256 + threadIdx.x;
  if (i < 12288){
    int c = i & 511; int k = (i >> 9) % 3; int r = i / 1536;
    KACC[r*1536 + k*512 + c] = ptsT[((size_t)r*1024 + k)*512 + c];
  }
  if (i < 24) KACC[12288 + i] = 1.f;
}

// fused k-means step
__global__ __launch_bounds__(256) void kstepk(const float* __restrict__ ptsT,
    const float* __restrict__ prev, float* __restrict__ next,
    int* __restrict__ a, int nodiv)
{
  const int r = blockIdx.x, sl = blockIdx.y;
  const int tid = threadIdx.x;
  __shared__ float sc[1536];
  __shared__ int sa[32];
  __shared__ float red[3][8][32];
  __shared__ int scnt[3];
  if (tid < 3) scnt[tid] = 0;
  for (int i = tid; i < 1536; i += 256){
    float s = prev[r*1536 + i];
    float cnt = nodiv ? 1.f : (prev[12288 + r*3 + (i>>9)] + 1e-6f);
    sc[i] = s / cnt;
  }
  __syncthreads();
  const float* base = ptsT + (size_t)r*524288;
  const int wid = tid >> 6, lane = tid & 63;
  for (int rep = 0; rep < 8; ++rep){
    int p = wid*8 + rep;
    int n = sl*32 + p;
    const float* pp = base + (size_t)n*512;
    float d0=0.f,d1=0.f,d2=0.f;
    #pragma unroll
    for (int i=0;i<8;i++){
      int c = lane + i*64;
      float v = pp[c];
      float e0 = v - sc[c], e1 = v - sc[512+c], e2 = v - sc[1024+c];
      d0 = fmaf(e0,e0,d0); d1 = fmaf(e1,e1,d1); d2 = fmaf(e2,e2,d2);
    }
    #pragma unroll
    for (int off=32; off>0; off>>=1){
      d0 += __shfl_down(d0, off, 64);
      d1 += __shfl_down(d1, off, 64);
      d2 += __shfl_down(d2, off, 64);
    }
    if (lane == 0){
      int bi = 0; float bd = d0;
      if (d1 < bd){ bd = d1; bi = 1; }
      if (d2 < bd){ bd = d2; bi = 2; }
      sa[p] = bi;
      a[r*1024 + n] = bi;
    }
  }
  __syncthreads();
  if (tid < 32) atomicAdd(&scnt[sa[tid]], 1);
  __syncthreads();
  if (tid < 3) atomicAdd(&next[12288 + r*3 + tid], (float)scnt[tid]);
  const int g = tid >> 5, lc = tid & 31;
  for (int cj = 0; cj < 16; ++cj){
    int c = cj*32 + lc;
    float s0=0.f,s1=0.f,s2=0.f;
    #pragma unroll
    for (int q=0;q<4;q++){
      int nl = g*4 + q;
      float v = base[(size_t)(sl*32+nl)*512 + c];
      int an = sa[nl];
      s0 += (an==0)?v:0.f;
      s1 += (an==1)?v:0.f;
      s2 += (an==2)?v:0.f;
    }
    red[0][g][lc]=s0; red[1][g][lc]=s1; red[2][g][lc]=s2;
    __syncthreads();
    if (g == 0){
      float t0=0.f,t1=0.f,t2=0.f;
      #pragma unroll
      for (int q2=0;q2<8;q2++){ t0+=red[0][q2][lc]; t1+=red[1][q2][lc]; t2+=red[2][q2][lc]; }
      atomicAdd(&next[r*1536 +          c], t0);
      atomicAdd(&next[r*1536 +  512 +   c], t1);
      atomicAdd(&next[r*1536 + 1024 +   c], t2);
    }
    __syncthreads();
  }
}

// final mu/counts from slot 11
__global__ __launch_bounds__(256) void mufink(const float* __restrict__ slot,
                                              float* __restrict__ mu, float* __restrict__ counts){
  int i = blockIdx.x*256 + threadIdx.x;
  if (i >= 12288) return;
  int c = i & 511; int k = (i >> 9) % 3; int r = i / 1536;
  int cs = r >> 2, img = r & 3;
  int i0 = cs*12 + img*3;
  float cnt = slot[12288 + r*3 + k];
  mu[(size_t)(i0+k)*512 + c] = slot[r*1536 + k*512 + c] / (cnt + 1e-6f);
  if (c == 0) counts[i0+k] = cnt;
}

// masked centered split planes
__global__ __launch_bounds__(256) void maskcenterk(const float* __restrict__ f4c, const float* __restrict__ f4s,
        const int* __restrict__ a, const float* __restrict__ mu,
        u16* __restrict__ Ph, u16* __restrict__ Pl){
  size_t i4 = ((size_t)blockIdx.x*256 + threadIdx.x)*4;
  if (i4 >= (size_t)PL*2) return;
  int z = (int)(i4 >> 19);
  int rc = (int)(i4 & 524287);
  int c = rc >> 10, n = rc & 1023;
  int cs = z / 12; int rem = z - cs*12; int img = rem / 3; int k = rem - img*3;
  const float* pts = (cs ? f4s : f4c) + (size_t)img*524288;
  float m = mu[(size_t)z*512 + c];
  const int* an = a + (cs*4 + img)*1024 + n;
  float4 v4 = *(const float4*)&pts[(size_t)c*1024 + n];
  float vv[4] = {v4.x, v4.y, v4.z, v4.w};
  u16x4 oh, ol;
  #pragma unroll
  for (int j=0;j<4;j++){
    float v = (an[j] == k) ? (vv[j] - m) : 0.f;
    u16 h = bf16_rne(v);
    oh[j] = (short)h;
    ol[j] = (short)bf16_rne(v - bf16f(h));
  }
  *(u16x4*)&Ph[i4] = oh;
  *(u16x4*)&Pl[i4] = ol;
}

// covariance via MFMA, trace accumulated
__global__ __launch_bounds__(256) void covgemm(const u16* __restrict__ Ph, const u16* __restrict__ Pl,
        const float* __restrict__ counts, float* __restrict__ Ycov, float* __restrict__ trsum){
  const int z = blockIdx.z;
  const u16* Pbh = Ph + (size_t)z*524288;
  const u16* Pbl = Pl + (size_t)z*524288;
  const int m0 = blockIdx.y*128, n0 = blockIdx.x*128;
  const int tid = threadIdx.x;

  __shared__ __align__(16) u16 sAh[128*40], sAl[128*40];
  __shared__ __align__(16) u16 sBh[128*40], sBl[128*40];

  const int ra = tid >> 2, qa = tid & 3;
  const int wid = tid >> 6, lane = tid & 63;
  const int wm = wid >> 1, wn = wid & 1;
  const int quad = lane >> 4, ln = lane & 15;

  f32x4 acc[4][4];
  #pragma unroll
  for (int i=0;i<4;i++)
    #pragma unroll
    for (int j=0;j<4;j++)
      #pragma unroll
      for (int e=0;e<4;e++) acc[i][j][e] = 0.f;

  for (int k0 = 0; k0 < 1024; k0 += 32){
    *(bf16x8*)&sAh[ra*40 + qa*8]      = *(const bf16x8*)&Pbh[(size_t)(m0+ra)*1024    + k0 + qa*8];
    *(bf16x8*)&sAl[ra*40 + qa*8]      = *(const bf16x8*)&Pbl[(size_t)(m0+ra)*1024    + k0 + qa*8];
    *(bf16x8*)&sAh[(ra+64)*40 + qa*8] = *(const bf16x8*)&Pbh[(size_t)(m0+ra+64)*1024 + k0 + qa*8];
    *(bf16x8*)&sAl[(ra+64)*40 + qa*8] = *(const bf16x8*)&Pbl[(size_t)(m0+ra+64)*1024 + k0 + qa*8];
    *(bf16x8*)&sBh[ra*40 + qa*8]      = *(const bf16x8*)&Pbh[(size_t)(n0+ra)*1024    + k0 + qa*8];
    *(bf16x8*)&sBl[ra*40 + qa*8]      = *(const bf16x8*)&Pbl[(size_t)(n0+ra)*1024    + k0 + qa*8];
    *(bf16x8*)&sBh[(ra+64)*40 + qa*8] = *(const bf16x8*)&Pbh[(size_t)(n0+ra+64)*1024 + k0 + qa*8];
    *(bf16x8*)&sBl[(ra+64)*40 + qa*8] = *(const bf16x8*)&Pbl[(size_t)(n0+ra+64)*1024 + k0 + qa*8];
    __syncthreads();

    bf16x8 ah[4], al[4], bh[4], bl[4];
    #pragma unroll
    for (int t=0;t<4;t++){
      const int moA = ((wm*4+t)*16 + ln)*40 + quad*8;
      const int moB = ((wn*4+t)*16 + ln)*40 + quad*8;
      ah[t] = *(const bf16x8*)&sAh[moA];
      al[t] = *(const bf16x8*)&sAl[moA];
      bh[t] = *(const bf16x8*)&sBh[moB];
      bl[t] = *(const bf16x8*)&sBl[moB];
    }
    #pragma unroll
    for (int mi=0;mi<4;mi++)
      #pragma unroll
      for (int ni=0;ni<4;ni++){
        acc[mi][ni] = __builtin_amdgcn_mfma_f32_16x16x32_bf16(ah[mi], bh[ni], acc[mi][ni], 0, 0, 0);
        acc[mi][ni] = __builtin_amdgcn_mfma_f32_16x16x32_bf16(ah[mi], bl[ni], acc[mi][ni], 0, 0, 0);
        acc[mi][ni] = __builtin_amdgcn_mfma_f32_16x16x32_bf16(al[mi], bh[ni], acc[mi][ni], 0, 0, 0);
      }
    __syncthreads();
  }
  const float inv = 1.f/(counts[z] + 1e-6f);
  float dsum = 0.f; bool anyd = false;
  #pragma unroll
  for (int mi=0;mi<4;mi++){
    const int mbase = m0 + (wm*4+mi)*16 + quad*4;
    #pragma unroll
    for (int ni=0;ni<4;ni++){
      const int n = n0 + (wn*4+ni)*16 + ln;
      #pragma unroll
      for (int rg=0;rg<4;rg++){
        const int m = mbase + rg;
        float v = acc[mi][ni][rg]*inv + ((m==n)?0.1f:0.f);
        Ycov[(size_t)z*MSZ + (size_t)m*512 + n] = v;
        if (m0==n0 && m==n){ dsum += v; anyd = true; }
      }
    }
  }
  if (anyd) atomicAdd(&trsum[z], dsum);
}

// init split planes: Y = Ycov/trace (hi+lo bf16), Z = I
__global__ __launch_bounds__(256) void nsinitk(const float* __restrict__ Ycov, const float* __restrict__ sval,
                                               u16* __restrict__ Yh, u16* __restrict__ Yl,
                                               u16* __restrict__ Zh, u16* __restrict__ Zl){
  size_t idx = (size_t)blockIdx.x*256 + threadIdx.x;
  if (idx >= (size_t)PL) return;
  int z = (int)(idx >> 18);
  int rc = (int)(idx & (MSZ-1));
  int rr = rc >> 9, cc = rc & 511;
  float y = Ycov[idx] / sval[z];
  u16 h = bf16_rne(y);
  Yh[idx] = h;
  Yl[idx] = bf16_rne(y - bf16f(h));
  Zh[idx] = (rr==cc) ? (u16)0x3F80 : (u16)0;
  Zl[idx] = 0;
}

// ---- split-bf16 MFMA batched GEMM 512x512x512 ----
template<int MODE, int SYMB>
__global__ __launch_bounds__(256) void bmms(
    const u16* __restrict__ Ah, const u16* __restrict__ Al,
    const u16* __restrict__ Bh, const u16* __restrict__ Bl,
    u16* __restrict__ Ch, u16* __restrict__ Cl,
    const float* __restrict__ osc,
    int aoff, float* __restrict__ trAcc)
{
  const int z = blockIdx.z;
  const u16* Abh = Ah + (size_t)(z+aoff)*MSZ;
  const u16* Abl = Al + (size_t)(z+aoff)*MSZ;
  const u16* Bbh = Bh + (size_t)z*MSZ;
  const u16* Bbl = Bl + (size_t)z*MSZ;
  const int m0 = blockIdx.y*128, n0 = blockIdx.x*128;
  const int tid = threadIdx.x;

  __shared__ __align__(16) u16 sAh[128*40], sAl[128*40];
  __shared__ __align__(16) u16 sBh[128*40], sBl[128*40];

  const int ra = tid >> 2, qa = tid & 3;
  const int kb = tid >> 4, gb = tid & 15;

  const int wid = tid >> 6, lane = tid & 63;
  const int wm = wid >> 1, wn = wid & 1;
  const int quad = lane >> 4, ln = lane & 15;

  f32x4 acc[4][4];
  #pragma unroll
  for (int i=0;i<4;i++)
    #pragma unroll
    for (int j=0;j<4;j++)
      #pragma unroll
      for (int e=0;e<4;e++) acc[i][j][e] = 0.f;

  for (int k0 = 0; k0 < 512; k0 += 32){
    *(bf16x8*)&sAh[ra*40 + qa*8]      = *(const bf16x8*)&Abh[(size_t)(m0+ra)*512    + k0 + qa*8];
    *(bf16x8*)&sAl[ra*40 + qa*8]      = *(const bf16x8*)&Abl[(size_t)(m0+ra)*512    + k0 + qa*8];
    *(bf16x8*)&sAh[(ra+64)*40 + qa*8] = *(const bf16x8*)&Abh[(size_t)(m0+ra+64)*512 + k0 + qa*8];
    *(bf16x8*)&sAl[(ra+64)*40 + qa*8] = *(const bf16x8*)&Abl[(size_t)(m0+ra+64)*512 + k0 + qa*8];
    if constexpr (SYMB){
      *(bf16x8*)&sBh[ra*40 + qa*8]      = *(const bf16x8*)&Bbh[(size_t)(n0+ra)*512    + k0 + qa*8];
      *(bf16x8*)&sBl[ra*40 + qa*8]      = *(const bf16x8*)&Bbl[(size_t)(n0+ra)*512    + k0 + qa*8];
      *(bf16x8*)&sBh[(ra+64)*40 + qa*8] = *(const bf16x8*)&Bbh[(size_t)(n0+ra+64)*512 + k0 + qa*8];
      *(bf16x8*)&sBl[(ra+64)*40 + qa*8] = *(const bf16x8*)&Bbl[(size_t)(n0+ra+64)*512 + k0 + qa*8];
    } else {
      bf16x8 vh = *(const bf16x8*)&Bbh[(size_t)(k0+kb)*512 + n0 + gb*8];
      bf16x8 vl = *(const bf16x8*)&Bbl[(size_t)(k0+kb)*512 + n0 + gb*8];
      #pragma unroll
      for (int j=0;j<8;j++){
        sBh[(gb*8+j)*40 + kb] = (u16)vh[j];
        sBl[(gb*8+j)*40 + kb] = (u16)vl[j];
      }
      vh = *(const bf16x8*)&Bbh[(size_t)(k0+kb+16)*512 + n0 + gb*8];
      vl = *(const bf16x8*)&Bbl[(size_t)(k0+kb+16)*512 + n0 + gb*8];
      #pragma unroll
      for (int j=0;j<8;j++){
        sBh[(gb*8+j)*40 + kb+16] = (u16)vh[j];
        sBl[(gb*8+j)*40 + kb+16] = (u16)vl[j];
      }
    }
    __syncthreads();

    bf16x8 ah[4], al[4], bh[4], bl[4];
    #pragma unroll
    for (int t=0;t<4;t++){
      const int moA = ((wm*4+t)*16 + ln)*40 + quad*8;
      const int moB = ((wn*4+t)*16 + ln)*40 + quad*8;
      ah[t] = *(const bf16x8*)&sAh[moA];
      al[t] = *(const bf16x8*)&sAl[moA];
      bh[t] = *(const bf16x8*)&sBh[moB];
      bl[t] = *(const bf16x8*)&sBl[moB];
    }
    #pragma unroll
    for (int mi=0;mi<4;mi++)
      #pragma unroll
      for (int ni=0;ni<4;ni++){
        acc[mi][ni] = __builtin_amdgcn_mfma_f32_16x16x32_bf16(ah[mi], bh[ni], acc[mi][ni], 0, 0, 0);
        acc[mi][ni] = __builtin_amdgcn_mfma_f32_16x16x32_bf16(ah[mi], bl[ni], acc[mi][ni], 0, 0, 0);
        acc[mi][ni] = __builtin_amdgcn_mfma_f32_16x16x32_bf16(al[mi], bh[ni], acc[mi][ni], 0, 0, 0);
      }
    __syncthreads();
  }

  float alpha = 1.f;
  if constexpr (MODE==2){ alpha = osc[z]; }

  float dsum = 0.f; bool anyd = false;
  #pragma unroll
  for (int mi=0;mi<4;mi++){
    const int mbase = m0 + (wm*4+mi)*16 + quad*4;
    #pragma unroll
    for (int ni=0;ni<4;ni++){
      const int n = n0 + (wn*4+ni)*16 + ln;
      #pragma unroll
      for (int rg=0;rg<4;rg++){
        const int m = mbase + rg;
        const size_t off = (size_t)z*MSZ + (size_t)m*512 + n;
        float v = alpha*acc[mi][ni][rg];
        u16 h = bf16_rne(v);
        Ch[off] = h;
        Cl[off] = bf16_rne(v - bf16f(h));
        if (MODE==0 && trAcc && m0==n0 && m==n){ dsum += v; anyd = true; }
      }
    }
  }
  if (MODE==0 && anyd) atomicAdd(&trAcc[z], dsum);
}

// merged NS update. last==0: z<24 -> Y-update(zz=z); z>=24 -> Z-update(zz=z-24); grid z=48.
// last==1: z<12 -> Z-update(zz=z, content); z>=12 -> Y-update(zz=z, style); grid z=24.
__global__ __launch_bounds__(256) void bmmpair(
    const u16* __restrict__ Yh, const u16* __restrict__ Yl,
    const u16* __restrict__ Mh, const u16* __restrict__ Ml,
    const u16* __restrict__ Zh, const u16* __restrict__ Zl,
    u16* __restrict__ Y2h, u16* __restrict__ Y2l,
    u16* __restrict__ Z2h, u16* __restrict__ Z2l,
    const float* __restrict__ trAcc, int last)
{
  const int z = blockIdx.z;
  int zz; bool isY;
  if (last){ zz = z; isY = (z >= 12); }
  else { isY = (z < 24); zz = isY ? z : (z - 24); }
  const size_t zo = (size_t)zz*MSZ;
  const u16 *Abh, *Abl, *Bbh, *Bbl, *Dbh, *Dbl;
  u16 *Cbh, *Cbl;
  if (isY){
    Abh = Yh + zo; Abl = Yl + zo;
    Bbh = Mh + zo; Bbl = Ml + zo;
    Dbh = Yh + zo; Dbl = Yl + zo;
    Cbh = Y2h + zo; Cbl = Y2l + zo;
  } else {
    Abh = Mh + zo; Abl = Ml + zo;
    Bbh = Zh + zo; Bbl = Zl + zo;
    Dbh = Zh + zo; Dbl = Zl + zo;
    Cbh = Z2h + zo; Cbl = Z2l + zo;
  }
  const int m0 = blockIdx.y*128, n0 = blockIdx.x*128;
  const int tid = threadIdx.x;

  __shared__ __align__(16) u16 sAh[128*40], sAl[128*40];
  __shared__ __align__(16) u16 sBh[128*40], sBl[128*40];

  const int ra = tid >> 2, qa = tid & 3;
  const int wid = tid >> 6, lane = tid & 63;
  const int wm = wid >> 1, wn = wid & 1;
  const int quad = lane >> 4, ln = lane & 15;

  f32x4 acc[4][4];
  #pragma unroll
  for (int i=0;i<4;i++)
    #pragma unroll
    for (int j=0;j<4;j++)
      #pragma unroll
      for (int e=0;e<4;e++) acc[i][j][e] = 0.f;

  for (int k0 = 0; k0 < 512; k0 += 32){
    *(bf16x8*)&sAh[ra*40 + qa*8]      = *(const bf16x8*)&Abh[(size_t)(m0+ra)*512    + k0 + qa*8];
    *(bf16x8*)&sAl[ra*40 + qa*8]      = *(const bf16x8*)&Abl[(size_t)(m0+ra)*512    + k0 + qa*8];
    *(bf16x8*)&sAh[(ra+64)*40 + qa*8] = *(const bf16x8*)&Abh[(size_t)(m0+ra+64)*512 + k0 + qa*8];
    *(bf16x8*)&sAl[(ra+64)*40 + qa*8] = *(const bf16x8*)&Abl[(size_t)(m0+ra+64)*512 + k0 + qa*8];
    *(bf16x8*)&sBh[ra*40 + qa*8]      = *(const bf16x8*)&Bbh[(size_t)(n0+ra)*512    + k0 + qa*8];
    *(bf16x8*)&sBl[ra*40 + qa*8]      = *(const bf16x8*)&Bbl[(size_t)(n0+ra)*512    + k0 + qa*8];
    *(bf16x8*)&sBh[(ra+64)*40 + qa*8] = *(const bf16x8*)&Bbh[(size_t)(n0+ra+64)*512 + k0 + qa*8];
    *(bf16x8*)&sBl[(ra+64)*40 + qa*8] = *(const bf16x8*)&Bbl[(size_t)(n0+ra+64)*512 + k0 + qa*8];
    __syncthreads();

    bf16x8 ah[4], al[4], bh[4], bl[4];
    #pragma unroll
    for (int t=0;t<4;t++){
      const int moA = ((wm*4+t)*16 + ln)*40 + quad*8;
      const int moB = ((wn*4+t)*16 + ln)*40 + quad*8;
      ah[t] = *(const bf16x8*)&sAh[moA];
      al[t] = *(const bf16x8*)&sAl[moA];
      bh[t] = *(const bf16x8*)&sBh[moB];
      bl[t] = *(const bf16x8*)&sBl[moB];
    }
    #pragma unroll
    for (int mi=0;mi<4;mi++)
      #pragma unroll
      for (int ni=0;ni<4;ni++){
        acc[mi][ni] = __builtin_amdgcn_mfma_f32_16x16x32_bf16(ah[mi], bh[ni], acc[mi][ni], 0, 0, 0);
        acc[mi][ni] = __builtin_amdgcn_mfma_f32_16x16x32_bf16(ah[mi], bl[ni], acc[mi][ni], 0, 0, 0);
        acc[mi][ni] = __builtin_amdgcn_mfma_f32_16x16x32_bf16(al[mi], bh[ni], acc[mi][ni], 0, 0, 0);
      }
    __syncthreads();
  }

  const float tr = trAcc[zz];
  const float g2 = fminf(512.f/fmaxf(tr, 1e-6f), 2.7f);
  const float oz = 0.5f*sqrtf(g2);
  const float alpha = -g2*oz, beta = 3.f*oz;

  #pragma unroll
  for (int mi=0;mi<4;mi++){
    const int mbase = m0 + (wm*4+mi)*16 + quad*4;
    #pragma unroll
    for (int ni=0;ni<4;ni++){
      const int n = n0 + (wn*4+ni)*16 + ln;
      #pragma unroll
      for (int rg=0;rg<4;rg++){
        const int m = mbase + rg;
        const size_t off = (size_t)m*512 + n;
        float v = alpha*acc[mi][ni][rg] + beta*(bf16f(Dbh[off]) + bf16f(Dbl[off]));
        u16 h = bf16_rne(v);
        Cbh[off] = h;
        Cbl[off] = bf16_rne(v - bf16f(h));
      }
    }
  }
}

// tpts = T[z] @ f[img]: M=512, N=1024, K=512, fp32 out
__global__ __launch_bounds__(256) void bmmt(
    const u16* __restrict__ Th, const u16* __restrict__ Tl,
    const u16* __restrict__ fh, const u16* __restrict__ fl,
    float* __restrict__ Cf)
{
  const int z = blockIdx.z;
  const u16* Abh = Th + (size_t)z*MSZ;
  const u16* Abl = Tl + (size_t)z*MSZ;
  const u16* Bbh = fh + (size_t)(z/3)*524288;
  const u16* Bbl = fl + (size_t)(z/3)*524288;
  const int m0 = blockIdx.y*128, n0 = blockIdx.x*128;
  const int tid = threadIdx.x;

  __shared__ __align__(16) u16 sAh[128*40], sAl[128*40];
  __shared__ __align__(16) u16 sBh[128*40], sBl[128*40];

  const int ra = tid >> 2, qa = tid & 3;
  const int kb = tid >> 4, gb = tid & 15;
  const int wid = tid >> 6, lane = tid & 63;
  const int wm = wid >> 1, wn = wid & 1;
  const int quad = lane >> 4, ln = lane & 15;

  f32x4 acc[4][4];
  #pragma unroll
  for (int i=0;i<4;i++)
    #pragma unroll
    for (int j=0;j<4;j++)
      #pragma unroll
      for (int e=0;e<4;e++) acc[i][j][e] = 0.f;

  for (int k0 = 0; k0 < 512; k0 += 32){
    *(bf16x8*)&sAh[ra*40 + qa*8]      = *(const bf16x8*)&Abh[(size_t)(m0+ra)*512    + k0 + qa*8];
    *(bf16x8*)&sAl[ra*40 + qa*8]      = *(const bf16x8*)&Abl[(size_t)(m0+ra)*512    + k0 + qa*8];
    *(bf16x8*)&sAh[(ra+64)*40 + qa*8] = *(const bf16x8*)&Abh[(size_t)(m0+ra+64)*512 + k0 + qa*8];
    *(bf16x8*)&sAl[(ra+64)*40 + qa*8] = *(const bf16x8*)&Abl[(size_t)(m0+ra+64)*512 + k0 + qa*8];
    {
      bf16x8 vh = *(const bf16x8*)&Bbh[(size_t)(k0+kb)*1024 + n0 + gb*8];
      bf16x8 vl = *(const bf16x8*)&Bbl[(size_t)(k0+kb)*1024 + n0 + gb*8];
      #pragma unroll
      for (int j=0;j<8;j++){
        sBh[(gb*8+j)*40 + kb] = (u16)vh[j];
        sBl[(gb*8+j)*40 + kb] = (u16)vl[j];
      }
      vh = *(const bf16x8*)&Bbh[(size_t)(k0+kb+16)*1024 + n0 + gb*8];
      vl = *(const bf16x8*)&Bbl[(size_t)(k0+kb+16)*1024 + n0 + gb*8];
      #pragma unroll
      for (int j=0;j<8;j++){
        sBh[(gb*8+j)*40 + kb+16] = (u16)vh[j];
        sBl[(gb*8+j)*40 + kb+16] = (u16)vl[j];
      }
    }
    __syncthreads();

    bf16x8 ah[4], al[4], bh[4], bl[4];
    #pragma unroll
    for (int t=0;t<4;t++){
      const int moA = ((wm*4+t)*16 + ln)*40 + quad*8;
      const int moB = ((wn*4+t)*16 + ln)*40 + quad*8;
      ah[t] = *(const bf16x8*)&sAh[moA];
      al[t] = *(const bf16x8*)&sAl[moA];
      bh[t] = *(const bf16x8*)&sBh[moB];
      bl[t] = *(const bf16x8*)&sBl[moB];
    }
    #pragma unroll
    for (int mi=0;mi<4;mi++)
      #pragma unroll
      for (int ni=0;ni<4;ni++){
        acc[mi][ni] = __builtin_amdgcn_mfma_f32_16x16x32_bf16(ah[mi], bh[ni], acc[mi][ni], 0, 0, 0);
        acc[mi][ni] = __builtin_amdgcn_mfma_f32_16x16x32_bf16(ah[mi], bl[ni], acc[mi][ni], 0, 0, 0);
        acc[mi][ni] = __builtin_amdgcn_mfma_f32_16x16x32_bf16(al[mi], bh[ni], acc[mi][ni], 0, 0, 0);
      }
    __syncthreads();
  }
  #pragma unroll
  for (int mi=0;mi<4;mi++){
    const int mbase = m0 + (wm*4+mi)*16 + quad*4;
    #pragma unroll
    for (int ni=0;ni<4;ni++){
      const int n = n0 + (wn*4+ni)*16 + ln;
      #pragma unroll
      for (int rg=0;rg<4;rg++){
        const int m = mbase + rg;
        Cf[(size_t)z*524288 + (size_t)m*1024 + n] = acc[mi][ni][rg];
      }
    }
  }
}

// generic fp32 -> split bf16
__global__ __launch_bounds__(256) void splitk(const float* __restrict__ src,
                                              u16* __restrict__ dh, u16* __restrict__ dl, int n4){
  int i = blockIdx.x*256 + threadIdx.x;
  if (i >= n4) return;
  float4 v4 = *(const float4*)&src[(size_t)i*4];
  float vv[4] = {v4.x, v4.y, v4.z, v4.w};
  u16x4 oh, ol;
  #pragma unroll
  for (int j=0;j<4;j++){
    u16 h = bf16_rne(vv[j]);
    oh[j] = (short)h;
    ol[j] = (short)bf16_rne(vv[j] - bf16f(h));
  }
  *(u16x4*)&dh[(size_t)i*4] = oh;
  *(u16x4*)&dl[(size_t)i*4] = ol;
}

__global__ void make_scalesk(const float* __restrict__ sval, float* __restrict__ scl){
  int i = threadIdx.x;
  if (i < 12) scl[i] = sqrtf(sval[12+i] / sval[i]);
}

// tvec[b] = mu_s[b] - T[b] @ mu_c[b]
__global__ __launch_bounds__(512) void tveck(const u16* __restrict__ Th, const u16* __restrict__ Tl,
                                             const float* __restrict__ mu, float* __restrict__ tvec){
  int b = blockIdx.x; int c = threadIdx.x;
  __shared__ float mc[512];
  mc[c] = mu[(size_t)b*512 + c];
  __syncthreads();
  const u16* Trh = Th + ((size_t)b*512 + c)*512;
  const u16* Trl = Tl + ((size_t)b*512 + c)*512;
  float s = 0.f;
  for (int d=0; d<512; d++) s = fmaf(bf16f(Trh[d]) + bf16f(Trl[d]), mc[d], s);
  tvec[b*512 + c] = mu[(size_t)(12+b)*512 + c] - s;
}

__global__ __launch_bounds__(256) void selectk(const float* __restrict__ tpts, const float* __restrict__ tvec,
        const int* __restrict__ a, const float* __restrict__ f4c, float* __restrict__ tf){
  size_t idx = (size_t)blockIdx.x*256 + threadIdx.x;
  if (idx >= 2097152ul) return;
  int n = (int)(idx & 1023);
  int c = (int)((idx >> 10) & 511);
  int img = (int)(idx >> 19);
  int k = a[img*1024 + n];
  int b = img*3 + k;
  float v = tpts[((size_t)b*512 + c)*1024 + n] + tvec[b*512 + c];
  tf[idx] = 0.6f*v + 0.4f*f4c[idx];
}

__global__ __launch_bounds__(256) void clossk(const float* __restrict__ x, const float* __restrict__ y,
                                              int n, float* __restrict__ acc){
  int tid = threadIdx.x;
  float s = 0.f;
  for (size_t i = (size_t)blockIdx.x*256 + tid; i < (size_t)n; i += (size_t)gridDim.x*256){
    float d = x[i] - y[i]; s = fmaf(d, d, s);
  }
  __shared__ float sh[256];
  sh[tid] = s; __syncthreads();
  for (int k=128;k>0;k>>=1){ if (tid<k) sh[tid]+=sh[tid+k]; __syncthreads(); }
  if (tid==0) atomicAdd(acc, sh[0]);
}

__global__ __launch_bounds__(256) void finalk(const float* __restrict__ sm, float* __restrict__ out){
  int tid = threadIdx.x;
  const int cnts[4] = {256,512,1024,2048};
  const int offs[4] = {0,256,768,1792};
  const float* mS = sm + SM_STATS_S;
  const float* sS = sm + SM_STATS_S + 3840;
  const float* mD = sm + SM_STATS_D;
  const float* sD = sm + SM_STATS_D + 3840;
  double sl = 0.0;
  for (int L=0; L<4; ++L){
    int cnt = cnts[L], off = offs[L];
    double inv = 1.0/cnt;
    for (int i=tid; i<cnt; i+=256){
      double dm = (double)mD[off+i] - (double)mS[off+i];
      double ds = (double)sD[off+i] - (double)sS[off+i];
      sl += (dm*dm + ds*ds)*inv;
    }
  }
  __shared__ double sh[256];
  sh[tid] = sl; __syncthreads();
  for (int k=128;k>0;k>>=1){ if (tid<k) sh[tid]+=sh[tid+k]; __syncthreads(); }
  if (tid==0){
    double closs = (double)sm[SM_CLOSS] / 2097152.0;
    out[0] = (float)(closs + 0.01*sh[0]);
  }
}

// ---------------- host ----------------

extern "C" void kernel_launch(void* const* d_in, const int* in_sizes, int n_in,
                              void* d_out, int out_size, void* d_ws, size_t ws_size,
                              hipStream_t stream)
{
  const float* content = (const float*)d_in[0];
  const float* style   = (const float*)d_in[1];
  const float* Wm[8]; const float* Bm[8];
  for (int i=0;i<8;i++){ Wm[i] = (const float*)d_in[2+2*i]; Bm[i] = (const float*)d_in[3+2*i]; }
  float* out = (float*)d_out;
  float* ws = (float*)d_ws;

  float* f4c  = ws + OFF_F4C;
  float* f4s  = ws + OFF_F4S;
  float* tf   = ws + OFF_TF;
  float* dec  = ws + OFF_DEC;
  float* sm   = ws + OFF_SMALL;
  float* AR   = ws + OFF_ARENA;
  int*   aPtr = (int*)(sm + SM_ASSIGN);
  float* mu   = sm + SM_MU;
  float* counts = sm + SM_COUNTS;
  float* sval = sm + SM_SVAL;
  float* scl  = sm + SM_SCALE;
  float* tvec = sm + SM_TVEC;
  float* trbuf = sm + SM_TR;

  u16* WB = (u16*)(ws + OFF_WSPL);
  u16 *w2h=WB+0,       *w2l=WB+73728;
  u16 *w3h=WB+147456,  *w3l=WB+442368;
  u16 *w4h=WB+737280,  *w4l=WB+1916928;
  u16 *v1h=WB+3096576, *v1l=WB+4276224;
  u16 *v2h=WB+5455872, *v2l=WB+5750784;
  u16 *v3h=WB+6045696, *v3l=WB+6119424;

  float* Ycov = AR;
  u16* Mh  = (u16*)(AR);
  u16* Ml  = (u16*)(AR + 3145728ul);
  u16* Yh  = (u16*)(AR + 6291456ul);
  u16* Yl  = (u16*)(AR + 9437184ul);
  u16* Zh  = (u16*)(AR + 12582912ul);
  u16* Zl  = (u16*)(AR + 15728640ul);
  u16* Y2h = (u16*)(AR + 18874368ul);
  u16* Y2l = (u16*)(AR + 22020096ul);
  u16* Z2h = (u16*)(AR + 25165824ul);
  u16* Z2l = (u16*)(AR + 28311552ul);
  u16* Ph  = (u16*)(AR + 18874368ul);
  u16* Pl  = (u16*)(AR + 25165824ul);
  float* ptsT = AR + 25165824ul;
  u16* Th  = (u16*)(AR + 18874368ul);
  u16* Tl  = (u16*)(AR + 20971520ul);
  u16* fsh = (u16*)(AR + 23068672ul);
  u16* fsl = (u16*)(AR + 24117248ul);
  float* KACC = AR + 0;

  zerok<<<512,256,0,stream>>>(sm, 131072);

  {
    auto wsp = [&](int li, u16* wh, u16* wl, int Co, int Ci){
      int n = 9*Co*Ci;
      wsplitk<<<(n+255)/256,256,0,stream>>>(Wm[li], wh, wl, Co, Ci);
    };
    wsp(1,w2h,w2l,128,64);
    wsp(2,w3h,w3l,256,128);
    wsp(3,w4h,w4l,512,256);
    wsp(4,v1h,v1l,256,512);
    wsp(5,v2h,v2l,128,256);
    wsp(6,v3h,v3l,64,128);
  }

  auto conv = [&](const float* inp, int li, float* outp, int B,int Ci,int Co,int H,int Wd,int relu,int cot){
    dim3 g((H>>5)*(Wd>>5), (Co + cot - 1)/cot, B);
    if (cot==8)      conv3x3<8><<<g,256,0,stream>>>(inp,Wm[li],Bm[li],outp,B,Ci,Co,H,Wd,relu);
    else if (cot==4) conv3x3<4><<<g,256,0,stream>>>(inp,Wm[li],Bm[li],outp,B,Ci,Co,H,Wd,relu);
    else             conv3x3<1><<<g,256,0,stream>>>(inp,Wm[li],Bm[li],outp,B,Ci,Co,H,Wd,relu);
  };
  // KS in {1,2,4}, RESIZE in {0,1,2}
  auto convM = [&](const float* inp, int li, float* outp, int B,int Ci,int Co,int H,int Wd,int relu,int KS,int RZ,float* part){
    const u16 *wh=nullptr,*wl=nullptr;
    switch(li){
      case 1: wh=w2h; wl=w2l; break;
      case 2: wh=w3h; wl=w3l; break;
      case 3: wh=w4h; wl=w4l; break;
      case 4: wh=v1h; wl=v1l; break;
      case 5: wh=v2h; wl=v2l; break;
      case 6: wh=v3h; wl=v3l; break;
    }
    int tiles = (H>>3)*(Wd>>3);
    if (KS==1){
      dim3 g(tiles,Co>>6,B);
      if (RZ==0)      convm<1,0><<<g,256,0,stream>>>(inp,wh,wl,Bm[li],outp,Ci,Co,H,Wd,relu);
      else if (RZ==1) convm<1,1><<<g,256,0,stream>>>(inp,wh,wl,Bm[li],outp,Ci,Co,H,Wd,relu);
      else            convm<1,2><<<g,256,0,stream>>>(inp,wh,wl,Bm[li],outp,Ci,Co,H,Wd,relu);
    } else {
      int n = B*Co*H*Wd;
      if (KS==2){
        dim3 g(tiles,Co>>6,B*2);
        if (RZ==0)      convm<2,0><<<g,256,0,stream>>>(inp,wh,wl,nullptr,part,Ci,Co,H,Wd,relu);
        else if (RZ==1) convm<2,1><<<g,256,0,stream>>>(inp,wh,wl,nullptr,part,Ci,Co,H,Wd,relu);
        else            convm<2,2><<<g,256,0,stream>>>(inp,wh,wl,nullptr,part,Ci,Co,H,Wd,relu);
      } else {
        dim3 g(tiles,Co>>6,B*4);
        if (RZ==0)      convm<4,0><<<g,256,0,stream>>>(inp,wh,wl,nullptr,part,Ci,Co,H,Wd,relu);
        else if (RZ==1) convm<4,1><<<g,256,0,stream>>>(inp,wh,wl,nullptr,part,Ci,Co,H,Wd,relu);
        else            convm<4,2><<<g,256,0,stream>>>(inp,wh,wl,nullptr,part,Ci,Co,H,Wd,relu);
      }
      sumk<<<(n+255)/256,256,0,stream>>>(part,Bm[li],outp,Co,H*Wd,KS,relu,n);
    }
  };
  auto pool = [&](const float* inp, float* outp, int B,int C,int Ho,int Wo){
    int n = B*C*Ho*Wo;
    pool2k<<<(n+255)/256,256,0,stream>>>(inp,outp,n,Ho,Wo);
  };
  auto up = [&](const float* inp, float* outp, int B,int C,int Ho,int Wo){
    int n = B*C*Ho*Wo;
    up2k<<<(n+255)/256,256,0,stream>>>(inp,outp,n,Ho,Wo);
  };

  float* mS = sm + SM_STATS_S;
  float* sS = sm + SM_STATS_S + 3840;

  // ---- batched content+style encode (B=8 from e2 down; e3/e4 pool fused) ----
  float* F1   = AR + 0;
  float* P1_8 = AR + 16777216ul;
  float* F2_8 = AR + 0;
  float* F3_8 = AR + 0;
  float* PART8 = AR + 10485760ul;

  conv(content, 0, F1, 4, 3,64,256,256,1,8);
  pool(F1, P1_8, 4, 64,128,128);
  conv(style, 0, F1, 4, 3,64,256,256,1,8);
  statsk<<<256,256,0,stream>>>(F1,65536, mS+0, sS+0);
  pool(F1, P1_8 + 4194304ul, 4, 64,128,128);

  convM(P1_8, 1, F2_8, 8, 64,128,128,128,1,1,0,nullptr);
  statsk<<<512,256,0,stream>>>(F2_8 + 8388608ul, 16384, mS+256, sS+256);
  convM(F2_8, 2, F3_8, 8, 128,256,64,64,1,1,1,nullptr);      // pool fused (input 128^2)
  statsk<<<1024,256,0,stream>>>(F3_8 + 4194304ul, 4096, mS+768, sS+768);
  convM(F3_8, 3, f4c, 8, 256,512,32,32,1,2,1,PART8);          // pool fused (input 64^2)
  statsk<<<2048,256,0,stream>>>(f4s,1024, mS+1792, sS+1792);

  // ---- fused k-means ----
  transposek<<<dim3(32,16,8),256,0,stream>>>(f4c,f4s,ptsT);
  zerok<<<(12*KSLOT+255)/256,256,0,stream>>>(KACC, 12*KSLOT);
  initcent2k<<<48,256,0,stream>>>(ptsT,KACC);
  for (int it=0; it<=10; ++it){
    kstepk<<<dim3(8,32),256,0,stream>>>(ptsT, KACC + (size_t)it*KSLOT, KACC + (size_t)(it+1)*KSLOT, aPtr, it==0 ? 1 : 0);
  }
  mufink<<<48,256,0,stream>>>(KACC + 11ul*KSLOT, mu, counts);

  // ---- covariances via MFMA ----
  maskcenterk<<<12288,256,0,stream>>>(f4c,f4s,aPtr,mu,Ph,Pl);
  covgemm<<<dim3(4,4,24),256,0,stream>>>(Ph,Pl,counts,Ycov,sval);
  nsinitk<<<24576,256,0,stream>>>(Ycov,sval,Yh,Yl,Zh,Zl);

  // ---- split-bf16 MFMA Newton-Schulz ----
  u16 *Ych=Yh,*Ycl=Yl,*Zch=Zh,*Zcl=Zl,*Yah=Y2h,*Yal=Y2l,*Zah=Z2h,*Zal=Z2l;
  for (int it=0; it<NS_ITERS; ++it){
    bmms<0,1><<<dim3(4,4,24),256,0,stream>>>(Zch,Zcl,Ych,Ycl,Mh,Ml,nullptr,0,trbuf+it*24);
    if (it < NS_ITERS-1)
      bmmpair<<<dim3(4,4,48),256,0,stream>>>(Ych,Ycl,Mh,Ml,Zch,Zcl,Yah,Yal,Zah,Zal,trbuf+it*24,0);
    else
      bmmpair<<<dim3(4,4,24),256,0,stream>>>(Ych,Ycl,Mh,Ml,Zch,Zcl,Yah,Yal,Zah,Zal,trbuf+it*24,1);
    u16* t;
    t=Ych;Ych=Yah;Yah=t; t=Ycl;Ycl=Yal;Yal=t;
    t=Zch;Zch=Zah;Zah=t; t=Zcl;Zcl=Zal;Zal=t;
  }
  make_scalesk<<<1,64,0,stream>>>(sval,scl);
  bmms<2,1><<<dim3(4,4,12),256,0,stream>>>(Ych,Ycl,Zch,Zcl,Th,Tl,scl,12,nullptr);
  tveck<<<12,512,0,stream>>>(Th,Tl,mu,tvec);
  splitk<<<2048,256,0,stream>>>(f4c,fsh,fsl,524288);
  float* Mb = AR + 0;
  bmmt<<<dim3(8,4,12),256,0,stream>>>(Th,Tl,fsh,fsl,Mb);
  selectk<<<8192,256,0,stream>>>(Mb,tvec,aPtr,f4c,tf);

  // ---- decode (B=4; up fused into d2/d3) ----
  float* X1 = AR + 0;
  float* X2 = AR + 5242880ul;
  float* X3 = AR + 0;
  float* U3 = AR + 4194304ul;
  float* PARTA = AR + 2097152ul;
  float* PARTB = AR + 7340032ul;
  convM(tf, 4, X1, 4, 512,256,32,32,1,4,0,PARTA);
  convM(X1,5,X2, 4, 256,128,64,64,1,2,2,PARTB);               // up fused (input 32^2)
  convM(X2,6,X3, 4, 128,64,128,128,1,1,2,nullptr);            // up fused (input 64^2)
  up(X3,U3, 4, 64,256,256);
  conv(U3,7,dec, 4, 64,3,256,256,0,1);

  // ---- decoded encode + stats + content loss (B=4) ----
  float* mD = sm + SM_STATS_D;
  float* sD = sm + SM_STATS_D + 3840;
  float* F1d = AR + 0;
  float* P1d = AR + 16777216ul;
  float* F2d = AR + 0;
  float* F3d = AR + 10485760ul;
  conv(dec, 0, F1d, 4, 3,64,256,256,1,8);
  statsk<<<256,256,0,stream>>>(F1d,65536, mD+0, sD+0);
  pool(F1d,P1d, 4, 64,128,128);
  convM(P1d,1,F2d, 4, 64,128,128,128,1,1,0,nullptr);
  statsk<<<512,256,0,stream>>>(F2d,16384, mD+256, sD+256);
  convM(F2d,2,F3d, 4, 128,256,64,64,1,1,1,nullptr);           // pool fused
  statsk<<<1024,256,0,stream>>>(F3d,4096, mD+768, sD+768);
  convM(F3d,3,tf, 4, 256,512,32,32,1,2,1,PARTA);              // pool fused
  statsk<<<2048,256,0,stream>>>(tf,1024, mD+1792, sD+1792);
  clossk<<<2048,256,0,stream>>>(tf,f4c,2097152, sm+SM_CLOSS);
  finalk<<<1,256,0,stream>>>(sm,out);
}